// Round 4
// baseline (7348.653 us; speedup 1.0000x reference)
//
#include <hip/hip_runtime.h>
#include <hip/hip_bf16.h>

#define BN 2
#define NH 12
#define NTOK 1600
#define NM 576
#define NS 1024
#define CD 768
#define HD 64
#define ROWS 4

typedef unsigned int u32;

__device__ __forceinline__ u32 f2s(float f) {  // order-preserving float->u32 key
    u32 u = __float_as_uint(f);
    return (u & 0x80000000u) ? ~u : (u | 0x80000000u);
}
__device__ __forceinline__ float s2f(u32 k) {
    u32 u = (k & 0x80000000u) ? (k & 0x7fffffffu) : ~k;
    return __uint_as_float(u);
}

__device__ __forceinline__ float dot768_ff(const float* __restrict__ a,
                                           const float* __restrict__ b) {
    float s = 0.f;
    for (int c = 0; c < CD; c += 4) {
        float4 fa = *(const float4*)(a + c);
        float4 fb = *(const float4*)(b + c);
        s += fa.x * fb.x + fa.y * fb.y + fa.z * fb.z + fa.w * fb.w;
    }
    return s;
}

// ---------------- small LoRA z kernels ----------------

__global__ __launch_bounds__(256) void z24_kernel(const float* __restrict__ x,
                                                  const float* __restrict__ Aq,
                                                  float* __restrict__ z) {
    int idx = blockIdx.x * 256 + threadIdx.x;  // exactly 76800
    int m = idx / 24, q = idx % 24;
    z[idx] = dot768_ff(x + (size_t)m * CD, Aq + (size_t)q * CD);
}

__global__ __launch_bounds__(256) void zid_kernel(const float* __restrict__ id,
                                                  const float* __restrict__ Ak,
                                                  const float* __restrict__ Av,
                                                  float* __restrict__ zk, float* __restrict__ zv) {
    int idx = blockIdx.x * 256 + threadIdx.x;  // exactly 18432
    int m = idx >> 4, q = idx & 15;
    const float* a = (q < 8) ? (Ak + (size_t)q * CD) : (Av + (size_t)(q - 8) * CD);
    float v = dot768_ff(id + (size_t)m * CD, a);
    if (q < 8) zk[m * 8 + q] = v; else zv[m * 8 + q - 8] = v;
}

__global__ __launch_bounds__(256) void idk_kernel(const float* __restrict__ id,
                                                  const float* __restrict__ Wk,
                                                  const float* __restrict__ bk,
                                                  const float* __restrict__ zk,
                                                  const float* __restrict__ Bk,
                                                  float* __restrict__ IDK) {
    int idx = blockIdx.x * 256 + threadIdx.x;  // exactly 13824
    int m = idx / NH, h = idx % NH;
    float v = dot768_ff(id + (size_t)m * CD, Wk + (size_t)h * CD) + bk[h];
    float lo = 0.f;
#pragma unroll
    for (int r = 0; r < 8; ++r) lo += zk[m * 8 + r] * Bk[h * 8 + r];
    IDK[idx] = v + 0.125f * lo;
}

// ---------------- GEMM core macro (64x64 tile, 256 thr, 4x4 micro), f32 ----------------
// acc[i][j] for C[m0+ty*4+i][j0+tx*4+jj] = sum_k A[m][k]*W[j][k]

#define GEMM_CORE(Aexpr, Wexpr)                                                 \
    float acc[4][4] = {};                                                       \
    {                                                                           \
        const int lr = tid >> 2, lk = (tid & 3) * 4;                            \
        for (int k0 = 0; k0 < CD; k0 += 16) {                                   \
            const float4 ta = *(const float4*)&(Aexpr)[(size_t)(m0 + lr) * CD + k0 + lk]; \
            const float4 tb = *(const float4*)&(Wexpr)[(size_t)(j0 + lr) * CD + k0 + lk]; \
            __syncthreads();                                                    \
            As[(lk + 0) * 68 + lr] = ta.x;                                      \
            As[(lk + 1) * 68 + lr] = ta.y;                                      \
            As[(lk + 2) * 68 + lr] = ta.z;                                      \
            As[(lk + 3) * 68 + lr] = ta.w;                                      \
            Bs[(lk + 0) * 68 + lr] = tb.x;                                      \
            Bs[(lk + 1) * 68 + lr] = tb.y;                                      \
            Bs[(lk + 2) * 68 + lr] = tb.z;                                      \
            Bs[(lk + 3) * 68 + lr] = tb.w;                                      \
            __syncthreads();                                                    \
            _Pragma("unroll")                                                   \
            for (int kk = 0; kk < 16; ++kk) {                                   \
                const float4 a4 = *(const float4*)&As[kk * 68 + ty * 4];        \
                const float4 b4 = *(const float4*)&Bs[kk * 68 + tx * 4];        \
                const float aa[4] = {a4.x, a4.y, a4.z, a4.w};                   \
                const float bb[4] = {b4.x, b4.y, b4.z, b4.w};                   \
                _Pragma("unroll")                                               \
                for (int i = 0; i < 4; ++i)                                     \
                    _Pragma("unroll")                                           \
                    for (int j = 0; j < 4; ++j) acc[i][j] += aa[i] * bb[j];     \
            }                                                                   \
        }                                                                       \
    }

// ---------------- ID_V GEMM: scatter into o_vm (d_out) ----------------
__global__ __launch_bounds__(256) void idv_kernel(const float* __restrict__ A,
                                                  const float* __restrict__ Bw,
                                                  const float* __restrict__ bias,
                                                  const float* __restrict__ zv,
                                                  const float* __restrict__ Bl,
                                                  float* __restrict__ ovm) {
    __shared__ float As[16 * 68];
    __shared__ float Bs[16 * 68];
    const int tid = threadIdx.x;
    const int tx = tid & 15, ty = tid >> 4;
    const int j0 = blockIdx.x * 64, m0 = blockIdx.y * 64;
    GEMM_CORE(A, Bw)
#pragma unroll
    for (int i = 0; i < 4; ++i) {
        const int m = m0 + ty * 4 + i;
        const int b = m / NM, n = m - (m / NM) * NM;
        const float* zr = zv + (size_t)m * 8;
#pragma unroll
        for (int jj = 0; jj < 4; ++jj) {
            const int j = j0 + tx * 4 + jj;
            const int h = j >> 6, d = j & 63;
            float lora = 0.f;
            const float* bl = Bl + (size_t)j * 8;
#pragma unroll
            for (int r = 0; r < 8; ++r) lora += zr[r] * bl[r];
            ovm[(((size_t)(b * NH + h)) * NM + n) * 64 + d] =
                acc[i][jj] + bias[j] + 0.125f * lora;
        }
    }
}

// ---------------- qkv GEMM: scatter q/k/v + fuse gate & ID_V add ----------------
__global__ __launch_bounds__(256) void qkv_kernel(const float* __restrict__ A,
                                                  const float* __restrict__ Bw,
                                                  const float* __restrict__ bias,
                                                  const float* __restrict__ zq,
                                                  const float* __restrict__ Bl,
                                                  const float* __restrict__ IDK,
                                                  float* __restrict__ qb,
                                                  float* __restrict__ kb,
                                                  float* __restrict__ okm,
                                                  float* __restrict__ ovm,
                                                  float* __restrict__ vtail) {
    __shared__ float As[16 * 68];
    __shared__ float Bs[16 * 68];
    const int tid = threadIdx.x;
    const int tx = tid & 15, ty = tid >> 4;
    const int j0 = blockIdx.x * 64, m0 = blockIdx.y * 64;
    GEMM_CORE(A, Bw)
    const int g = j0 / CD;          // 0=q 1=k 2=v (tile never crosses group/head)
    const int hq = (j0 % CD) >> 6;  // head
#pragma unroll
    for (int i = 0; i < 4; ++i) {
        const int m = m0 + ty * 4 + i;
        const int b = m / NTOK, n = m - (m / NTOK) * NTOK;
        float gate = 0.f;
        if (g == 1 && n < NM) gate = 1.f + tanhf(IDK[(b * NM + n) * NH + hq]);
        const float* zr = zq + (size_t)m * 24 + g * 8;
#pragma unroll
        for (int jj = 0; jj < 4; ++jj) {
            const int d = tx * 4 + jj;
            const int c = hq * 64 + d;
            const int j = j0 + tx * 4 + jj;
            float lora = 0.f;
            const float* bl = Bl + (size_t)(g * CD + c) * 8;
#pragma unroll
            for (int r = 0; r < 8; ++r) lora += zr[r] * bl[r];
            float val = acc[i][jj] + bias[j] + 0.125f * lora;
            const size_t o = (((size_t)(b * NH + hq)) * NTOK + n) * 64 + d;
            const size_t om = (((size_t)(b * NH + hq)) * NM + n) * 64 + d;
            if (g == 0) {
                qb[o] = val * 0.125f;  // q pre-scaled by hd^-0.5
            } else if (g == 1) {
                kb[o] = val;                       // raw k (seq attn)
                if (n < NM) okm[om] = val * gate;  // k_m output & mem-attn K
            } else {
                if (n < NM) {
                    ovm[om] = val + ovm[om];  // ovm held ID_V -> now v_m (& attn V)
                } else {
                    vtail[(((size_t)(b * NH + hq)) * NS + (n - NM)) * 64 + d] = val;
                }
            }
        }
    }
}

// ---------------- top-k softmax attention (f32) ----------------
// One block = ROWS query rows of one (b,h). Full logit row in LDS; exact k-th
// largest via byte-radix select; tie mass counted per reference. V in 3 segments.
__global__ __launch_bounds__(256) void attn_kernel(const float* __restrict__ qb,
                                                   const float* __restrict__ K1,
                                                   const float* __restrict__ K2,
                                                   const float* __restrict__ V1,
                                                   const float* __restrict__ V2,
                                                   const float* __restrict__ V3,
                                                   float* __restrict__ aob,
                                                   int L1, int L, int top, int row_start,
                                                   int k2_rows, int v2_rows, int v3_rows) {
    extern __shared__ float sm[];
    float* qs = sm;                 // 256
    float* red = sm + 256;          // 256
    u32* hist = (u32*)(sm + 512);   // 256
    u32* bcu = (u32*)(sm + 768);    // 8
    float* wgt = sm + 776;          // ROWS * L

    const int tid = threadIdx.x;
    const int bh = blockIdx.y;
    const int b = bh / NH, h = bh - b * NH;
    const int r0 = blockIdx.x * ROWS;

    qs[tid] = qb[(((size_t)bh) * NTOK + row_start + r0) * 64 + tid];
    __syncthreads();

    const size_t base1 = ((size_t)bh) * NTOK * 64;  // K1/V1 panels have NTOK(=N_mem) rows
    const size_t k2base = ((size_t)bh) * (size_t)k2_rows * 64;
    const size_t v2base = ((size_t)bh) * (size_t)v2_rows * 64;
    const size_t v3base = ((size_t)bh) * (size_t)v3_rows * 64;

    for (int l = tid; l < L; l += 256) {
        float acc[ROWS] = {0.f, 0.f, 0.f, 0.f};
        const float* kp = (l < L1) ? (K1 + base1 + (size_t)l * 64)
                                   : (K2 + k2base + (size_t)(l - L1) * 64);
#pragma unroll
        for (int dq = 0; dq < 16; ++dq) {
            const float4 k4 = *(const float4*)(kp + dq * 4);
#pragma unroll
            for (int rr = 0; rr < ROWS; ++rr) {
                const float4 q4 = *(const float4*)(qs + rr * 64 + dq * 4);
                acc[rr] += k4.x * q4.x + k4.y * q4.y + k4.z * q4.z + k4.w * q4.w;
            }
        }
#pragma unroll
        for (int rr = 0; rr < ROWS; ++rr) wgt[rr * L + l] = acc[rr];
    }
    __syncthreads();

    for (int rr = 0; rr < ROWS; ++rr) {
        float* row = wgt + rr * L;
        u32 prefix = 0;
        int want = top;
        for (int by = 3; by >= 0; --by) {
            hist[tid] = 0;
            __syncthreads();
            const int sh = by * 8;
            for (int l = tid; l < L; l += 256) {
                const u32 u = f2s(row[l]);
                const bool ok = (by == 3) || (((u ^ prefix) >> (sh + 8)) == 0);
                if (ok) atomicAdd(&hist[(u >> sh) & 255u], 1u);
            }
            __syncthreads();
            if (tid == 0) {
                int cum = 0;
                u32 dsel = 0;
                for (int d = 255; d >= 0; --d) {
                    const int c = (int)hist[d];
                    if (cum + c >= want) { dsel = (u32)d; break; }
                    cum += c;
                }
                bcu[0] = dsel;
                bcu[1] = (u32)(want - cum);
            }
            __syncthreads();
            prefix |= bcu[0] << sh;
            want = (int)bcu[1];
            __syncthreads();
        }
        const u32 T = prefix;    // key of the top-th largest value
        const int wantT = want;  // # elements == T the reference includes (>=1)

        float mx = -3.4e38f;
        for (int l = tid; l < L; l += 256) mx = fmaxf(mx, row[l]);
        red[tid] = mx;
        __syncthreads();
        for (int s = 128; s > 0; s >>= 1) {
            if (tid < s) red[tid] = fmaxf(red[tid], red[tid + s]);
            __syncthreads();
        }
        const float M = red[0];
        __syncthreads();

        float ps = 0.f;
        for (int l = tid; l < L; l += 256) {
            const float v = row[l];
            if (f2s(v) > T) ps += __expf(fminf(v - M, 0.f));
        }
        red[tid] = ps;
        __syncthreads();
        for (int s = 128; s > 0; s >>= 1) {
            if (tid < s) red[tid] += red[tid + s];
            __syncthreads();
        }
        const float total = red[0] + (float)wantT * __expf(fminf(s2f(T) - M, 0.f));
        const float inv = 1.f / fmaxf(total, 1e-30f);
        __syncthreads();
        for (int l = tid; l < L; l += 256) {
            const float v = row[l];
            row[l] = (f2s(v) >= T) ? __expf(fminf(v - M, 0.f)) * inv : 0.f;
        }
        __syncthreads();
    }

    // P.V : wave rr = query row, lane d; zero-weight skip is wave-uniform
    const int rr = tid >> 6, d = tid & 63;
    const float* wrow = wgt + rr * L;
    float acc = 0.f;
    int l = 0;
    for (; l < L1; ++l) {
        const float w = wrow[l];
        if (w != 0.f) acc += w * V1[base1 + (size_t)l * 64 + d];
    }
    const int e2 = L1 + v2_rows;
    for (; l < e2 && l < L; ++l) {
        const float w = wrow[l];
        if (w != 0.f) acc += w * V2[v2base + (size_t)(l - L1) * 64 + d];
    }
    for (; l < L; ++l) {
        const float w = wrow[l];
        if (w != 0.f) acc += w * V3[v3base + (size_t)(l - e2) * 64 + d];
    }
    const int token = row_start + r0 + rr;
    aob[(((size_t)b) * NTOK + token) * CD + h * 64 + d] = acc;
}

// ---------------- proj routing coefficients ----------------
__global__ __launch_bounds__(256) void coef_kernel(const float* __restrict__ aob,
                                                   const float* __restrict__ rW,
                                                   const float* __restrict__ Ap,
                                                   float* __restrict__ coef) {
    __shared__ float rl[8][4];
    __shared__ float rw[8][4];
    const int slot = threadIdx.x >> 5, lane = threadIdx.x & 31;
    const int m = blockIdx.x * 8 + slot;  // 400 * 8 = 3200
    const float* xr = aob + (size_t)m * CD;
    const float z = dot768_ff(xr, Ap + (size_t)lane * CD);
    if (lane < 4) rl[slot][lane] = dot768_ff(xr, rW + (size_t)lane * CD);
    __syncthreads();
    if (lane == 0) {
        const float mx = fmaxf(fmaxf(rl[slot][0], rl[slot][1]), fmaxf(rl[slot][2], rl[slot][3]));
        const float e0 = __expf(rl[slot][0] - mx), e1 = __expf(rl[slot][1] - mx);
        const float e2 = __expf(rl[slot][2] - mx), e3 = __expf(rl[slot][3] - mx);
        const float is = 1.f / (e0 + e1 + e2 + e3);
        rw[slot][0] = e0 * is; rw[slot][1] = e1 * is; rw[slot][2] = e2 * is; rw[slot][3] = e3 * is;
    }
    __syncthreads();
    coef[(size_t)m * 32 + lane] = rw[slot][lane >> 3] * z * 0.125f;
}

// ---------------- proj GEMM, race-free in-place on io (d_out `out` region) ----------------
// Block owns 16 rows: copies them to LDS, then computes & overwrites only those rows.
__global__ __launch_bounds__(256) void proj_kernel(float* __restrict__ io,
                                                   const float* __restrict__ W,
                                                   const float* __restrict__ bias,
                                                   const float* __restrict__ coef,
                                                   const float* __restrict__ Bp) {
    __shared__ __align__(16) float Apan[16 * CD];  // 49152 B
    __shared__ float Bs[16 * 68];                  // 4352 B
    const int tid = threadIdx.x;
    const int m0 = blockIdx.x * 16;
    for (int t = tid; t < 16 * CD / 4; t += 256)
        ((float4*)Apan)[t] = ((const float4*)(io + (size_t)m0 * CD))[t];
    __syncthreads();
    const int tx = tid & 15, ty = tid >> 4;
    const int lr = tid >> 2, lk = (tid & 3) * 4;
    for (int j0 = 0; j0 < CD; j0 += 64) {
        float acc4[4] = {};
        for (int k0 = 0; k0 < CD; k0 += 16) {
            const float4 tb = *(const float4*)&W[(size_t)(j0 + lr) * CD + k0 + lk];
            __syncthreads();
            Bs[(lk + 0) * 68 + lr] = tb.x;
            Bs[(lk + 1) * 68 + lr] = tb.y;
            Bs[(lk + 2) * 68 + lr] = tb.z;
            Bs[(lk + 3) * 68 + lr] = tb.w;
            __syncthreads();
#pragma unroll
            for (int kk = 0; kk < 16; ++kk) {
                const float a0 = Apan[ty * CD + k0 + kk];
                const float4 b4 = *(const float4*)&Bs[kk * 68 + tx * 4];
                acc4[0] += a0 * b4.x; acc4[1] += a0 * b4.y;
                acc4[2] += a0 * b4.z; acc4[3] += a0 * b4.w;
            }
        }
        const int m = m0 + ty;
        const float* cf = coef + (size_t)m * 32;
#pragma unroll
        for (int jj = 0; jj < 4; ++jj) {
            const int j = j0 + tx * 4 + jj;
            float lora = 0.f;
#pragma unroll
            for (int e = 0; e < 4; ++e) {
                const float* bl = Bp + (size_t)(e * CD + j) * 8;
#pragma unroll
                for (int r = 0; r < 8; ++r) lora += cf[e * 8 + r] * bl[r];
            }
            io[(size_t)m * CD + j] = acc4[jj] + bias[j] + lora;
        }
    }
}

extern "C" void kernel_launch(void* const* d_in, const int* in_sizes, int n_in,
                              void* d_out, int out_size, void* d_ws, size_t ws_size,
                              hipStream_t stream) {
    const float* x = (const float*)d_in[0];
    const float* id_total = (const float*)d_in[1];
    const float* mem_k = (const float*)d_in[2];
    const float* mem_v = (const float*)d_in[3];
    const float* W_qkv = (const float*)d_in[4];
    const float* b_qkv = (const float*)d_in[5];
    const float* A_qkv = (const float*)d_in[6];
    const float* B_qkv = (const float*)d_in[7];
    const float* W_proj = (const float*)d_in[8];
    const float* b_proj = (const float*)d_in[9];
    const float* routeW_proj = (const float*)d_in[10];
    const float* A_proj = (const float*)d_in[11];
    const float* B_proj = (const float*)d_in[12];
    const float* W_idk = (const float*)d_in[13];
    const float* b_idk = (const float*)d_in[14];
    const float* A_idk = (const float*)d_in[16];
    const float* B_idk = (const float*)d_in[17];
    const float* W_idv = (const float*)d_in[18];
    const float* b_idv = (const float*)d_in[19];
    const float* A_idv = (const float*)d_in[21];
    const float* B_idv = (const float*)d_in[22];
    // d_in[15]/d_in[20] (single-expert route weights), d_in[23] (id_add) unused.

    float* io = (float*)d_out;                    // 2457600: aob then final out
    float* o_km = io + (size_t)BN * NTOK * CD;    // 884736: k_m (& mem-attn K)
    float* o_vm = o_km + (size_t)BN * NH * NM * HD;  // 884736: ID_V -> v_m (& attn V)

    // workspace: 26,798,080 bytes total (f32)
    float* qb = (float*)d_ws;        // 2457600 (B,H,1600,64), pre-scaled
    float* kb = qb + 2457600;        // 2457600 raw k
    float* vtail = kb + 2457600;     // 1572864 (B,H,NS,64) v rows 576..1599
    float* zq = vtail + 1572864;     // 76800
    float* zik = zq + 76800;         // 9216
    float* ziv = zik + 9216;         // 9216
    float* IDK = ziv + 9216;         // 13824
    float* coef = IDK + 13824;       // 102400

    zid_kernel<<<72, 256, 0, stream>>>(id_total, A_idk, A_idv, zik, ziv);
    idk_kernel<<<54, 256, 0, stream>>>(id_total, W_idk, b_idk, zik, B_idk, IDK);
    z24_kernel<<<300, 256, 0, stream>>>(x, A_qkv, zq);
    idv_kernel<<<dim3(12, 18), 256, 0, stream>>>(id_total, W_idv, b_idv, ziv, B_idv, o_vm);
    qkv_kernel<<<dim3(36, 50), 256, 0, stream>>>(x, W_qkv, b_qkv, zq, B_qkv, IDK,
                                                 qb, kb, o_km, o_vm, vtail);

    // memory attention: L=576, top=288, K=o_km, V=o_vm
    attn_kernel<<<dim3(NM / ROWS, BN * NH), 256, (776 + ROWS * NM) * 4, stream>>>(
        qb, qb, o_km, qb, o_vm, o_vm, io, 0, NM, NM / 2, 0, NM, NM, NM);
    // seq attention: L=3200, top=1600, K=[mem_k|kb], V=[mem_v|o_vm|vtail]
    attn_kernel<<<dim3(NS / ROWS, BN * NH), 256, (776 + ROWS * 2 * NTOK) * 4, stream>>>(
        qb, mem_k, kb, mem_v, o_vm, vtail, io, NTOK, 2 * NTOK, NTOK, NM, NTOK, NM, NS);

    coef_kernel<<<400, 256, 0, stream>>>(io, routeW_proj, A_proj, coef);
    proj_kernel<<<200, 256, 0, stream>>>(io, W_proj, b_proj, coef, B_proj);
}

// Round 5
// 3731.755 us; speedup vs baseline: 1.9692x; 1.9692x over previous
//
#include <hip/hip_runtime.h>
#include <hip/hip_bf16.h>

#define BN 2
#define NH 12
#define NTOK 1600
#define NM 576
#define NS 1024
#define CD 768
#define HD 64

typedef unsigned short u16;
typedef unsigned int u32;

__device__ __forceinline__ float fbits(u32 u) { return __uint_as_float(u); }
__device__ __forceinline__ u16 f2b(float f) {  // RNE f32->bf16
    u32 u = __float_as_uint(f);
    u32 r = u + 0x7FFFu + ((u >> 16) & 1u);
    return (u16)(r >> 16);
}
__device__ __forceinline__ float b2f(u16 s) { return fbits(((u32)s) << 16); }
__device__ __forceinline__ u32 flip16(u32 u) {  // order-preserving bf16-bits -> u16 key
    return (u & 0x8000u) ? (0xFFFFu & ~u) : (u | 0x8000u);
}
__device__ __forceinline__ float key2f(u32 k) {
    u32 b = (k & 0x8000u) ? (k & 0x7FFFu) : (0xFFFFu & ~k);
    return fbits(b << 16);
}

__device__ __forceinline__ float dot768_ff(const float* __restrict__ a,
                                           const float* __restrict__ b) {
    float s = 0.f;
    for (int c = 0; c < CD; c += 4) {
        float4 fa = *(const float4*)(a + c);
        float4 fb = *(const float4*)(b + c);
        s += fa.x * fb.x + fa.y * fb.y + fa.z * fb.z + fa.w * fb.w;
    }
    return s;
}

// ---------------- small LoRA z kernels ----------------

__global__ __launch_bounds__(256) void z24_kernel(const float* __restrict__ x,
                                                  const float* __restrict__ Aq,
                                                  float* __restrict__ z) {
    int idx = blockIdx.x * 256 + threadIdx.x;  // exactly 76800
    int m = idx / 24, q = idx % 24;
    z[idx] = dot768_ff(x + (size_t)m * CD, Aq + (size_t)q * CD);
}

__global__ __launch_bounds__(256) void zid_kernel(const float* __restrict__ id,
                                                  const float* __restrict__ Ak,
                                                  const float* __restrict__ Av,
                                                  float* __restrict__ zk, float* __restrict__ zv) {
    int idx = blockIdx.x * 256 + threadIdx.x;  // exactly 18432
    int m = idx >> 4, q = idx & 15;
    const float* a = (q < 8) ? (Ak + (size_t)q * CD) : (Av + (size_t)(q - 8) * CD);
    float v = dot768_ff(id + (size_t)m * CD, a);
    if (q < 8) zk[m * 8 + q] = v; else zv[m * 8 + q - 8] = v;
}

__global__ __launch_bounds__(256) void idk_kernel(const float* __restrict__ id,
                                                  const float* __restrict__ Wk,
                                                  const float* __restrict__ bk,
                                                  const float* __restrict__ zk,
                                                  const float* __restrict__ Bk,
                                                  float* __restrict__ IDK) {
    int idx = blockIdx.x * 256 + threadIdx.x;  // exactly 13824
    int m = idx / NH, h = idx % NH;
    float v = dot768_ff(id + (size_t)m * CD, Wk + (size_t)h * CD) + bk[h];
    float lo = 0.f;
#pragma unroll
    for (int r = 0; r < 8; ++r) lo += zk[m * 8 + r] * Bk[h * 8 + r];
    IDK[idx] = v + 0.125f * lo;
}

// ---------------- GEMM core macro (64x64 tile, 256 thr, 4x4 micro), f32 ----------------

#define GEMM_CORE(Aexpr, Wexpr)                                                 \
    float acc[4][4] = {};                                                       \
    {                                                                           \
        const int lr = tid >> 2, lk = (tid & 3) * 4;                            \
        for (int k0 = 0; k0 < CD; k0 += 16) {                                   \
            const float4 ta = *(const float4*)&(Aexpr)[(size_t)(m0 + lr) * CD + k0 + lk]; \
            const float4 tb = *(const float4*)&(Wexpr)[(size_t)(j0 + lr) * CD + k0 + lk]; \
            __syncthreads();                                                    \
            As[(lk + 0) * 68 + lr] = ta.x;                                      \
            As[(lk + 1) * 68 + lr] = ta.y;                                      \
            As[(lk + 2) * 68 + lr] = ta.z;                                      \
            As[(lk + 3) * 68 + lr] = ta.w;                                      \
            Bs[(lk + 0) * 68 + lr] = tb.x;                                      \
            Bs[(lk + 1) * 68 + lr] = tb.y;                                      \
            Bs[(lk + 2) * 68 + lr] = tb.z;                                      \
            Bs[(lk + 3) * 68 + lr] = tb.w;                                      \
            __syncthreads();                                                    \
            _Pragma("unroll")                                                   \
            for (int kk = 0; kk < 16; ++kk) {                                   \
                const float4 a4 = *(const float4*)&As[kk * 68 + ty * 4];        \
                const float4 b4 = *(const float4*)&Bs[kk * 68 + tx * 4];        \
                const float aa[4] = {a4.x, a4.y, a4.z, a4.w};                   \
                const float bb[4] = {b4.x, b4.y, b4.z, b4.w};                   \
                _Pragma("unroll")                                               \
                for (int i = 0; i < 4; ++i)                                     \
                    _Pragma("unroll")                                           \
                    for (int j = 0; j < 4; ++j) acc[i][j] += aa[i] * bb[j];     \
            }                                                                   \
        }                                                                       \
    }

// ---------------- ID_V GEMM: scatter into o_vm (d_out) ----------------
__global__ __launch_bounds__(256) void idv_kernel(const float* __restrict__ A,
                                                  const float* __restrict__ Bw,
                                                  const float* __restrict__ bias,
                                                  const float* __restrict__ zv,
                                                  const float* __restrict__ Bl,
                                                  float* __restrict__ ovm) {
    __shared__ float As[16 * 68];
    __shared__ float Bs[16 * 68];
    const int tid = threadIdx.x;
    const int tx = tid & 15, ty = tid >> 4;
    const int j0 = blockIdx.x * 64, m0 = blockIdx.y * 64;
    GEMM_CORE(A, Bw)
#pragma unroll
    for (int i = 0; i < 4; ++i) {
        const int m = m0 + ty * 4 + i;
        const int b = m / NM, n = m - (m / NM) * NM;
        const float* zr = zv + (size_t)m * 8;
#pragma unroll
        for (int jj = 0; jj < 4; ++jj) {
            const int j = j0 + tx * 4 + jj;
            const int h = j >> 6, d = j & 63;
            float lora = 0.f;
            const float* bl = Bl + (size_t)j * 8;
#pragma unroll
            for (int r = 0; r < 8; ++r) lora += zr[r] * bl[r];
            ovm[(((size_t)(b * NH + h)) * NM + n) * 64 + d] =
                acc[i][jj] + bias[j] + 0.125f * lora;
        }
    }
}

// ---------------- qkv GEMM: scatter q/k/v + fuse gate & ID_V add ----------------
__global__ __launch_bounds__(256) void qkv_kernel(const float* __restrict__ A,
                                                  const float* __restrict__ Bw,
                                                  const float* __restrict__ bias,
                                                  const float* __restrict__ zq,
                                                  const float* __restrict__ Bl,
                                                  const float* __restrict__ IDK,
                                                  float* __restrict__ qb,
                                                  float* __restrict__ kb,
                                                  float* __restrict__ okm,
                                                  float* __restrict__ ovm,
                                                  float* __restrict__ vtail) {
    __shared__ float As[16 * 68];
    __shared__ float Bs[16 * 68];
    const int tid = threadIdx.x;
    const int tx = tid & 15, ty = tid >> 4;
    const int j0 = blockIdx.x * 64, m0 = blockIdx.y * 64;
    GEMM_CORE(A, Bw)
    const int g = j0 / CD;
    const int hq = (j0 % CD) >> 6;
#pragma unroll
    for (int i = 0; i < 4; ++i) {
        const int m = m0 + ty * 4 + i;
        const int b = m / NTOK, n = m - (m / NTOK) * NTOK;
        float gate = 0.f;
        if (g == 1 && n < NM) gate = 1.f + tanhf(IDK[(b * NM + n) * NH + hq]);
        const float* zr = zq + (size_t)m * 24 + g * 8;
#pragma unroll
        for (int jj = 0; jj < 4; ++jj) {
            const int d = tx * 4 + jj;
            const int c = hq * 64 + d;
            const int j = j0 + tx * 4 + jj;
            float lora = 0.f;
            const float* bl = Bl + (size_t)(g * CD + c) * 8;
#pragma unroll
            for (int r = 0; r < 8; ++r) lora += zr[r] * bl[r];
            float val = acc[i][jj] + bias[j] + 0.125f * lora;
            const size_t o = (((size_t)(b * NH + hq)) * NTOK + n) * 64 + d;
            const size_t om = (((size_t)(b * NH + hq)) * NM + n) * 64 + d;
            if (g == 0) {
                qb[o] = val * 0.125f;
            } else if (g == 1) {
                kb[o] = val;
                if (n < NM) okm[om] = val * gate;
            } else {
                if (n < NM) {
                    ovm[om] = val + ovm[om];
                } else {
                    vtail[(((size_t)(b * NH + hq)) * NS + (n - NM)) * 64 + d] = val;
                }
            }
        }
    }
}

// ---------------- v5 top-k attention: tiled, bf16 logits, parallel radix ----------------
// 512 threads, 8 query rows/block. LDS: wgt bf16[8][L] (later PT[L][8]) |
// stage bf16[512][68] | qs f32[512] | hist u32[8][256] | bcu u32[8][4].
template <bool SEQ>
__global__ __launch_bounds__(512) void attn5_kernel(const float* __restrict__ qb,
                                                    const float* __restrict__ K1,
                                                    const float* __restrict__ K2,
                                                    const float* __restrict__ V1,
                                                    const float* __restrict__ V2,
                                                    const float* __restrict__ V3,
                                                    float* __restrict__ aob,
                                                    int L, int top, int row_start) {
    extern __shared__ __align__(16) u16 smem[];
    u16* wgt = smem;                       // 8*L bf16  (becomes PT[L][8])
    u16* stg = smem + 8 * L;               // 512*68 bf16
    float* qs = (float*)(stg + 512 * 68);  // 512 f32
    u32* hist = (u32*)(qs + 512);          // 8*256
    u32* bcu = hist + 2048;                // 8*4

    const int tid = threadIdx.x;
    const int bh = blockIdx.y;
    const int b = bh / NH, h = bh - b * NH;
    const int r0blk = row_start + blockIdx.x * 8;
    const int NP = (L + 511) >> 9;  // passes of 512 keys

    qs[tid] = qb[(((size_t)bh) * NTOK + r0blk + (tid >> 6)) * 64 + (tid & 63)];

    // ---------- phase 1: logits ----------
    {
        const int kq = tid & 127;
        const int rr = (tid >> 7) * 2;  // rows rr, rr+1
        const float* q0 = qs + rr * 64;
        const float* q1 = qs + rr * 64 + 64;
        for (int pass = 0; pass < NP; ++pass) {
            __syncthreads();
            // stage 512 keys of K (8 sub-tiles of 64, segment-uniform)
            for (int sub = 0; sub < 8; ++sub) {
                const int l0 = pass * 512 + sub * 64;
                const int krow = tid >> 3;           // 0..63
                const int off = (tid & 7) * 8;       // 0..56
                float4 a = {0, 0, 0, 0}, b4 = {0, 0, 0, 0};
                if (l0 + krow < L) {
                    const float* src;
                    if (SEQ) {
                        src = (l0 < NTOK) ? K1 + ((size_t)bh * NTOK + l0) * 64
                                          : K2 + ((size_t)bh * NTOK + (l0 - NTOK)) * 64;
                    } else {
                        src = K1 + ((size_t)bh * NM + l0) * 64;
                    }
                    src += (size_t)krow * 64 + off;
                    a = *(const float4*)src;
                    b4 = *(const float4*)(src + 4);
                }
                u16* dst = stg + (sub * 64 + krow) * 68 + off;
                ((uint2*)dst)[0] = make_uint2((u32)f2b(a.x) | ((u32)f2b(a.y) << 16),
                                              (u32)f2b(a.z) | ((u32)f2b(a.w) << 16));
                ((uint2*)dst)[1] = make_uint2((u32)f2b(b4.x) | ((u32)f2b(b4.y) << 16),
                                              (u32)f2b(b4.z) | ((u32)f2b(b4.w) << 16));
            }
            __syncthreads();
            float acc[2][4] = {};
#pragma unroll 4
            for (int c = 0; c < 16; ++c) {
                const float4 qa = *(const float4*)(q0 + c * 4);
                const float4 qc = *(const float4*)(q1 + c * 4);
#pragma unroll
                for (int p = 0; p < 4; ++p) {
                    const uint2 kk = *(const uint2*)(stg + (kq + 128 * p) * 68 + c * 4);
                    const float k0 = fbits(kk.x << 16), k1 = fbits(kk.x & 0xffff0000u);
                    const float k2 = fbits(kk.y << 16), k3 = fbits(kk.y & 0xffff0000u);
                    acc[0][p] += qa.x * k0 + qa.y * k1 + qa.z * k2 + qa.w * k3;
                    acc[1][p] += qc.x * k0 + qc.y * k1 + qc.z * k2 + qc.w * k3;
                }
            }
#pragma unroll
            for (int p = 0; p < 4; ++p) {
                const int l = pass * 512 + kq + 128 * p;
                if (l < L) {
                    wgt[rr * L + l] = f2b(acc[0][p]);
                    wgt[(rr + 1) * L + l] = f2b(acc[1][p]);
                }
            }
        }
        __syncthreads();
    }

    // ---------- phase 2: per-row top-k select (wave r <-> row r), 2-round radix ----------
    const int wv = tid >> 6, lane = tid & 63;
    u32 T16;
    int wantT;
    float Mx, inv;
    {
        const u16* row = wgt + wv * L;
        int want = top;
        u32 sel1 = 0, sel2 = 0;
        for (int round = 0; round < 2; ++round) {
#pragma unroll
            for (int i = 0; i < 4; ++i) hist[wv * 256 + lane + 64 * i] = 0;
            __syncthreads();
            for (int l = lane; l < L; l += 64) {
                const u32 k = flip16((u32)row[l]);
                if (round == 0) {
                    atomicAdd(&hist[wv * 256 + (k >> 8)], 1u);
                } else if ((k >> 8) == sel1) {
                    atomicAdd(&hist[wv * 256 + (k & 255u)], 1u);
                }
            }
            __syncthreads();
            u32 hh[4];
#pragma unroll
            for (int j = 0; j < 4; ++j) hh[j] = hist[wv * 256 + 4 * lane + j];
            u32 s = hh[0] + hh[1] + hh[2] + hh[3];
            u32 sum = s;
#pragma unroll
            for (int off = 1; off < 64; off <<= 1) {
                u32 t = __shfl_down(sum, off);
                if (lane + off < 64) sum += t;
            }
            int cnt = (int)(sum - s);  // count strictly above this lane's bins
            for (int j = 3; j >= 0; --j) {
                const int c = (int)hh[j];
                if (cnt < want && cnt + c >= want) {
                    bcu[wv * 4] = (u32)(4 * lane + j);
                    bcu[wv * 4 + 1] = (u32)(want - cnt);
                }
                cnt += c;
            }
            __syncthreads();
            if (round == 0) sel1 = bcu[wv * 4];
            else sel2 = bcu[wv * 4];
            want = (int)bcu[wv * 4 + 1];
            __syncthreads();
        }
        T16 = (sel1 << 8) | sel2;
        wantT = want;

        float mx = -3.4e38f;
        for (int l = lane; l < L; l += 64) mx = fmaxf(mx, b2f(row[l]));
#pragma unroll
        for (int off = 1; off < 64; off <<= 1) mx = fmaxf(mx, __shfl_xor(mx, off));
        Mx = mx;
        float ps = 0.f;
        for (int l = lane; l < L; l += 64) {
            const u16 u = row[l];
            if (flip16((u32)u) > T16) ps += __expf(fminf(b2f(u) - Mx, 0.f));
        }
#pragma unroll
        for (int off = 1; off < 64; off <<= 1) ps += __shfl_xor(ps, off);
        const float total = ps + (float)wantT * __expf(fminf(key2f(T16) - Mx, 0.f));
        inv = 1.f / fmaxf(total, 1e-30f);
    }

    // ---------- phase 3: normalize into registers, transpose to PT[L][8] ----------
    {
        u16 wreg[50];
        const int cnt = L >> 6;  // L multiple of 64
        for (int i = 0, l = lane; i < cnt; ++i, l += 64) {
            const u16 u = wgt[wv * L + l];
            const float w = (flip16((u32)u) >= T16)
                                ? __expf(fminf(b2f(u) - Mx, 0.f)) * inv : 0.f;
            wreg[i] = f2b(w);
        }
        __syncthreads();  // all reads of wgt done
        for (int i = 0, l = lane; i < cnt; ++i, l += 64) wgt[l * 8 + wv] = wreg[i];
        __syncthreads();
    }

    // ---------- phase 4: P.V (thread = 2 rows x 4 dims, wave = 64-key partition) ----------
    {
        const int part = wv;
        const int rp = (lane >> 4) & 3;  // rows 2rp, 2rp+1
        const int dq = lane & 15;        // dims 4dq..4dq+3
        float acc[2][4] = {};
        for (int pass = 0; pass < NP; ++pass) {
            __syncthreads();
            for (int sub = 0; sub < 8; ++sub) {
                const int l0 = pass * 512 + sub * 64;
                const int krow = tid >> 3;
                const int off = (tid & 7) * 8;
                float4 a = {0, 0, 0, 0}, b4 = {0, 0, 0, 0};
                if (l0 + krow < L) {
                    const float* src;
                    if (SEQ) {
                        if (l0 < NTOK) src = V1 + ((size_t)bh * NTOK + l0) * 64;
                        else if (l0 < NTOK + NM) src = V2 + ((size_t)bh * NM + (l0 - NTOK)) * 64;
                        else src = V3 + ((size_t)bh * NS + (l0 - NTOK - NM)) * 64;
                    } else {
                        src = V2 + ((size_t)bh * NM + l0) * 64;
                    }
                    src += (size_t)krow * 64 + off;
                    a = *(const float4*)src;
                    b4 = *(const float4*)(src + 4);
                }
                u16* dst = stg + (sub * 64 + krow) * 68 + off;
                ((uint2*)dst)[0] = make_uint2((u32)f2b(a.x) | ((u32)f2b(a.y) << 16),
                                              (u32)f2b(a.z) | ((u32)f2b(a.w) << 16));
                ((uint2*)dst)[1] = make_uint2((u32)f2b(b4.x) | ((u32)f2b(b4.y) << 16),
                                              (u32)f2b(b4.z) | ((u32)f2b(b4.w) << 16));
            }
            __syncthreads();
            const int rem = L - pass * 512 - part * 64;
            const int iMax = rem < 64 ? (rem < 0 ? 0 : rem) : 64;
            for (int i = 0; i < iMax; ++i) {
                const int key = part * 64 + i;
                const int labs = pass * 512 + key;
                const u32 wpair = *(const u32*)(wgt + labs * 8 + 2 * rp);
                if (wpair != 0u) {
                    const float w0 = fbits(wpair << 16), w1 = fbits(wpair & 0xffff0000u);
                    const uint2 vv = *(const uint2*)(stg + key * 68 + dq * 4);
                    const float v0 = fbits(vv.x << 16), v1 = fbits(vv.x & 0xffff0000u);
                    const float v2 = fbits(vv.y << 16), v3 = fbits(vv.y & 0xffff0000u);
                    acc[0][0] += w0 * v0; acc[0][1] += w0 * v1;
                    acc[0][2] += w0 * v2; acc[0][3] += w0 * v3;
                    acc[1][0] += w1 * v0; acc[1][1] += w1 * v1;
                    acc[1][2] += w1 * v2; acc[1][3] += w1 * v3;
                }
            }
        }
        __syncthreads();  // stage free -> reuse as reduction buffer
        float* red = (float*)stg;  // [8 part][8 row][64 dim]
#pragma unroll
        for (int ri = 0; ri < 2; ++ri)
#pragma unroll
            for (int di = 0; di < 4; ++di)
                red[((part * 8) + 2 * rp + ri) * 64 + dq * 4 + di] = acc[ri][di];
        __syncthreads();
        const int r = tid >> 6, d = tid & 63;
        float s = 0.f;
#pragma unroll
        for (int p = 0; p < 8; ++p) s += red[(p * 8 + r) * 64 + d];
        const int token = r0blk + r;
        aob[(((size_t)b) * NTOK + token) * CD + h * 64 + d] = s;
    }
}

// ---------------- proj routing coefficients ----------------
__global__ __launch_bounds__(256) void coef_kernel(const float* __restrict__ aob,
                                                   const float* __restrict__ rW,
                                                   const float* __restrict__ Ap,
                                                   float* __restrict__ coef) {
    __shared__ float rl[8][4];
    __shared__ float rw[8][4];
    const int slot = threadIdx.x >> 5, lane = threadIdx.x & 31;
    const int m = blockIdx.x * 8 + slot;  // 400 * 8 = 3200
    const float* xr = aob + (size_t)m * CD;
    const float z = dot768_ff(xr, Ap + (size_t)lane * CD);
    if (lane < 4) rl[slot][lane] = dot768_ff(xr, rW + (size_t)lane * CD);
    __syncthreads();
    if (lane == 0) {
        const float mx = fmaxf(fmaxf(rl[slot][0], rl[slot][1]), fmaxf(rl[slot][2], rl[slot][3]));
        const float e0 = __expf(rl[slot][0] - mx), e1 = __expf(rl[slot][1] - mx);
        const float e2 = __expf(rl[slot][2] - mx), e3 = __expf(rl[slot][3] - mx);
        const float is = 1.f / (e0 + e1 + e2 + e3);
        rw[slot][0] = e0 * is; rw[slot][1] = e1 * is; rw[slot][2] = e2 * is; rw[slot][3] = e3 * is;
    }
    __syncthreads();
    coef[(size_t)m * 32 + lane] = rw[slot][lane >> 3] * z * 0.125f;
}

// ---------------- proj GEMM, race-free in-place on io ----------------
__global__ __launch_bounds__(256) void proj_kernel(float* __restrict__ io,
                                                   const float* __restrict__ W,
                                                   const float* __restrict__ bias,
                                                   const float* __restrict__ coef,
                                                   const float* __restrict__ Bp) {
    __shared__ __align__(16) float Apan[16 * CD];
    __shared__ float Bs[16 * 68];
    const int tid = threadIdx.x;
    const int m0 = blockIdx.x * 16;
    for (int t = tid; t < 16 * CD / 4; t += 256)
        ((float4*)Apan)[t] = ((const float4*)(io + (size_t)m0 * CD))[t];
    __syncthreads();
    const int tx = tid & 15, ty = tid >> 4;
    const int lr = tid >> 2, lk = (tid & 3) * 4;
    for (int j0 = 0; j0 < CD; j0 += 64) {
        float acc4[4] = {};
        for (int k0 = 0; k0 < CD; k0 += 16) {
            const float4 tb = *(const float4*)&W[(size_t)(j0 + lr) * CD + k0 + lk];
            __syncthreads();
            Bs[(lk + 0) * 68 + lr] = tb.x;
            Bs[(lk + 1) * 68 + lr] = tb.y;
            Bs[(lk + 2) * 68 + lr] = tb.z;
            Bs[(lk + 3) * 68 + lr] = tb.w;
            __syncthreads();
#pragma unroll
            for (int kk = 0; kk < 16; ++kk) {
                const float a0 = Apan[ty * CD + k0 + kk];
                const float4 b4 = *(const float4*)&Bs[kk * 68 + tx * 4];
                acc4[0] += a0 * b4.x; acc4[1] += a0 * b4.y;
                acc4[2] += a0 * b4.z; acc4[3] += a0 * b4.w;
            }
        }
        const int m = m0 + ty;
        const float* cf = coef + (size_t)m * 32;
#pragma unroll
        for (int jj = 0; jj < 4; ++jj) {
            const int j = j0 + tx * 4 + jj;
            float lora = 0.f;
#pragma unroll
            for (int e = 0; e < 4; ++e) {
                const float* bl = Bp + (size_t)(e * CD + j) * 8;
#pragma unroll
                for (int r = 0; r < 8; ++r) lora += cf[e * 8 + r] * bl[r];
            }
            io[(size_t)m * CD + j] = acc4[jj] + bias[j] + lora;
        }
    }
}

extern "C" void kernel_launch(void* const* d_in, const int* in_sizes, int n_in,
                              void* d_out, int out_size, void* d_ws, size_t ws_size,
                              hipStream_t stream) {
    const float* x = (const float*)d_in[0];
    const float* id_total = (const float*)d_in[1];
    const float* mem_k = (const float*)d_in[2];
    const float* mem_v = (const float*)d_in[3];
    const float* W_qkv = (const float*)d_in[4];
    const float* b_qkv = (const float*)d_in[5];
    const float* A_qkv = (const float*)d_in[6];
    const float* B_qkv = (const float*)d_in[7];
    const float* W_proj = (const float*)d_in[8];
    const float* b_proj = (const float*)d_in[9];
    const float* routeW_proj = (const float*)d_in[10];
    const float* A_proj = (const float*)d_in[11];
    const float* B_proj = (const float*)d_in[12];
    const float* W_idk = (const float*)d_in[13];
    const float* b_idk = (const float*)d_in[14];
    const float* A_idk = (const float*)d_in[16];
    const float* B_idk = (const float*)d_in[17];
    const float* W_idv = (const float*)d_in[18];
    const float* b_idv = (const float*)d_in[19];
    const float* A_idv = (const float*)d_in[21];
    const float* B_idv = (const float*)d_in[22];

    float* io = (float*)d_out;
    float* o_km = io + (size_t)BN * NTOK * CD;
    float* o_vm = o_km + (size_t)BN * NH * NM * HD;

    float* qb = (float*)d_ws;
    float* kb = qb + 2457600;
    float* vtail = kb + 2457600;
    float* zq = vtail + 1572864;
    float* zik = zq + 76800;
    float* ziv = zik + 9216;
    float* IDK = ziv + 9216;
    float* coef = IDK + 13824;

    const int smem_seq = (8 * 3200 + 512 * 68) * 2 + 512 * 4 + (8 * 256 + 32) * 4;  // 131200
    const int smem_mem = (8 * 576 + 512 * 68) * 2 + 512 * 4 + (8 * 256 + 32) * 4;   // 89216
    static_assert(smem_seq <= 160 * 1024, "LDS");
    hipFuncSetAttribute((const void*)attn5_kernel<true>,
                        hipFuncAttributeMaxDynamicSharedMemorySize, smem_seq);
    hipFuncSetAttribute((const void*)attn5_kernel<false>,
                        hipFuncAttributeMaxDynamicSharedMemorySize, smem_seq);

    zid_kernel<<<72, 256, 0, stream>>>(id_total, A_idk, A_idv, zik, ziv);
    idk_kernel<<<54, 256, 0, stream>>>(id_total, W_idk, b_idk, zik, B_idk, IDK);
    z24_kernel<<<300, 256, 0, stream>>>(x, A_qkv, zq);
    idv_kernel<<<dim3(12, 18), 256, 0, stream>>>(id_total, W_idv, b_idv, ziv, B_idv, o_vm);
    qkv_kernel<<<dim3(36, 50), 256, 0, stream>>>(x, W_qkv, b_qkv, zq, B_qkv, IDK,
                                                 qb, kb, o_km, o_vm, vtail);

    // memory attention: L=576, top=288, K=o_km, V=o_vm
    attn5_kernel<false><<<dim3(NM / 8, BN * NH), 512, smem_mem, stream>>>(
        qb, o_km, nullptr, nullptr, o_vm, nullptr, io, NM, NM / 2, 0);
    // seq attention: L=3200, top=1600, K=[mem_k|kb], V=[mem_v|o_vm|vtail]
    attn5_kernel<true><<<dim3(NS / 8, BN * NH), 512, smem_seq, stream>>>(
        qb, mem_k, kb, mem_v, o_vm, vtail, io, 2 * NTOK, NTOK, NM);

    coef_kernel<<<400, 256, 0, stream>>>(io, routeW_proj, A_proj, coef);
    proj_kernel<<<200, 256, 0, stream>>>(io, W_proj, b_proj, coef, B_proj);
}

// Round 6
// 1319.378 us; speedup vs baseline: 5.5698x; 2.8284x over previous
//
#include <hip/hip_runtime.h>
#include <hip/hip_bf16.h>

#define BN 2
#define NH 12
#define NTOK 1600
#define NM 576
#define NS 1024
#define CD 768
#define HD 64

typedef unsigned short u16;
typedef unsigned int u32;
typedef __attribute__((ext_vector_type(8))) short short8;   // 8 bf16 (4 VGPRs)
typedef __attribute__((ext_vector_type(4))) float f32x4;    // MFMA C/D

__device__ __forceinline__ float fbits(u32 u) { return __uint_as_float(u); }
__device__ __forceinline__ u16 f2b(float f) {  // RNE f32->bf16
    u32 u = __float_as_uint(f);
    u32 r = u + 0x7FFFu + ((u >> 16) & 1u);
    return (u16)(r >> 16);
}
__device__ __forceinline__ float b2f(u16 s) { return fbits(((u32)s) << 16); }
__device__ __forceinline__ u32 flip16(u32 u) {  // order-preserving bf16 -> u16 key
    return (u & 0x8000u) ? (0xFFFFu & ~u) : (u | 0x8000u);
}
__device__ __forceinline__ float key2f(u32 k) {
    u32 b = (k & 0x8000u) ? (k & 0x7FFFu) : (0xFFFFu & ~k);
    return fbits(b << 16);
}

__device__ __forceinline__ float dot768_ff(const float* __restrict__ a,
                                           const float* __restrict__ b) {
    float s = 0.f;
    for (int c = 0; c < CD; c += 4) {
        float4 fa = *(const float4*)(a + c);
        float4 fb = *(const float4*)(b + c);
        s += fa.x * fb.x + fa.y * fb.y + fa.z * fb.z + fa.w * fb.w;
    }
    return s;
}

// ---------------- small LoRA z kernels ----------------

__global__ __launch_bounds__(256) void z24_kernel(const float* __restrict__ x,
                                                  const float* __restrict__ Aq,
                                                  float* __restrict__ z) {
    int idx = blockIdx.x * 256 + threadIdx.x;  // exactly 76800
    int m = idx / 24, q = idx % 24;
    z[idx] = dot768_ff(x + (size_t)m * CD, Aq + (size_t)q * CD);
}

__global__ __launch_bounds__(256) void zid_kernel(const float* __restrict__ id,
                                                  const float* __restrict__ Ak,
                                                  const float* __restrict__ Av,
                                                  float* __restrict__ zk, float* __restrict__ zv) {
    int idx = blockIdx.x * 256 + threadIdx.x;  // exactly 18432
    int m = idx >> 4, q = idx & 15;
    const float* a = (q < 8) ? (Ak + (size_t)q * CD) : (Av + (size_t)(q - 8) * CD);
    float v = dot768_ff(id + (size_t)m * CD, a);
    if (q < 8) zk[m * 8 + q] = v; else zv[m * 8 + q - 8] = v;
}

__global__ __launch_bounds__(256) void idk_kernel(const float* __restrict__ id,
                                                  const float* __restrict__ Wk,
                                                  const float* __restrict__ bk,
                                                  const float* __restrict__ zk,
                                                  const float* __restrict__ Bk,
                                                  float* __restrict__ IDK) {
    int idx = blockIdx.x * 256 + threadIdx.x;  // exactly 13824
    int m = idx / NH, h = idx % NH;
    float v = dot768_ff(id + (size_t)m * CD, Wk + (size_t)h * CD) + bk[h];
    float lo = 0.f;
#pragma unroll
    for (int r = 0; r < 8; ++r) lo += zk[m * 8 + r] * Bk[h * 8 + r];
    IDK[idx] = v + 0.125f * lo;
}

// ---------------- GEMM core macro (64x64 tile, 256 thr, 4x4 micro), f32 ----------------

#define GEMM_CORE(Aexpr, Wexpr)                                                 \
    float acc[4][4] = {};                                                       \
    {                                                                           \
        const int lr = tid >> 2, lk = (tid & 3) * 4;                            \
        for (int k0 = 0; k0 < CD; k0 += 16) {                                   \
            const float4 ta = *(const float4*)&(Aexpr)[(size_t)(m0 + lr) * CD + k0 + lk]; \
            const float4 tb = *(const float4*)&(Wexpr)[(size_t)(j0 + lr) * CD + k0 + lk]; \
            __syncthreads();                                                    \
            As[(lk + 0) * 68 + lr] = ta.x;                                      \
            As[(lk + 1) * 68 + lr] = ta.y;                                      \
            As[(lk + 2) * 68 + lr] = ta.z;                                      \
            As[(lk + 3) * 68 + lr] = ta.w;                                      \
            Bs[(lk + 0) * 68 + lr] = tb.x;                                      \
            Bs[(lk + 1) * 68 + lr] = tb.y;                                      \
            Bs[(lk + 2) * 68 + lr] = tb.z;                                      \
            Bs[(lk + 3) * 68 + lr] = tb.w;                                      \
            __syncthreads();                                                    \
            _Pragma("unroll")                                                   \
            for (int kk = 0; kk < 16; ++kk) {                                   \
                const float4 a4 = *(const float4*)&As[kk * 68 + ty * 4];        \
                const float4 b4 = *(const float4*)&Bs[kk * 68 + tx * 4];        \
                const float aa[4] = {a4.x, a4.y, a4.z, a4.w};                   \
                const float bb[4] = {b4.x, b4.y, b4.z, b4.w};                   \
                _Pragma("unroll")                                               \
                for (int i = 0; i < 4; ++i)                                     \
                    _Pragma("unroll")                                           \
                    for (int j = 0; j < 4; ++j) acc[i][j] += aa[i] * bb[j];     \
            }                                                                   \
        }                                                                       \
    }

// ---------------- ID_V GEMM: scatter into o_vm (d_out, f32) ----------------
__global__ __launch_bounds__(256) void idv_kernel(const float* __restrict__ A,
                                                  const float* __restrict__ Bw,
                                                  const float* __restrict__ bias,
                                                  const float* __restrict__ zv,
                                                  const float* __restrict__ Bl,
                                                  float* __restrict__ ovm) {
    __shared__ float As[16 * 68];
    __shared__ float Bs[16 * 68];
    const int tid = threadIdx.x;
    const int tx = tid & 15, ty = tid >> 4;
    const int j0 = blockIdx.x * 64, m0 = blockIdx.y * 64;
    GEMM_CORE(A, Bw)
#pragma unroll
    for (int i = 0; i < 4; ++i) {
        const int m = m0 + ty * 4 + i;
        const int b = m / NM, n = m - (m / NM) * NM;
        const float* zr = zv + (size_t)m * 8;
#pragma unroll
        for (int jj = 0; jj < 4; ++jj) {
            const int j = j0 + tx * 4 + jj;
            const int h = j >> 6, d = j & 63;
            float lora = 0.f;
            const float* bl = Bl + (size_t)j * 8;
#pragma unroll
            for (int r = 0; r < 8; ++r) lora += zr[r] * bl[r];
            ovm[(((size_t)(b * NH + h)) * NM + n) * 64 + d] =
                acc[i][jj] + bias[j] + 0.125f * lora;
        }
    }
}

// ---------------- qkv GEMM: scatter bf16 q/k/VT + f32 k_m/v_m outputs ----------------
__global__ __launch_bounds__(256) void qkv_kernel(const float* __restrict__ A,
                                                  const float* __restrict__ Bw,
                                                  const float* __restrict__ bias,
                                                  const float* __restrict__ zq,
                                                  const float* __restrict__ Bl,
                                                  const float* __restrict__ IDK,
                                                  u16* __restrict__ qbh,
                                                  u16* __restrict__ kseq,
                                                  u16* __restrict__ vt,
                                                  float* __restrict__ okm,
                                                  float* __restrict__ ovm) {
    __shared__ float As[16 * 68];
    __shared__ float Bs[16 * 68];
    const int tid = threadIdx.x;
    const int tx = tid & 15, ty = tid >> 4;
    const int j0 = blockIdx.x * 64, m0 = blockIdx.y * 64;
    GEMM_CORE(A, Bw)
    const int g = j0 / CD;          // 0=q 1=k 2=v (tile never crosses group/head)
    const int hq = (j0 % CD) >> 6;  // head
#pragma unroll
    for (int i = 0; i < 4; ++i) {
        const int m = m0 + ty * 4 + i;
        const int b = m / NTOK, n = m - (m / NTOK) * NTOK;
        float gate = 0.f;
        if (g == 1 && n < NM) gate = 1.f + tanhf(IDK[(b * NM + n) * NH + hq]);
        const float* zr = zq + (size_t)m * 24 + g * 8;
#pragma unroll
        for (int jj = 0; jj < 4; ++jj) {
            const int d = tx * 4 + jj;
            const int c = hq * 64 + d;
            const int j = j0 + tx * 4 + jj;
            float lora = 0.f;
            const float* bl = Bl + (size_t)(g * CD + c) * 8;
#pragma unroll
            for (int r = 0; r < 8; ++r) lora += zr[r] * bl[r];
            float val = acc[i][jj] + bias[j] + 0.125f * lora;
            const size_t bh = (size_t)(b * NH + hq);
            const size_t om = (bh * NM + n) * 64 + d;
            if (g == 0) {
                qbh[(bh * NTOK + n) * 64 + d] = f2b(val * 0.125f);  // q * hd^-0.5
            } else if (g == 1) {
                kseq[(bh * 3200 + 1600 + n) * 64 + d] = f2b(val);  // seq-attn K rows
                if (n < NM) okm[om] = val * gate;  // k_m output & mem-attn K (f32)
            } else {
                float vv = val;
                if (n < NM) {
                    vv = val + ovm[om];  // ovm held ID_V
                    ovm[om] = vv;        // v_m output (f32)
                }
                vt[(bh * 64 + d) * 3200 + 1600 + n] = f2b(vv);  // transposed V
            }
        }
    }
}

// ---------------- mem_k -> kseq rows 0..1599 (bf16 convert) ----------------
__global__ __launch_bounds__(256) void memk_cvt(const float* __restrict__ mk,
                                                u16* __restrict__ kseq) {
    const int t = blockIdx.x * 256 + threadIdx.x;  // 307200 threads * 8 elems
    const size_t e = (size_t)t * 8;
    const size_t bh = e / (1600 * 64);
    const size_t rem = e - bh * (1600 * 64);
    const float4 f0 = *(const float4*)(mk + e);
    const float4 f1 = *(const float4*)(mk + e + 4);
    short8 s;
    s[0] = (short)f2b(f0.x); s[1] = (short)f2b(f0.y);
    s[2] = (short)f2b(f0.z); s[3] = (short)f2b(f0.w);
    s[4] = (short)f2b(f1.x); s[5] = (short)f2b(f1.y);
    s[6] = (short)f2b(f1.z); s[7] = (short)f2b(f1.w);
    *(short8*)(kseq + bh * (3200 * 64) + rem) = s;
}

// ---------------- mem_v -> VT cols 0..1599 (LDS-tiled transpose + bf16) ----------------
__global__ __launch_bounds__(256) void memv_cvt(const float* __restrict__ mv,
                                                u16* __restrict__ vt) {
    __shared__ float tile[64][65];
    const int bh = blockIdx.y;
    const int kt = blockIdx.x;  // 25 tiles of 64 keys
    const int t = threadIdx.x;
    const int r = t >> 2, c0 = (t & 3) * 16;
    const float* src = mv + ((size_t)bh * 1600 + (size_t)kt * 64 + r) * 64 + c0;
#pragma unroll
    for (int i = 0; i < 4; ++i) {
        const float4 f = *(const float4*)(src + i * 4);
        tile[r][c0 + i * 4 + 0] = f.x;
        tile[r][c0 + i * 4 + 1] = f.y;
        tile[r][c0 + i * 4 + 2] = f.z;
        tile[r][c0 + i * 4 + 3] = f.w;
    }
    __syncthreads();
    short8 s0, s1;
#pragma unroll
    for (int i = 0; i < 8; ++i) s0[i] = (short)f2b(tile[c0 + i][r]);
#pragma unroll
    for (int i = 0; i < 8; ++i) s1[i] = (short)f2b(tile[c0 + 8 + i][r]);
    u16* dst = vt + ((size_t)bh * 64 + r) * 3200 + (size_t)kt * 64 + c0;
    *(short8*)dst = s0;
    *(short8*)(dst + 8) = s1;
}

// ---------------- v6 top-k attention: MFMA logits + MFMA PV ----------------
// 512 threads, 16 q rows/block. LDS: wgt bf16[16][LP] | hist u32[16][256] (aliased
// as O-reduce f32[2][16][64] in phase 4) | rowmax f32[8][16] | invtot f32[16] | bcu.
// Phase 2/3 are wave-private (row <-> wave), no block barriers inside.
template <bool KF32>
__global__ __launch_bounds__(512) void attn6_kernel(const u16* __restrict__ qbh,
                                                    const u16* __restrict__ Kb,
                                                    const float* __restrict__ Kf,
                                                    const u16* __restrict__ vt,
                                                    float* __restrict__ aob,
                                                    int L, int LP, int top, int row_start,
                                                    int krows, int vtoff) {
    extern __shared__ __align__(16) u16 smem[];
    u16* wgt = smem;                          // 16*LP bf16
    u32* hist = (u32*)(smem + 16 * LP);       // 16*256
    float* obuf = (float*)hist;               // alias: 2*16*64 f32 (phase 4)
    float* rowmax = (float*)(hist + 4096);    // 8*16
    float* invtot = rowmax + 128;             // 16
    u32* bcu = (u32*)(invtot + 16);           // 16

    const int tid = threadIdx.x;
    const int lane = tid & 63, wv = tid >> 6;
    const int quad = lane >> 4, n16 = lane & 15;
    const int bh = blockIdx.y;
    const int bb = bh / NH, hh = bh - bb * NH;
    const int r0 = row_start + blockIdx.x * 16;

    // Q A-frags (loop-invariant): A[m=lane&15][k=quad*8+j], two k-chunks
    short8 aQ0, aQ1;
    {
        const u16* qp = qbh + ((size_t)bh * NTOK + r0 + n16) * 64;
        aQ0 = *(const short8*)(qp + quad * 8);
        aQ1 = *(const short8*)(qp + 32 + quad * 8);
    }

    // ---- phase 1: logits via MFMA, track per-row max in regs ----
    float rmax[4] = {-3.4e38f, -3.4e38f, -3.4e38f, -3.4e38f};
    for (int c = wv; c < (L >> 4); c += 8) {
        const int l0 = c << 4;
        short8 fb0, fb1;
        if (KF32) {
            const float* kp = Kf + ((size_t)bh * krows + l0 + n16) * 64 + quad * 8;
            const float4 x0 = *(const float4*)kp;
            const float4 x1 = *(const float4*)(kp + 4);
            const float4 y0 = *(const float4*)(kp + 32);
            const float4 y1 = *(const float4*)(kp + 36);
            fb0[0] = (short)f2b(x0.x); fb0[1] = (short)f2b(x0.y);
            fb0[2] = (short)f2b(x0.z); fb0[3] = (short)f2b(x0.w);
            fb0[4] = (short)f2b(x1.x); fb0[5] = (short)f2b(x1.y);
            fb0[6] = (short)f2b(x1.z); fb0[7] = (short)f2b(x1.w);
            fb1[0] = (short)f2b(y0.x); fb1[1] = (short)f2b(y0.y);
            fb1[2] = (short)f2b(y0.z); fb1[3] = (short)f2b(y0.w);
            fb1[4] = (short)f2b(y1.x); fb1[5] = (short)f2b(y1.y);
            fb1[6] = (short)f2b(y1.z); fb1[7] = (short)f2b(y1.w);
        } else {
            const u16* kp = Kb + ((size_t)bh * krows + l0 + n16) * 64 + quad * 8;
            fb0 = *(const short8*)kp;
            fb1 = *(const short8*)(kp + 32);
        }
        f32x4 d = {0.f, 0.f, 0.f, 0.f};
        d = __builtin_amdgcn_mfma_f32_16x16x32_bf16(aQ0, fb0, d, 0, 0, 0);
        d = __builtin_amdgcn_mfma_f32_16x16x32_bf16(aQ1, fb1, d, 0, 0, 0);
#pragma unroll
        for (int r = 0; r < 4; ++r) {  // D: col=lane&15(key), row=quad*4+r
            const float v = d[r];
            rmax[r] = fmaxf(rmax[r], v);
            wgt[(size_t)(quad * 4 + r) * LP + l0 + n16] = f2b(v);
        }
    }
#pragma unroll
    for (int off = 1; off < 16; off <<= 1) {
#pragma unroll
        for (int r = 0; r < 4; ++r) rmax[r] = fmaxf(rmax[r], __shfl_xor(rmax[r], off));
    }
    if (n16 == 0) {
#pragma unroll
        for (int r = 0; r < 4; ++r) rowmax[wv * 16 + quad * 4 + r] = rmax[r];
    }
    __syncthreads();

    // ---- phase 2+3: per-row (wave-private) radix top-k + masked exp, sum deferred ----
    for (int rp = 0; rp < 2; ++rp) {
        const int rr = wv + 8 * rp;
        u16* row = wgt + (size_t)rr * LP;
        u32* hrow = hist + rr * 256;
        float M = -3.4e38f;
#pragma unroll
        for (int w = 0; w < 8; ++w) M = fmaxf(M, rowmax[w * 16 + rr]);

        int want = top;
        u32 sel1 = 0, sel2 = 0;
        for (int round = 0; round < 2; ++round) {
#pragma unroll
            for (int i = 0; i < 4; ++i) hrow[lane + 64 * i] = 0;
            __threadfence_block();
            for (int l = 2 * lane; l < L; l += 128) {
                const u32 pr = *(const u32*)(row + l);
                const u32 k0 = flip16(pr & 0xffffu);
                const u32 k1 = flip16(pr >> 16);
                if (round == 0) {
                    atomicAdd(&hrow[k0 >> 8], 1u);
                    atomicAdd(&hrow[k1 >> 8], 1u);
                } else {
                    if ((k0 >> 8) == sel1) atomicAdd(&hrow[k0 & 255u], 1u);
                    if ((k1 >> 8) == sel1) atomicAdd(&hrow[k1 & 255u], 1u);
                }
            }
            __threadfence_block();
            u32 hh4[4];
#pragma unroll
            for (int j = 0; j < 4; ++j) hh4[j] = hrow[4 * lane + j];
            const u32 s = hh4[0] + hh4[1] + hh4[2] + hh4[3];
            u32 sum = s;
#pragma unroll
            for (int off = 1; off < 64; off <<= 1) {
                const u32 t = __shfl_down(sum, off);
                if (lane + off < 64) sum += t;
            }
            int cnt = (int)(sum - s);  // keys in strictly-higher bins
            for (int j = 3; j >= 0; --j) {
                const int c = (int)hh4[j];
                if (cnt < want && cnt + c >= want) {
                    bcu[wv * 2] = (u32)(4 * lane + j);
                    bcu[wv * 2 + 1] = (u32)(want - cnt);
                }
                cnt += c;
            }
            __threadfence_block();
            if (round == 0) sel1 = bcu[wv * 2]; else sel2 = bcu[wv * 2];
            want = (int)bcu[wv * 2 + 1];
            __threadfence_block();
        }
        const u32 T = (sel1 << 8) | sel2;
        const int wantT = want;

        float ps = 0.f;
        for (int l = 2 * lane; l < L; l += 128) {
            const u32 pr = *(const u32*)(row + l);
            const u32 k0 = flip16(pr & 0xffffu);
            const u32 k1 = flip16(pr >> 16);
            float w0 = 0.f, w1 = 0.f;
            if (k0 >= T) {
                w0 = __expf(fminf(b2f((u16)(pr & 0xffffu)) - M, 0.f));
                if (k0 > T) ps += w0;
            }
            if (k1 >= T) {
                w1 = __expf(fminf(b2f((u16)(pr >> 16)) - M, 0.f));
                if (k1 > T) ps += w1;
            }
            *(u32*)(row + l) = (u32)f2b(w0) | ((u32)f2b(w1) << 16);
        }
#pragma unroll
        for (int off = 1; off < 64; off <<= 1) ps += __shfl_xor(ps, off);
        const float total = ps + (float)wantT * __expf(fminf(key2f(T) - M, 0.f));
        if (lane == 0) invtot[rr] = 1.f / fmaxf(total, 1e-30f);
    }
    __syncthreads();

    // ---- phase 4: P.V via MFMA; wave = (dim-chunk, key-half); normalize at end ----
    const int half = wv & 1, dc = wv >> 1;
    f32x4 acc = {0.f, 0.f, 0.f, 0.f};
    {
        const int kbeg = half * (L >> 1);
        const int kendv = kbeg + (L >> 1);
        const u16* vp = vt + ((size_t)bh * 64 + dc * 16 + n16) * 3200 + vtoff + quad * 8;
        const u16* wrow2 = wgt + (size_t)n16 * LP + quad * 8;
        for (int k0 = kbeg; k0 < kendv; k0 += 32) {
            const short8 a = *(const short8*)(wrow2 + k0);   // A: P[row][key]
            const short8 bf = *(const short8*)(vp + k0);     // B: VT[dim][key]
            acc = __builtin_amdgcn_mfma_f32_16x16x32_bf16(a, bf, acc, 0, 0, 0);
        }
    }
#pragma unroll
    for (int r = 0; r < 4; ++r) {  // D: col=lane&15(dim), row=quad*4+r
        const int rowi = quad * 4 + r;
        obuf[(half * 16 + rowi) * 64 + dc * 16 + n16] = acc[r] * invtot[rowi];
    }
    __syncthreads();
#pragma unroll
    for (int ii = 0; ii < 2; ++ii) {
        const int idx = tid + ii * 512;
        const int rowi = idx >> 6, dd = idx & 63;
        aob[((size_t)bb * NTOK + r0 + rowi) * CD + hh * 64 + dd] =
            obuf[rowi * 64 + dd] + obuf[(16 + rowi) * 64 + dd];
    }
}

// ---------------- proj routing coefficients ----------------
__global__ __launch_bounds__(256) void coef_kernel(const float* __restrict__ aob,
                                                   const float* __restrict__ rW,
                                                   const float* __restrict__ Ap,
                                                   float* __restrict__ coef) {
    __shared__ float rl[8][4];
    __shared__ float rw[8][4];
    const int slot = threadIdx.x >> 5, lane = threadIdx.x & 31;
    const int m = blockIdx.x * 8 + slot;  // 400 * 8 = 3200
    const float* xr = aob + (size_t)m * CD;
    const float z = dot768_ff(xr, Ap + (size_t)lane * CD);
    if (lane < 4) rl[slot][lane] = dot768_ff(xr, rW + (size_t)lane * CD);
    __syncthreads();
    if (lane == 0) {
        const float mx = fmaxf(fmaxf(rl[slot][0], rl[slot][1]), fmaxf(rl[slot][2], rl[slot][3]));
        const float e0 = __expf(rl[slot][0] - mx), e1 = __expf(rl[slot][1] - mx);
        const float e2 = __expf(rl[slot][2] - mx), e3 = __expf(rl[slot][3] - mx);
        const float is = 1.f / (e0 + e1 + e2 + e3);
        rw[slot][0] = e0 * is; rw[slot][1] = e1 * is; rw[slot][2] = e2 * is; rw[slot][3] = e3 * is;
    }
    __syncthreads();
    coef[(size_t)m * 32 + lane] = rw[slot][lane >> 3] * z * 0.125f;
}

// ---------------- proj GEMM, race-free in-place on io ----------------
__global__ __launch_bounds__(256) void proj_kernel(float* __restrict__ io,
                                                   const float* __restrict__ W,
                                                   const float* __restrict__ bias,
                                                   const float* __restrict__ coef,
                                                   const float* __restrict__ Bp) {
    __shared__ __align__(16) float Apan[16 * CD];
    __shared__ float Bs[16 * 68];
    const int tid = threadIdx.x;
    const int m0 = blockIdx.x * 16;
    for (int t = tid; t < 16 * CD / 4; t += 256)
        ((float4*)Apan)[t] = ((const float4*)(io + (size_t)m0 * CD))[t];
    __syncthreads();
    const int tx = tid & 15, ty = tid >> 4;
    const int lr = tid >> 2, lk = (tid & 3) * 4;
    for (int j0 = 0; j0 < CD; j0 += 64) {
        float acc4[4] = {};
        for (int k0 = 0; k0 < CD; k0 += 16) {
            const float4 tb = *(const float4*)&W[(size_t)(j0 + lr) * CD + k0 + lk];
            __syncthreads();
            Bs[(lk + 0) * 68 + lr] = tb.x;
            Bs[(lk + 1) * 68 + lr] = tb.y;
            Bs[(lk + 2) * 68 + lr] = tb.z;
            Bs[(lk + 3) * 68 + lr] = tb.w;
            __syncthreads();
#pragma unroll
            for (int kk = 0; kk < 16; ++kk) {
                const float a0 = Apan[ty * CD + k0 + kk];
                const float4 b4 = *(const float4*)&Bs[kk * 68 + tx * 4];
                acc4[0] += a0 * b4.x; acc4[1] += a0 * b4.y;
                acc4[2] += a0 * b4.z; acc4[3] += a0 * b4.w;
            }
        }
        const int m = m0 + ty;
        const float* cf = coef + (size_t)m * 32;
#pragma unroll
        for (int jj = 0; jj < 4; ++jj) {
            const int j = j0 + tx * 4 + jj;
            float lora = 0.f;
#pragma unroll
            for (int e = 0; e < 4; ++e) {
                const float* bl = Bp + (size_t)(e * CD + j) * 8;
#pragma unroll
                for (int r = 0; r < 8; ++r) lora += cf[e * 8 + r] * bl[r];
            }
            io[(size_t)m * CD + j] = acc4[jj] + bias[j] + lora;
        }
    }
}

extern "C" void kernel_launch(void* const* d_in, const int* in_sizes, int n_in,
                              void* d_out, int out_size, void* d_ws, size_t ws_size,
                              hipStream_t stream) {
    const float* x = (const float*)d_in[0];
    const float* id_total = (const float*)d_in[1];
    const float* mem_k = (const float*)d_in[2];
    const float* mem_v = (const float*)d_in[3];
    const float* W_qkv = (const float*)d_in[4];
    const float* b_qkv = (const float*)d_in[5];
    const float* A_qkv = (const float*)d_in[6];
    const float* B_qkv = (const float*)d_in[7];
    const float* W_proj = (const float*)d_in[8];
    const float* b_proj = (const float*)d_in[9];
    const float* routeW_proj = (const float*)d_in[10];
    const float* A_proj = (const float*)d_in[11];
    const float* B_proj = (const float*)d_in[12];
    const float* W_idk = (const float*)d_in[13];
    const float* b_idk = (const float*)d_in[14];
    const float* A_idk = (const float*)d_in[16];
    const float* B_idk = (const float*)d_in[17];
    const float* W_idv = (const float*)d_in[18];
    const float* b_idv = (const float*)d_in[19];
    const float* A_idv = (const float*)d_in[21];
    const float* B_idv = (const float*)d_in[22];

    float* io = (float*)d_out;                       // aob then final out
    float* o_km = io + (size_t)BN * NTOK * CD;       // f32 k_m (& mem-attn K)
    float* o_vm = o_km + (size_t)BN * NH * NM * HD;  // f32 ID_V -> v_m

    // workspace: 25,421,824 bytes
    u16* qbh = (u16*)d_ws;            // 2,457,600 u16 (B,H,N,64) scaled Q bf16
    u16* kseq = qbh + 2457600;        // 4,915,200 u16 (B,H,3200,64) [mem_k|k]
    u16* vt = kseq + 4915200;         // 4,915,200 u16 (B,H,64,3200) [mem_v|v_m|v]^T
    float* zq = (float*)(vt + 4915200);  // 76,800
    float* zik = zq + 76800;          // 9,216
    float* ziv = zik + 9216;          // 9,216
    float* IDK = ziv + 9216;          // 13,824
    float* coef = IDK + 13824;        // 102,400

    const int LPs = 3200 + 8, LPm = NM + 8;
    const int smem_seq = 16 * LPs * 2 + 4096 * 4 + 128 * 4 + 16 * 4 + 16 * 4;  // 119,680
    const int smem_mem = 16 * LPm * 2 + 4096 * 4 + 128 * 4 + 16 * 4 + 16 * 4;  // 35,712
    hipFuncSetAttribute((const void*)attn6_kernel<false>,
                        hipFuncAttributeMaxDynamicSharedMemorySize, smem_seq);
    hipFuncSetAttribute((const void*)attn6_kernel<true>,
                        hipFuncAttributeMaxDynamicSharedMemorySize, smem_mem);

    zid_kernel<<<72, 256, 0, stream>>>(id_total, A_idk, A_idv, zik, ziv);
    idk_kernel<<<54, 256, 0, stream>>>(id_total, W_idk, b_idk, zik, B_idk, IDK);
    z24_kernel<<<300, 256, 0, stream>>>(x, A_qkv, zq);
    idv_kernel<<<dim3(12, 18), 256, 0, stream>>>(id_total, W_idv, b_idv, ziv, B_idv, o_vm);
    memk_cvt<<<1200, 256, 0, stream>>>(mem_k, kseq);
    memv_cvt<<<dim3(25, BN * NH), 256, 0, stream>>>(mem_v, vt);
    qkv_kernel<<<dim3(36, 50), 256, 0, stream>>>(x, W_qkv, b_qkv, zq, B_qkv, IDK,
                                                 qbh, kseq, vt, o_km, o_vm);

    // memory attention: L=576, top=288, K=o_km (f32), V=VT cols 1600..2175
    attn6_kernel<true><<<dim3(NM / 16, BN * NH), 512, smem_mem, stream>>>(
        qbh, nullptr, o_km, vt, io, NM, LPm, NM / 2, 0, NM, 1600);
    // seq attention: L=3200, top=1600, K=kseq bf16, V=VT cols 0..3199
    attn6_kernel<false><<<dim3(NS / 16, BN * NH), 512, smem_seq, stream>>>(
        qbh, kseq, nullptr, vt, io, 3200, LPs, 1600, NM, 3200, 0);

    coef_kernel<<<400, 256, 0, stream>>>(io, routeW_proj, A_proj, coef);
    proj_kernel<<<200, 256, 0, stream>>>(io, W_proj, b_proj, coef, B_proj);
}

// Round 7
// 865.770 us; speedup vs baseline: 8.4880x; 1.5239x over previous
//
#include <hip/hip_runtime.h>
#include <hip/hip_bf16.h>

#define BN 2
#define NH 12
#define NTOK 1600
#define NM 576
#define NS 1024
#define CD 768
#define HD 64

typedef unsigned short u16;
typedef unsigned int u32;
typedef __attribute__((ext_vector_type(8))) short short8;   // 8 bf16 (4 VGPRs)
typedef __attribute__((ext_vector_type(4))) float f32x4;    // MFMA C/D

__device__ __forceinline__ float fbits(u32 u) { return __uint_as_float(u); }
__device__ __forceinline__ u16 f2b(float f) {  // RNE f32->bf16
    u32 u = __float_as_uint(f);
    u32 r = u + 0x7FFFu + ((u >> 16) & 1u);
    return (u16)(r >> 16);
}
__device__ __forceinline__ float b2f(u16 s) { return fbits(((u32)s) << 16); }
__device__ __forceinline__ u32 flip16(u32 u) {  // order-preserving bf16 -> u16 key
    return (u & 0x8000u) ? (0xFFFFu & ~u) : (u | 0x8000u);
}
__device__ __forceinline__ float key2f(u32 k) {
    u32 b = (k & 0x8000u) ? (k & 0x7FFFu) : (0xFFFFu & ~k);
    return fbits(b << 16);
}

__device__ __forceinline__ float dot768_ff(const float* __restrict__ a,
                                           const float* __restrict__ b) {
    float s = 0.f;
    for (int c = 0; c < CD; c += 4) {
        float4 fa = *(const float4*)(a + c);
        float4 fb = *(const float4*)(b + c);
        s += fa.x * fb.x + fa.y * fb.y + fa.z * fb.z + fa.w * fb.w;
    }
    return s;
}

// ---------------- small LoRA z kernels ----------------

__global__ __launch_bounds__(256) void z24_kernel(const float* __restrict__ x,
                                                  const float* __restrict__ Aq,
                                                  float* __restrict__ z) {
    int idx = blockIdx.x * 256 + threadIdx.x;  // exactly 76800
    int m = idx / 24, q = idx % 24;
    z[idx] = dot768_ff(x + (size_t)m * CD, Aq + (size_t)q * CD);
}

__global__ __launch_bounds__(256) void zid_kernel(const float* __restrict__ id,
                                                  const float* __restrict__ Ak,
                                                  const float* __restrict__ Av,
                                                  float* __restrict__ zk, float* __restrict__ zv) {
    int idx = blockIdx.x * 256 + threadIdx.x;  // exactly 18432
    int m = idx >> 4, q = idx & 15;
    const float* a = (q < 8) ? (Ak + (size_t)q * CD) : (Av + (size_t)(q - 8) * CD);
    float v = dot768_ff(id + (size_t)m * CD, a);
    if (q < 8) zk[m * 8 + q] = v; else zv[m * 8 + q - 8] = v;
}

__global__ __launch_bounds__(256) void idk_kernel(const float* __restrict__ id,
                                                  const float* __restrict__ Wk,
                                                  const float* __restrict__ bk,
                                                  const float* __restrict__ zk,
                                                  const float* __restrict__ Bk,
                                                  float* __restrict__ IDK) {
    int idx = blockIdx.x * 256 + threadIdx.x;  // exactly 13824
    int m = idx / NH, h = idx % NH;
    float v = dot768_ff(id + (size_t)m * CD, Wk + (size_t)h * CD) + bk[h];
    float lo = 0.f;
#pragma unroll
    for (int r = 0; r < 8; ++r) lo += zk[m * 8 + r] * Bk[h * 8 + r];
    IDK[idx] = v + 0.125f * lo;
}

// ---------------- f32 GEMM core (used only by small idv GEMM) ----------------

#define GEMM_CORE(Aexpr, Wexpr)                                                 \
    float acc[4][4] = {};                                                       \
    {                                                                           \
        const int lr = tid >> 2, lk = (tid & 3) * 4;                            \
        for (int k0 = 0; k0 < CD; k0 += 16) {                                   \
            const float4 ta = *(const float4*)&(Aexpr)[(size_t)(m0 + lr) * CD + k0 + lk]; \
            const float4 tb = *(const float4*)&(Wexpr)[(size_t)(j0 + lr) * CD + k0 + lk]; \
            __syncthreads();                                                    \
            As[(lk + 0) * 68 + lr] = ta.x;                                      \
            As[(lk + 1) * 68 + lr] = ta.y;                                      \
            As[(lk + 2) * 68 + lr] = ta.z;                                      \
            As[(lk + 3) * 68 + lr] = ta.w;                                      \
            Bs[(lk + 0) * 68 + lr] = tb.x;                                      \
            Bs[(lk + 1) * 68 + lr] = tb.y;                                      \
            Bs[(lk + 2) * 68 + lr] = tb.z;                                      \
            Bs[(lk + 3) * 68 + lr] = tb.w;                                      \
            __syncthreads();                                                    \
            _Pragma("unroll")                                                   \
            for (int kk = 0; kk < 16; ++kk) {                                   \
                const float4 a4 = *(const float4*)&As[kk * 68 + ty * 4];        \
                const float4 b4 = *(const float4*)&Bs[kk * 68 + tx * 4];        \
                const float aa[4] = {a4.x, a4.y, a4.z, a4.w};                   \
                const float bb[4] = {b4.x, b4.y, b4.z, b4.w};                   \
                _Pragma("unroll")                                               \
                for (int i = 0; i < 4; ++i)                                     \
                    _Pragma("unroll")                                           \
                    for (int j = 0; j < 4; ++j) acc[i][j] += aa[i] * bb[j];     \
            }                                                                   \
        }                                                                       \
    }

// ---------------- ID_V GEMM: scatter into o_vm (d_out, f32) ----------------
__global__ __launch_bounds__(256) void idv_kernel(const float* __restrict__ A,
                                                  const float* __restrict__ Bw,
                                                  const float* __restrict__ bias,
                                                  const float* __restrict__ zv,
                                                  const float* __restrict__ Bl,
                                                  float* __restrict__ ovm) {
    __shared__ float As[16 * 68];
    __shared__ float Bs[16 * 68];
    const int tid = threadIdx.x;
    const int tx = tid & 15, ty = tid >> 4;
    const int j0 = blockIdx.x * 64, m0 = blockIdx.y * 64;
    GEMM_CORE(A, Bw)
#pragma unroll
    for (int i = 0; i < 4; ++i) {
        const int m = m0 + ty * 4 + i;
        const int b = m / NM, n = m - (m / NM) * NM;
        const float* zr = zv + (size_t)m * 8;
#pragma unroll
        for (int jj = 0; jj < 4; ++jj) {
            const int j = j0 + tx * 4 + jj;
            const int h = j >> 6, d = j & 63;
            float lora = 0.f;
            const float* bl = Bl + (size_t)j * 8;
#pragma unroll
            for (int r = 0; r < 8; ++r) lora += zr[r] * bl[r];
            ovm[(((size_t)(b * NH + h)) * NM + n) * 64 + d] =
                acc[i][jj] + bias[j] + 0.125f * lora;
        }
    }
}

// ---------------- augmented-operand builders (bf16, K=800) ----------------
// x_aug[m][0:768]=x, [768:792]=zq, [792:800]=0
__global__ __launch_bounds__(256) void cvt_xaug(const float* __restrict__ x,
                                                const float* __restrict__ zq,
                                                u16* __restrict__ dst) {
    const int idx = blockIdx.x * 256 + threadIdx.x;  // 320000
    const int m = idx / 100, c8 = idx - m * 100;
    short8 v;
    if (c8 < 96) {
        const float* s = x + (size_t)m * CD + c8 * 8;
#pragma unroll
        for (int i = 0; i < 8; ++i) v[i] = (short)f2b(s[i]);
    } else if (c8 < 99) {
        const float* s = zq + (size_t)m * 24 + (c8 - 96) * 8;
#pragma unroll
        for (int i = 0; i < 8; ++i) v[i] = (short)f2b(s[i]);
    } else {
#pragma unroll
        for (int i = 0; i < 8; ++i) v[i] = 0;
    }
    *(short8*)(dst + (size_t)m * 800 + c8 * 8) = v;
}

// W_qkv_aug[j][0:768]=W_qkv[j], [768+g'*8+r] = (g'==g(j)) ? 0.125*B_qkv[g][c][r] : 0
__global__ __launch_bounds__(256) void cvt_wqkv(const float* __restrict__ W,
                                                const float* __restrict__ Bq,
                                                u16* __restrict__ dst) {
    const int idx = blockIdx.x * 256 + threadIdx.x;  // 230400
    const int j = idx / 100, c8 = idx - j * 100;
    short8 v;
    if (c8 < 96) {
        const float* s = W + (size_t)j * CD + c8 * 8;
#pragma unroll
        for (int i = 0; i < 8; ++i) v[i] = (short)f2b(s[i]);
    } else if (c8 < 99) {
        const int g = j / CD, c = j - g * CD;
        const int gp = c8 - 96;  // aligned: each 8-chunk is one g' block
#pragma unroll
        for (int i = 0; i < 8; ++i)
            v[i] = (gp == g) ? (short)f2b(0.125f * Bq[((size_t)g * CD + c) * 8 + i]) : (short)0;
    } else {
#pragma unroll
        for (int i = 0; i < 8; ++i) v[i] = 0;
    }
    *(short8*)(dst + (size_t)j * 800 + c8 * 8) = v;
}

// W_proj_aug[j][0:768]=W_proj[j], [768+e*8+r]=B_proj[e][j][r]
__global__ __launch_bounds__(256) void cvt_wproj(const float* __restrict__ W,
                                                 const float* __restrict__ Bp,
                                                 u16* __restrict__ dst) {
    const int idx = blockIdx.x * 256 + threadIdx.x;  // 76800
    const int j = idx / 100, c8 = idx - j * 100;
    short8 v;
    if (c8 < 96) {
        const float* s = W + (size_t)j * CD + c8 * 8;
#pragma unroll
        for (int i = 0; i < 8; ++i) v[i] = (short)f2b(s[i]);
    } else {
        const int e = c8 - 96;
#pragma unroll
        for (int i = 0; i < 8; ++i) v[i] = (short)f2b(Bp[((size_t)e * CD + j) * 8 + i]);
    }
    *(short8*)(dst + (size_t)j * 800 + c8 * 8) = v;
}

// aob_aug[m][0:768]=aob(f32 in io), [768+e*8+r]=coef[m][e*8+r]
__global__ __launch_bounds__(256) void cvt_aobaug(const float* __restrict__ aob,
                                                  const float* __restrict__ coef,
                                                  u16* __restrict__ dst) {
    const int idx = blockIdx.x * 256 + threadIdx.x;  // 320000
    const int m = idx / 100, c8 = idx - m * 100;
    short8 v;
    if (c8 < 96) {
        const float* s = aob + (size_t)m * CD + c8 * 8;
#pragma unroll
        for (int i = 0; i < 8; ++i) v[i] = (short)f2b(s[i]);
    } else {
        const float* s = coef + (size_t)m * 32 + (c8 - 96) * 8;
#pragma unroll
        for (int i = 0; i < 8; ++i) v[i] = (short)f2b(s[i]);
    }
    *(short8*)(dst + (size_t)m * 800 + c8 * 8) = v;
}

// ---------------- MFMA GEMM, K=800 augmented, no LDS (L2-direct frags) ----------------
// MODE 0 (qkv): 256 thr, block tile 128x128, grid (2304/128, 3200/128).
//   Epilogue: scatter bf16 q/k/VT + f32 k_m/v_m with gate & ID_V fusion.
// MODE 1 (proj): 128 thr, block tile 64x128, grid (768/128, 3200/64). f32 out.
template <int MODE>
__global__ __launch_bounds__(MODE == 0 ? 256 : 128) void
gemm16_kernel(const u16* __restrict__ A16, const u16* __restrict__ B16,
              const float* __restrict__ bias, const float* __restrict__ IDK,
              u16* __restrict__ qbh, u16* __restrict__ kseq, u16* __restrict__ vt,
              float* __restrict__ okm, float* __restrict__ ovm,
              float* __restrict__ io) {
    const int tid = threadIdx.x;
    const int lane = tid & 63, wv = tid >> 6;
    const int quad = lane >> 4, n16 = lane & 15;
    int m0, n0;
    if (MODE == 0) {
        m0 = blockIdx.y * 128 + (wv >> 1) * 64;
        n0 = blockIdx.x * 128 + (wv & 1) * 64;
    } else {
        m0 = blockIdx.y * 64;
        n0 = blockIdx.x * 128 + wv * 64;
    }

    f32x4 acc[4][4];
#pragma unroll
    for (int a = 0; a < 4; ++a)
#pragma unroll
        for (int b = 0; b < 4; ++b) acc[a][b] = (f32x4){0.f, 0.f, 0.f, 0.f};

    const u16* ap = A16 + (size_t)(m0 + n16) * 800 + quad * 8;
    const u16* bp = B16 + (size_t)(n0 + n16) * 800 + quad * 8;
    for (int k0 = 0; k0 < 800; k0 += 32) {
        short8 aA[4], aB[4];
#pragma unroll
        for (int c = 0; c < 4; ++c) {
            aA[c] = *(const short8*)(ap + (size_t)c * 16 * 800 + k0);
            aB[c] = *(const short8*)(bp + (size_t)c * 16 * 800 + k0);
        }
#pragma unroll
        for (int mc = 0; mc < 4; ++mc)
#pragma unroll
            for (int nc = 0; nc < 4; ++nc)
                acc[mc][nc] =
                    __builtin_amdgcn_mfma_f32_16x16x32_bf16(aA[mc], aB[nc], acc[mc][nc], 0, 0, 0);
    }

    if (MODE == 0) {
        const int g = n0 / CD;          // wave-uniform (64 | 768)
        const int hq = (n0 % CD) >> 6;  // wave-uniform
#pragma unroll
        for (int mc = 0; mc < 4; ++mc) {
#pragma unroll
            for (int r = 0; r < 4; ++r) {
                const int m = m0 + mc * 16 + quad * 4 + r;
                const int b = m / NTOK, n = m - (m / NTOK) * NTOK;
                const size_t bh = (size_t)(b * NH + hq);
                float gate = 0.f;
                if (g == 1 && n < NM) gate = 1.f + tanhf(IDK[(b * NM + n) * NH + hq]);
#pragma unroll
                for (int nc = 0; nc < 4; ++nc) {
                    const int d = nc * 16 + n16;            // 0..63
                    const int j = n0 + d;
                    const float val = acc[mc][nc][r] + bias[j];
                    const size_t om = (bh * NM + n) * 64 + d;
                    if (g == 0) {
                        qbh[(bh * NTOK + n) * 64 + d] = f2b(val * 0.125f);
                    } else if (g == 1) {
                        kseq[(bh * 3200 + 1600 + n) * 64 + d] = f2b(val);
                        if (n < NM) okm[om] = val * gate;
                    } else {
                        float vv = val;
                        if (n < NM) {
                            vv = val + ovm[om];
                            ovm[om] = vv;
                        }
                        vt[(bh * 64 + d) * 3200 + 1600 + n] = f2b(vv);
                    }
                }
            }
        }
    } else {
#pragma unroll
        for (int mc = 0; mc < 4; ++mc) {
#pragma unroll
            for (int r = 0; r < 4; ++r) {
                const int m = m0 + mc * 16 + quad * 4 + r;
#pragma unroll
                for (int nc = 0; nc < 4; ++nc) {
                    const int j = n0 + nc * 16 + n16;
                    io[(size_t)m * CD + j] = acc[mc][nc][r] + bias[j];
                }
            }
        }
    }
}

// ---------------- mem_k -> kseq rows 0..1599 (bf16 convert) ----------------
__global__ __launch_bounds__(256) void memk_cvt(const float* __restrict__ mk,
                                                u16* __restrict__ kseq) {
    const int t = blockIdx.x * 256 + threadIdx.x;  // 307200 threads * 8 elems
    const size_t e = (size_t)t * 8;
    const size_t bh = e / (1600 * 64);
    const size_t rem = e - bh * (1600 * 64);
    const float4 f0 = *(const float4*)(mk + e);
    const float4 f1 = *(const float4*)(mk + e + 4);
    short8 s;
    s[0] = (short)f2b(f0.x); s[1] = (short)f2b(f0.y);
    s[2] = (short)f2b(f0.z); s[3] = (short)f2b(f0.w);
    s[4] = (short)f2b(f1.x); s[5] = (short)f2b(f1.y);
    s[6] = (short)f2b(f1.z); s[7] = (short)f2b(f1.w);
    *(short8*)(kseq + bh * (3200 * 64) + rem) = s;
}

// ---------------- mem_v -> VT cols 0..1599 (LDS-tiled transpose + bf16) ----------------
__global__ __launch_bounds__(256) void memv_cvt(const float* __restrict__ mv,
                                                u16* __restrict__ vt) {
    __shared__ float tile[64][65];
    const int bh = blockIdx.y;
    const int kt = blockIdx.x;  // 25 tiles of 64 keys
    const int t = threadIdx.x;
    const int r = t >> 2, c0 = (t & 3) * 16;
    const float* src = mv + ((size_t)bh * 1600 + (size_t)kt * 64 + r) * 64 + c0;
#pragma unroll
    for (int i = 0; i < 4; ++i) {
        const float4 f = *(const float4*)(src + i * 4);
        tile[r][c0 + i * 4 + 0] = f.x;
        tile[r][c0 + i * 4 + 1] = f.y;
        tile[r][c0 + i * 4 + 2] = f.z;
        tile[r][c0 + i * 4 + 3] = f.w;
    }
    __syncthreads();
    short8 s0, s1;
#pragma unroll
    for (int i = 0; i < 8; ++i) s0[i] = (short)f2b(tile[c0 + i][r]);
#pragma unroll
    for (int i = 0; i < 8; ++i) s1[i] = (short)f2b(tile[c0 + 8 + i][r]);
    u16* dst = vt + ((size_t)bh * 64 + r) * 3200 + (size_t)kt * 64 + c0;
    *(short8*)dst = s0;
    *(short8*)(dst + 8) = s1;
}

// ---------------- v6 top-k attention: MFMA logits + MFMA PV (unchanged from r6) ----------------
template <bool KF32>
__global__ __launch_bounds__(512) void attn6_kernel(const u16* __restrict__ qbh,
                                                    const u16* __restrict__ Kb,
                                                    const float* __restrict__ Kf,
                                                    const u16* __restrict__ vt,
                                                    float* __restrict__ aob,
                                                    int L, int LP, int top, int row_start,
                                                    int krows, int vtoff) {
    extern __shared__ __align__(16) u16 smem[];
    u16* wgt = smem;                          // 16*LP bf16
    u32* hist = (u32*)(smem + 16 * LP);       // 16*256
    float* obuf = (float*)hist;               // alias: 2*16*64 f32 (phase 4)
    float* rowmax = (float*)(hist + 4096);    // 8*16
    float* invtot = rowmax + 128;             // 16
    u32* bcu = (u32*)(invtot + 16);           // 16

    const int tid = threadIdx.x;
    const int lane = tid & 63, wv = tid >> 6;
    const int quad = lane >> 4, n16 = lane & 15;
    const int bh = blockIdx.y;
    const int bb = bh / NH, hh = bh - bb * NH;
    const int r0 = row_start + blockIdx.x * 16;

    short8 aQ0, aQ1;
    {
        const u16* qp = qbh + ((size_t)bh * NTOK + r0 + n16) * 64;
        aQ0 = *(const short8*)(qp + quad * 8);
        aQ1 = *(const short8*)(qp + 32 + quad * 8);
    }

    float rmax[4] = {-3.4e38f, -3.4e38f, -3.4e38f, -3.4e38f};
    for (int c = wv; c < (L >> 4); c += 8) {
        const int l0 = c << 4;
        short8 fb0, fb1;
        if (KF32) {
            const float* kp = Kf + ((size_t)bh * krows + l0 + n16) * 64 + quad * 8;
            const float4 x0 = *(const float4*)kp;
            const float4 x1 = *(const float4*)(kp + 4);
            const float4 y0 = *(const float4*)(kp + 32);
            const float4 y1 = *(const float4*)(kp + 36);
            fb0[0] = (short)f2b(x0.x); fb0[1] = (short)f2b(x0.y);
            fb0[2] = (short)f2b(x0.z); fb0[3] = (short)f2b(x0.w);
            fb0[4] = (short)f2b(x1.x); fb0[5] = (short)f2b(x1.y);
            fb0[6] = (short)f2b(x1.z); fb0[7] = (short)f2b(x1.w);
            fb1[0] = (short)f2b(y0.x); fb1[1] = (short)f2b(y0.y);
            fb1[2] = (short)f2b(y0.z); fb1[3] = (short)f2b(y0.w);
            fb1[4] = (short)f2b(y1.x); fb1[5] = (short)f2b(y1.y);
            fb1[6] = (short)f2b(y1.z); fb1[7] = (short)f2b(y1.w);
        } else {
            const u16* kp = Kb + ((size_t)bh * krows + l0 + n16) * 64 + quad * 8;
            fb0 = *(const short8*)kp;
            fb1 = *(const short8*)(kp + 32);
        }
        f32x4 d = {0.f, 0.f, 0.f, 0.f};
        d = __builtin_amdgcn_mfma_f32_16x16x32_bf16(aQ0, fb0, d, 0, 0, 0);
        d = __builtin_amdgcn_mfma_f32_16x16x32_bf16(aQ1, fb1, d, 0, 0, 0);
#pragma unroll
        for (int r = 0; r < 4; ++r) {
            const float v = d[r];
            rmax[r] = fmaxf(rmax[r], v);
            wgt[(size_t)(quad * 4 + r) * LP + l0 + n16] = f2b(v);
        }
    }
#pragma unroll
    for (int off = 1; off < 16; off <<= 1) {
#pragma unroll
        for (int r = 0; r < 4; ++r) rmax[r] = fmaxf(rmax[r], __shfl_xor(rmax[r], off));
    }
    if (n16 == 0) {
#pragma unroll
        for (int r = 0; r < 4; ++r) rowmax[wv * 16 + quad * 4 + r] = rmax[r];
    }
    __syncthreads();

    for (int rp = 0; rp < 2; ++rp) {
        const int rr = wv + 8 * rp;
        u16* row = wgt + (size_t)rr * LP;
        u32* hrow = hist + rr * 256;
        float M = -3.4e38f;
#pragma unroll
        for (int w = 0; w < 8; ++w) M = fmaxf(M, rowmax[w * 16 + rr]);

        int want = top;
        u32 sel1 = 0, sel2 = 0;
        for (int round = 0; round < 2; ++round) {
#pragma unroll
            for (int i = 0; i < 4; ++i) hrow[lane + 64 * i] = 0;
            __threadfence_block();
            for (int l = 2 * lane; l < L; l += 128) {
                const u32 pr = *(const u32*)(row + l);
                const u32 k0 = flip16(pr & 0xffffu);
                const u32 k1 = flip16(pr >> 16);
                if (round == 0) {
                    atomicAdd(&hrow[k0 >> 8], 1u);
                    atomicAdd(&hrow[k1 >> 8], 1u);
                } else {
                    if ((k0 >> 8) == sel1) atomicAdd(&hrow[k0 & 255u], 1u);
                    if ((k1 >> 8) == sel1) atomicAdd(&hrow[k1 & 255u], 1u);
                }
            }
            __threadfence_block();
            u32 hh4[4];
#pragma unroll
            for (int j = 0; j < 4; ++j) hh4[j] = hrow[4 * lane + j];
            const u32 s = hh4[0] + hh4[1] + hh4[2] + hh4[3];
            u32 sum = s;
#pragma unroll
            for (int off = 1; off < 64; off <<= 1) {
                const u32 t = __shfl_down(sum, off);
                if (lane + off < 64) sum += t;
            }
            int cnt = (int)(sum - s);
            for (int j = 3; j >= 0; --j) {
                const int c = (int)hh4[j];
                if (cnt < want && cnt + c >= want) {
                    bcu[wv * 2] = (u32)(4 * lane + j);
                    bcu[wv * 2 + 1] = (u32)(want - cnt);
                }
                cnt += c;
            }
            __threadfence_block();
            if (round == 0) sel1 = bcu[wv * 2]; else sel2 = bcu[wv * 2];
            want = (int)bcu[wv * 2 + 1];
            __threadfence_block();
        }
        const u32 T = (sel1 << 8) | sel2;
        const int wantT = want;

        float ps = 0.f;
        for (int l = 2 * lane; l < L; l += 128) {
            const u32 pr = *(const u32*)(row + l);
            const u32 k0 = flip16(pr & 0xffffu);
            const u32 k1 = flip16(pr >> 16);
            float w0 = 0.f, w1 = 0.f;
            if (k0 >= T) {
                w0 = __expf(fminf(b2f((u16)(pr & 0xffffu)) - M, 0.f));
                if (k0 > T) ps += w0;
            }
            if (k1 >= T) {
                w1 = __expf(fminf(b2f((u16)(pr >> 16)) - M, 0.f));
                if (k1 > T) ps += w1;
            }
            *(u32*)(row + l) = (u32)f2b(w0) | ((u32)f2b(w1) << 16);
        }
#pragma unroll
        for (int off = 1; off < 64; off <<= 1) ps += __shfl_xor(ps, off);
        const float total = ps + (float)wantT * __expf(fminf(key2f(T) - M, 0.f));
        if (lane == 0) invtot[rr] = 1.f / fmaxf(total, 1e-30f);
    }
    __syncthreads();

    const int half = wv & 1, dc = wv >> 1;
    f32x4 acc = {0.f, 0.f, 0.f, 0.f};
    {
        const int kbeg = half * (L >> 1);
        const int kendv = kbeg + (L >> 1);
        const u16* vp = vt + ((size_t)bh * 64 + dc * 16 + n16) * 3200 + vtoff + quad * 8;
        const u16* wrow2 = wgt + (size_t)n16 * LP + quad * 8;
        for (int k0 = kbeg; k0 < kendv; k0 += 32) {
            const short8 a = *(const short8*)(wrow2 + k0);
            const short8 bf = *(const short8*)(vp + k0);
            acc = __builtin_amdgcn_mfma_f32_16x16x32_bf16(a, bf, acc, 0, 0, 0);
        }
    }
#pragma unroll
    for (int r = 0; r < 4; ++r) {
        const int rowi = quad * 4 + r;
        obuf[(half * 16 + rowi) * 64 + dc * 16 + n16] = acc[r] * invtot[rowi];
    }
    __syncthreads();
#pragma unroll
    for (int ii = 0; ii < 2; ++ii) {
        const int idx = tid + ii * 512;
        const int rowi = idx >> 6, dd = idx & 63;
        aob[((size_t)bb * NTOK + r0 + rowi) * CD + hh * 64 + dd] =
            obuf[rowi * 64 + dd] + obuf[(16 + rowi) * 64 + dd];
    }
}

// ---------------- proj routing coefficients ----------------
__global__ __launch_bounds__(256) void coef_kernel(const float* __restrict__ aob,
                                                   const float* __restrict__ rW,
                                                   const float* __restrict__ Ap,
                                                   float* __restrict__ coef) {
    __shared__ float rl[8][4];
    __shared__ float rw[8][4];
    const int slot = threadIdx.x >> 5, lane = threadIdx.x & 31;
    const int m = blockIdx.x * 8 + slot;  // 400 * 8 = 3200
    const float* xr = aob + (size_t)m * CD;
    const float z = dot768_ff(xr, Ap + (size_t)lane * CD);
    if (lane < 4) rl[slot][lane] = dot768_ff(xr, rW + (size_t)lane * CD);
    __syncthreads();
    if (lane == 0) {
        const float mx = fmaxf(fmaxf(rl[slot][0], rl[slot][1]), fmaxf(rl[slot][2], rl[slot][3]));
        const float e0 = __expf(rl[slot][0] - mx), e1 = __expf(rl[slot][1] - mx);
        const float e2 = __expf(rl[slot][2] - mx), e3 = __expf(rl[slot][3] - mx);
        const float is = 1.f / (e0 + e1 + e2 + e3);
        rw[slot][0] = e0 * is; rw[slot][1] = e1 * is; rw[slot][2] = e2 * is; rw[slot][3] = e3 * is;
    }
    __syncthreads();
    coef[(size_t)m * 32 + lane] = rw[slot][lane >> 3] * z * 0.125f;
}

extern "C" void kernel_launch(void* const* d_in, const int* in_sizes, int n_in,
                              void* d_out, int out_size, void* d_ws, size_t ws_size,
                              hipStream_t stream) {
    const float* x = (const float*)d_in[0];
    const float* id_total = (const float*)d_in[1];
    const float* mem_k = (const float*)d_in[2];
    const float* mem_v = (const float*)d_in[3];
    const float* W_qkv = (const float*)d_in[4];
    const float* b_qkv = (const float*)d_in[5];
    const float* A_qkv = (const float*)d_in[6];
    const float* B_qkv = (const float*)d_in[7];
    const float* W_proj = (const float*)d_in[8];
    const float* b_proj = (const float*)d_in[9];
    const float* routeW_proj = (const float*)d_in[10];
    const float* A_proj = (const float*)d_in[11];
    const float* B_proj = (const float*)d_in[12];
    const float* W_idk = (const float*)d_in[13];
    const float* b_idk = (const float*)d_in[14];
    const float* A_idk = (const float*)d_in[16];
    const float* B_idk = (const float*)d_in[17];
    const float* W_idv = (const float*)d_in[18];
    const float* b_idv = (const float*)d_in[19];
    const float* A_idv = (const float*)d_in[21];
    const float* B_idv = (const float*)d_in[22];

    float* io = (float*)d_out;                       // staging -> aob -> final out
    float* o_km = io + (size_t)BN * NTOK * CD;       // f32 k_m (& mem-attn K)
    float* o_vm = o_km + (size_t)BN * NH * NM * HD;  // f32 ID_V -> v_m

    // io region (9,830,400 B) doubles as bf16 staging before attention:
    u16* x_aug = (u16*)io;            // 3200*800 u16 = 5,120,000 B
    u16* wqkv_aug = x_aug + 2560000;  // 2304*800 u16 = 3,686,400 B (total 8.8 MB ok)

    // workspace: 26,650,624 bytes
    u16* qbh = (u16*)d_ws;               // 4,915,200 B  (B,H,N,64) scaled Q bf16
    u16* kseq = qbh + 2457600;           // 9,830,400 B  (B,H,3200,64) [mem_k|k]; later aob_aug
    u16* vt = kseq + 4915200;            // 9,830,400 B  (B,H,64,3200) V^T
    float* zq = (float*)(vt + 4915200);  // 307,200 B
    float* zik = zq + 76800;
    float* ziv = zik + 9216;
    float* IDK = ziv + 9216;
    float* coef = IDK + 13824;
    u16* wproj_aug = (u16*)(coef + 102400);  // 768*800 u16 = 1,228,800 B

    const int LPs = 3200 + 8, LPm = NM + 8;
    const int smem_seq = 16 * LPs * 2 + 4096 * 4 + 128 * 4 + 16 * 4 + 16 * 4;  // 119,680
    const int smem_mem = 16 * LPm * 2 + 4096 * 4 + 128 * 4 + 16 * 4 + 16 * 4;  // 35,712
    hipFuncSetAttribute((const void*)attn6_kernel<false>,
                        hipFuncAttributeMaxDynamicSharedMemorySize, smem_seq);
    hipFuncSetAttribute((const void*)attn6_kernel<true>,
                        hipFuncAttributeMaxDynamicSharedMemorySize, smem_mem);

    z24_kernel<<<300, 256, 0, stream>>>(x, A_qkv, zq);
    zid_kernel<<<72, 256, 0, stream>>>(id_total, A_idk, A_idv, zik, ziv);
    idk_kernel<<<54, 256, 0, stream>>>(id_total, W_idk, b_idk, zik, B_idk, IDK);
    idv_kernel<<<dim3(12, 18), 256, 0, stream>>>(id_total, W_idv, b_idv, ziv, B_idv, o_vm);

    cvt_xaug<<<1250, 256, 0, stream>>>(x, zq, x_aug);
    cvt_wqkv<<<900, 256, 0, stream>>>(W_qkv, B_qkv, wqkv_aug);
    cvt_wproj<<<300, 256, 0, stream>>>(W_proj, B_proj, wproj_aug);
    memk_cvt<<<1200, 256, 0, stream>>>(mem_k, kseq);
    memv_cvt<<<dim3(25, BN * NH), 256, 0, stream>>>(mem_v, vt);

    // qkv: C[3200x2304] via MFMA, fused LoRA (augmented K) + gate/ID_V epilogue
    gemm16_kernel<0><<<dim3(18, 25), 256, 0, stream>>>(x_aug, wqkv_aug, b_qkv, IDK,
                                                       qbh, kseq, vt, o_km, o_vm, nullptr);

    // memory attention: L=576, top=288, K=o_km (f32), V=VT cols 1600..2175
    attn6_kernel<true><<<dim3(NM / 16, BN * NH), 512, smem_mem, stream>>>(
        qbh, nullptr, o_km, vt, io, NM, LPm, NM / 2, 0, NM, 1600);
    // seq attention: L=3200, top=1600, K=kseq bf16, V=VT cols 0..3199
    attn6_kernel<false><<<dim3(NS / 16, BN * NH), 512, smem_seq, stream>>>(
        qbh, kseq, nullptr, vt, io, 3200, LPs, 1600, NM, 3200, 0);

    coef_kernel<<<400, 256, 0, stream>>>(io, routeW_proj, A_proj, coef);
    // aob_aug into kseq region (dead after seq attention)
    cvt_aobaug<<<1250, 256, 0, stream>>>(io, coef, kseq);
    // proj: C[3200x768] via MFMA, fused routed-LoRA (augmented K), f32 out in-place
    gemm16_kernel<1><<<dim3(6, 50), 128, 0, stream>>>(kseq, wproj_aug, b_proj, nullptr,
                                                      nullptr, nullptr, nullptr, nullptr,
                                                      nullptr, io);
}

// Round 8
// 684.059 us; speedup vs baseline: 10.7427x; 1.2656x over previous
//
#include <hip/hip_runtime.h>
#include <hip/hip_bf16.h>

#define BN 2
#define NH 12
#define NTOK 1600
#define NM 576
#define NS 1024
#define CD 768
#define HD 64

typedef unsigned short u16;
typedef unsigned int u32;
typedef __attribute__((ext_vector_type(8))) short short8;   // 8 bf16 (4 VGPRs)
typedef __attribute__((ext_vector_type(4))) float f32x4;    // MFMA C/D

__device__ __forceinline__ float fbits(u32 u) { return __uint_as_float(u); }
__device__ __forceinline__ u16 f2b(float f) {  // RNE f32->bf16
    u32 u = __float_as_uint(f);
    u32 r = u + 0x7FFFu + ((u >> 16) & 1u);
    return (u16)(r >> 16);
}
__device__ __forceinline__ float b2f(u16 s) { return fbits(((u32)s) << 16); }
__device__ __forceinline__ u32 flip16(u32 u) {  // order-preserving bf16 -> u16 key
    return (u & 0x8000u) ? (0xFFFFu & ~u) : (u | 0x8000u);
}
__device__ __forceinline__ float key2f(u32 k) {
    u32 b = (k & 0x8000u) ? (k & 0x7FFFu) : (0xFFFFu & ~k);
    return fbits(b << 16);
}
__device__ __forceinline__ float wave_red(float p) {
#pragma unroll
    for (int off = 1; off < 64; off <<= 1) p += __shfl_xor(p, off);
    return p;
}

__device__ __forceinline__ float dot768_ff(const float* __restrict__ a,
                                           const float* __restrict__ b) {
    float s = 0.f;
    for (int c = 0; c < CD; c += 4) {
        float4 fa = *(const float4*)(a + c);
        float4 fb = *(const float4*)(b + c);
        s += fa.x * fb.x + fa.y * fb.y + fa.z * fb.z + fa.w * fb.w;
    }
    return s;
}

// ---------------- small_dots: z24 (x tokens) + ziv/IDK (id tokens) ----------------
__global__ __launch_bounds__(256) void small_dots(const float* __restrict__ x,
                                                  const float* __restrict__ Aq,
                                                  float* __restrict__ zq,
                                                  const float* __restrict__ id,
                                                  const float* __restrict__ Aik,
                                                  const float* __restrict__ Aiv,
                                                  const float* __restrict__ Wik,
                                                  const float* __restrict__ bik,
                                                  const float* __restrict__ Bik,
                                                  float* __restrict__ ziv,
                                                  float* __restrict__ IDK) {
    __shared__ float dres[28];
    const int blk = blockIdx.x;
    const int tid = threadIdx.x, lane = tid & 63, wv = tid >> 6;
    if (blk < 3200) {  // x token: 24 LoRA dots
        const float* xr = x + (size_t)blk * CD;
#pragma unroll
        for (int t = 0; t < 6; ++t) {
            const int q = wv * 6 + t;
            const float* ar = Aq + (size_t)q * CD;
            float p = 0.f;
#pragma unroll
            for (int c = 0; c < 12; ++c) p += xr[lane + c * 64] * ar[lane + c * 64];
            p = wave_red(p);
            if (lane == 0) zq[(size_t)blk * 24 + q] = p;
        }
    } else {  // id token: 8 zik + 8 ziv + 12 W_idk dots, then IDK
        const int m = blk - 3200;
        const float* xr = id + (size_t)m * CD;
#pragma unroll
        for (int t = 0; t < 7; ++t) {
            const int q = wv * 7 + t;
            const float* ar = (q < 8) ? Aik + (size_t)q * CD
                            : (q < 16) ? Aiv + (size_t)(q - 8) * CD
                                       : Wik + (size_t)(q - 16) * CD;
            float p = 0.f;
#pragma unroll
            for (int c = 0; c < 12; ++c) p += xr[lane + c * 64] * ar[lane + c * 64];
            p = wave_red(p);
            if (lane == 0) dres[q] = p;
        }
        __syncthreads();
        if (tid < 8) ziv[(size_t)m * 8 + tid] = dres[8 + tid];
        if (tid < 12) {
            float v = dres[16 + tid] + bik[tid];
            float lo = 0.f;
#pragma unroll
            for (int r = 0; r < 8; ++r) lo += dres[r] * Bik[tid * 8 + r];
            IDK[m * NH + tid] = v + 0.125f * lo;
        }
    }
}

// ---------------- stage_all: every bf16 staging conversion in one launch ----------------
__global__ __launch_bounds__(256) void stage_all(const float* __restrict__ x,
                                                 const float* __restrict__ zq,
                                                 u16* __restrict__ x_aug,
                                                 const float* __restrict__ Wq,
                                                 const float* __restrict__ Bq,
                                                 u16* __restrict__ wqkv_aug,
                                                 const float* __restrict__ Wp,
                                                 const float* __restrict__ Bp,
                                                 u16* __restrict__ wproj_aug,
                                                 const float* __restrict__ mk,
                                                 u16* __restrict__ kseq,
                                                 const float* __restrict__ mv,
                                                 u16* __restrict__ vt,
                                                 const float* __restrict__ id,
                                                 const float* __restrict__ ziv,
                                                 u16* __restrict__ id_aug,
                                                 const float* __restrict__ Widv,
                                                 const float* __restrict__ Bidv,
                                                 u16* __restrict__ widv_aug) {
    __shared__ float tile[64][65];
    const int blk = blockIdx.x;
    const int tid = threadIdx.x;
    if (blk < 1250) {  // x_aug: [x | zq | 0]
        const int idx = blk * 256 + tid;
        const int m = idx / 100, c8 = idx - m * 100;
        short8 v;
        if (c8 < 96) {
            const float* s = x + (size_t)m * CD + c8 * 8;
#pragma unroll
            for (int i = 0; i < 8; ++i) v[i] = (short)f2b(s[i]);
        } else if (c8 < 99) {
            const float* s = zq + (size_t)m * 24 + (c8 - 96) * 8;
#pragma unroll
            for (int i = 0; i < 8; ++i) v[i] = (short)f2b(s[i]);
        } else {
#pragma unroll
            for (int i = 0; i < 8; ++i) v[i] = 0;
        }
        *(short8*)(x_aug + (size_t)m * 800 + c8 * 8) = v;
    } else if (blk < 2150) {  // wqkv_aug
        const int idx = (blk - 1250) * 256 + tid;
        const int j = idx / 100, c8 = idx - j * 100;
        short8 v;
        if (c8 < 96) {
            const float* s = Wq + (size_t)j * CD + c8 * 8;
#pragma unroll
            for (int i = 0; i < 8; ++i) v[i] = (short)f2b(s[i]);
        } else if (c8 < 99) {
            const int g = j / CD, c = j - g * CD;
            const int gp = c8 - 96;
#pragma unroll
            for (int i = 0; i < 8; ++i)
                v[i] = (gp == g) ? (short)f2b(0.125f * Bq[((size_t)g * CD + c) * 8 + i])
                                 : (short)0;
        } else {
#pragma unroll
            for (int i = 0; i < 8; ++i) v[i] = 0;
        }
        *(short8*)(wqkv_aug + (size_t)j * 800 + c8 * 8) = v;
    } else if (blk < 2450) {  // wproj_aug
        const int idx = (blk - 2150) * 256 + tid;
        const int j = idx / 100, c8 = idx - j * 100;
        short8 v;
        if (c8 < 96) {
            const float* s = Wp + (size_t)j * CD + c8 * 8;
#pragma unroll
            for (int i = 0; i < 8; ++i) v[i] = (short)f2b(s[i]);
        } else {
            const int e = c8 - 96;
#pragma unroll
            for (int i = 0; i < 8; ++i) v[i] = (short)f2b(Bp[((size_t)e * CD + j) * 8 + i]);
        }
        *(short8*)(wproj_aug + (size_t)j * 800 + c8 * 8) = v;
    } else if (blk < 3650) {  // mem_k -> kseq rows 0..1599
        const int t = (blk - 2450) * 256 + tid;
        const size_t e = (size_t)t * 8;
        const size_t bh = e / (1600 * 64);
        const size_t rem = e - bh * (1600 * 64);
        const float4 f0 = *(const float4*)(mk + e);
        const float4 f1 = *(const float4*)(mk + e + 4);
        short8 s;
        s[0] = (short)f2b(f0.x); s[1] = (short)f2b(f0.y);
        s[2] = (short)f2b(f0.z); s[3] = (short)f2b(f0.w);
        s[4] = (short)f2b(f1.x); s[5] = (short)f2b(f1.y);
        s[6] = (short)f2b(f1.z); s[7] = (short)f2b(f1.w);
        *(short8*)(kseq + bh * (3200 * 64) + rem) = s;
    } else if (blk < 4250) {  // mem_v -> VT cols 0..1599 (transpose)
        const int i = blk - 3650;
        const int kt = i % 25, bh = i / 25;
        const int r = tid >> 2, c0 = (tid & 3) * 16;
        const float* src = mv + ((size_t)bh * 1600 + (size_t)kt * 64 + r) * 64 + c0;
#pragma unroll
        for (int q = 0; q < 4; ++q) {
            const float4 f = *(const float4*)(src + q * 4);
            tile[r][c0 + q * 4 + 0] = f.x;
            tile[r][c0 + q * 4 + 1] = f.y;
            tile[r][c0 + q * 4 + 2] = f.z;
            tile[r][c0 + q * 4 + 3] = f.w;
        }
        __syncthreads();
        short8 s0, s1;
#pragma unroll
        for (int q = 0; q < 8; ++q) s0[q] = (short)f2b(tile[c0 + q][r]);
#pragma unroll
        for (int q = 0; q < 8; ++q) s1[q] = (short)f2b(tile[c0 + 8 + q][r]);
        u16* dst = vt + ((size_t)bh * 64 + r) * 3200 + (size_t)kt * 64 + c0;
        *(short8*)dst = s0;
        *(short8*)(dst + 8) = s1;
    } else if (blk < 4700) {  // id_aug: [id | ziv | 0]
        const int idx = (blk - 4250) * 256 + tid;  // 115200
        const int m = idx / 100, c8 = idx - m * 100;
        short8 v;
        if (c8 < 96) {
            const float* s = id + (size_t)m * CD + c8 * 8;
#pragma unroll
            for (int i = 0; i < 8; ++i) v[i] = (short)f2b(s[i]);
        } else if (c8 == 96) {
            const float* s = ziv + (size_t)m * 8;
#pragma unroll
            for (int i = 0; i < 8; ++i) v[i] = (short)f2b(s[i]);
        } else {
#pragma unroll
            for (int i = 0; i < 8; ++i) v[i] = 0;
        }
        *(short8*)(id_aug + (size_t)m * 800 + c8 * 8) = v;
    } else {  // widv_aug
        const int idx = (blk - 4700) * 256 + tid;  // 76800
        const int j = idx / 100, c8 = idx - j * 100;
        short8 v;
        if (c8 < 96) {
            const float* s = Widv + (size_t)j * CD + c8 * 8;
#pragma unroll
            for (int i = 0; i < 8; ++i) v[i] = (short)f2b(s[i]);
        } else if (c8 == 96) {
#pragma unroll
            for (int i = 0; i < 8; ++i) v[i] = (short)f2b(0.125f * Bidv[(size_t)j * 8 + i]);
        } else {
#pragma unroll
            for (int i = 0; i < 8; ++i) v[i] = 0;
        }
        *(short8*)(widv_aug + (size_t)j * 800 + c8 * 8) = v;
    }
}

// ---------------- MFMA GEMM, K=800 augmented ----------------
// MODE 0: qkv 128x128, 256 thr. MODE 1: proj 64x128, 128 thr, f32 out.
// MODE 2: idv 64x128, 128 thr, scatter into ovm.
template <int MODE>
__global__ __launch_bounds__(MODE == 0 ? 256 : 128) void
gemm16_kernel(const u16* __restrict__ A16, const u16* __restrict__ B16,
              const float* __restrict__ bias, const float* __restrict__ IDK,
              u16* __restrict__ qbh, u16* __restrict__ kseq, u16* __restrict__ vt,
              float* __restrict__ okm, float* __restrict__ ovm,
              float* __restrict__ io) {
    const int tid = threadIdx.x;
    const int lane = tid & 63, wv = tid >> 6;
    const int quad = lane >> 4, n16 = lane & 15;
    int m0, n0;
    if (MODE == 0) {
        m0 = blockIdx.y * 128 + (wv >> 1) * 64;
        n0 = blockIdx.x * 128 + (wv & 1) * 64;
    } else {
        m0 = blockIdx.y * 64;
        n0 = blockIdx.x * 128 + wv * 64;
    }

    f32x4 acc[4][4];
#pragma unroll
    for (int a = 0; a < 4; ++a)
#pragma unroll
        for (int b = 0; b < 4; ++b) acc[a][b] = (f32x4){0.f, 0.f, 0.f, 0.f};

    const u16* ap = A16 + (size_t)(m0 + n16) * 800 + quad * 8;
    const u16* bp = B16 + (size_t)(n0 + n16) * 800 + quad * 8;
#pragma unroll 2
    for (int k0 = 0; k0 < 800; k0 += 32) {
        short8 aA[4], aB[4];
#pragma unroll
        for (int c = 0; c < 4; ++c) {
            aA[c] = *(const short8*)(ap + (size_t)c * 16 * 800 + k0);
            aB[c] = *(const short8*)(bp + (size_t)c * 16 * 800 + k0);
        }
#pragma unroll
        for (int mc = 0; mc < 4; ++mc)
#pragma unroll
            for (int nc = 0; nc < 4; ++nc)
                acc[mc][nc] =
                    __builtin_amdgcn_mfma_f32_16x16x32_bf16(aA[mc], aB[nc], acc[mc][nc], 0, 0, 0);
    }

    if (MODE == 0) {
        const int g = n0 / CD;
        const int hq = (n0 % CD) >> 6;
#pragma unroll
        for (int mc = 0; mc < 4; ++mc) {
#pragma unroll
            for (int r = 0; r < 4; ++r) {
                const int m = m0 + mc * 16 + quad * 4 + r;
                const int b = m / NTOK, n = m - (m / NTOK) * NTOK;
                const size_t bh = (size_t)(b * NH + hq);
                float gate = 0.f;
                if (g == 1 && n < NM) gate = 1.f + tanhf(IDK[(b * NM + n) * NH + hq]);
#pragma unroll
                for (int nc = 0; nc < 4; ++nc) {
                    const int d = nc * 16 + n16;
                    const int j = n0 + d;
                    const float val = acc[mc][nc][r] + bias[j];
                    const size_t om = (bh * NM + n) * 64 + d;
                    if (g == 0) {
                        qbh[(bh * NTOK + n) * 64 + d] = f2b(val * 0.125f);
                    } else if (g == 1) {
                        kseq[(bh * 3200 + 1600 + n) * 64 + d] = f2b(val);
                        if (n < NM) okm[om] = val * gate;
                    } else {
                        float vv = val;
                        if (n < NM) {
                            vv = val + ovm[om];
                            ovm[om] = vv;
                        }
                        vt[(bh * 64 + d) * 3200 + 1600 + n] = f2b(vv);
                    }
                }
            }
        }
    } else if (MODE == 1) {
#pragma unroll
        for (int mc = 0; mc < 4; ++mc) {
#pragma unroll
            for (int r = 0; r < 4; ++r) {
                const int m = m0 + mc * 16 + quad * 4 + r;
#pragma unroll
                for (int nc = 0; nc < 4; ++nc) {
                    const int j = n0 + nc * 16 + n16;
                    io[(size_t)m * CD + j] = acc[mc][nc][r] + bias[j];
                }
            }
        }
    } else {  // MODE 2: idv -> ovm scatter
#pragma unroll
        for (int mc = 0; mc < 4; ++mc) {
#pragma unroll
            for (int r = 0; r < 4; ++r) {
                const int m = m0 + mc * 16 + quad * 4 + r;
                const int b = m / NM, n = m - (m / NM) * NM;
#pragma unroll
                for (int nc = 0; nc < 4; ++nc) {
                    const int j = n0 + nc * 16 + n16;
                    const int h = j >> 6, d = j & 63;
                    ovm[(((size_t)(b * NH + h)) * NM + n) * 64 + d] = acc[mc][nc][r] + bias[j];
                }
            }
        }
    }
}

// ---------------- v8 top-k attention: register-resident selection ----------------
// 512 thr, 16 q rows. Logits live in VGPRs (pk). LDS: wgt (weights for PV) +
// 2-replica hist + small scalars. All loops compile-time, unrolled.
template <int L, bool KF32>
__global__ __launch_bounds__(512) void attn8_kernel(const u16* __restrict__ qbh,
                                                    const u16* __restrict__ Kb,
                                                    const float* __restrict__ Kf,
                                                    const u16* __restrict__ vt,
                                                    float* __restrict__ aob,
                                                    int top, int row_start, int krows,
                                                    int vtoff) {
    constexpr int LP = L + 8;
    constexpr int NCHT = L / 16;
    constexpr int NCH = (NCHT + 7) / 8;
    extern __shared__ __align__(16) u16 smem[];
    u16* wgt = smem;                          // 16*LP u16
    u32* hist = (u32*)(smem + 16 * LP);       // 2 replicas x 16 x 256 u32
    float* obuf = (float*)hist;               // alias (PV phase)
    float* rowmax = (float*)(hist + 8192);    // 128
    float* invtot = rowmax + 128;             // 16 (tot, then 1/tot)
    float* Mrow = invtot + 16;                // 16
    u32* selb = (u32*)(Mrow + 16);            // 16
    u32* Trow = selb + 16;                    // 16
    u32* wantr = Trow + 16;                   // 16

    const int tid = threadIdx.x;
    const int lane = tid & 63, wv = tid >> 6;
    const int quad = lane >> 4, n16 = lane & 15;
    const int rep = (n16 & 1) * 4096;
    const int bh = blockIdx.y;
    const int bb = bh / NH, hh = bh - bb * NH;
    const int r0 = row_start + blockIdx.x * 16;

    for (int i = tid; i < 8192; i += 512) hist[i] = 0;

    short8 aQ0, aQ1;
    {
        const u16* qp = qbh + ((size_t)bh * NTOK + r0 + n16) * 64;
        aQ0 = *(const short8*)(qp + quad * 8);
        aQ1 = *(const short8*)(qp + 32 + quad * 8);
    }
    __syncthreads();  // hist zero visible

    // ---- phase 1: QK^T MFMA; logits stay in regs; coarse hist from regs ----
    u32 pk[NCH][2];
    float rmax[4] = {-3.4e38f, -3.4e38f, -3.4e38f, -3.4e38f};
#pragma unroll
    for (int i = 0; i < NCH; ++i) {
        pk[i][0] = 0u; pk[i][1] = 0u;
        const int c = wv + i * 8;
        if (c < NCHT) {
            const int l0 = c << 4;
            short8 fb0, fb1;
            if (KF32) {
                const float* kp = Kf + ((size_t)bh * krows + l0 + n16) * 64 + quad * 8;
                const float4 x0 = *(const float4*)kp;
                const float4 x1 = *(const float4*)(kp + 4);
                const float4 y0 = *(const float4*)(kp + 32);
                const float4 y1 = *(const float4*)(kp + 36);
                fb0[0] = (short)f2b(x0.x); fb0[1] = (short)f2b(x0.y);
                fb0[2] = (short)f2b(x0.z); fb0[3] = (short)f2b(x0.w);
                fb0[4] = (short)f2b(x1.x); fb0[5] = (short)f2b(x1.y);
                fb0[6] = (short)f2b(x1.z); fb0[7] = (short)f2b(x1.w);
                fb1[0] = (short)f2b(y0.x); fb1[1] = (short)f2b(y0.y);
                fb1[2] = (short)f2b(y0.z); fb1[3] = (short)f2b(y0.w);
                fb1[4] = (short)f2b(y1.x); fb1[5] = (short)f2b(y1.y);
                fb1[6] = (short)f2b(y1.z); fb1[7] = (short)f2b(y1.w);
            } else {
                const u16* kp = Kb + ((size_t)bh * krows + l0 + n16) * 64 + quad * 8;
                fb0 = *(const short8*)kp;
                fb1 = *(const short8*)(kp + 32);
            }
            f32x4 d = {0.f, 0.f, 0.f, 0.f};
            d = __builtin_amdgcn_mfma_f32_16x16x32_bf16(aQ0, fb0, d, 0, 0, 0);
            d = __builtin_amdgcn_mfma_f32_16x16x32_bf16(aQ1, fb1, d, 0, 0, 0);
            const u16 w0 = f2b(d[0]), w1 = f2b(d[1]), w2 = f2b(d[2]), w3 = f2b(d[3]);
#pragma unroll
            for (int r = 0; r < 4; ++r) rmax[r] = fmaxf(rmax[r], d[r]);
            pk[i][0] = (u32)w0 | ((u32)w1 << 16);
            pk[i][1] = (u32)w2 | ((u32)w3 << 16);
            atomicAdd(&hist[rep + (quad * 4 + 0) * 256 + (flip16((u32)w0) >> 8)], 1u);
            atomicAdd(&hist[rep + (quad * 4 + 1) * 256 + (flip16((u32)w1) >> 8)], 1u);
            atomicAdd(&hist[rep + (quad * 4 + 2) * 256 + (flip16((u32)w2) >> 8)], 1u);
            atomicAdd(&hist[rep + (quad * 4 + 3) * 256 + (flip16((u32)w3) >> 8)], 1u);
        }
    }
#pragma unroll
    for (int off = 1; off < 16; off <<= 1) {
#pragma unroll
        for (int r = 0; r < 4; ++r) rmax[r] = fmaxf(rmax[r], __shfl_xor(rmax[r], off));
    }
    if (n16 == 0) {
#pragma unroll
        for (int r = 0; r < 4; ++r) rowmax[wv * 16 + quad * 4 + r] = rmax[r];
    }
    __syncthreads();

    // ---- scan0: wave per row (rows wv, wv+8) ----
#pragma unroll
    for (int rp = 0; rp < 2; ++rp) {
        const int rr = wv + 8 * rp;
        float M = -3.4e38f;
#pragma unroll
        for (int w = 0; w < 8; ++w) M = fmaxf(M, rowmax[w * 16 + rr]);
        if (lane == 0) Mrow[rr] = M;
        u32 hh4[4];
#pragma unroll
        for (int j = 0; j < 4; ++j)
            hh4[j] = hist[rr * 256 + 4 * lane + j] + hist[4096 + rr * 256 + 4 * lane + j];
        const u32 s = hh4[0] + hh4[1] + hh4[2] + hh4[3];
        u32 sum = s;
#pragma unroll
        for (int off = 1; off < 64; off <<= 1) {
            const u32 t = __shfl_down(sum, off);
            if (lane + off < 64) sum += t;
        }
        int cnt = (int)(sum - s);
        const int want = top;
        for (int j = 3; j >= 0; --j) {
            const int c = (int)hh4[j];
            if (cnt < want && cnt + c >= want) {
                selb[rr] = (u32)(4 * lane + j);
                wantr[rr] = (u32)(want - cnt);
            }
            cnt += c;
        }
    }
    __syncthreads();
    for (int i = tid; i < 8192; i += 512) hist[i] = 0;
    __syncthreads();

    // ---- round 1 from registers ----
    {
        u32 sl[4];
#pragma unroll
        for (int r = 0; r < 4; ++r) sl[r] = selb[quad * 4 + r];
#pragma unroll
        for (int i = 0; i < NCH; ++i) {
            const int c = wv + i * 8;
            if (c < NCHT) {
#pragma unroll
                for (int h = 0; h < 2; ++h) {
                    const u32 pr = pk[i][h];
                    const u32 k0 = flip16(pr & 0xffffu), k1 = flip16(pr >> 16);
                    const int r0i = quad * 4 + 2 * h, r1i = r0i + 1;
                    if ((k0 >> 8) == sl[2 * h])
                        atomicAdd(&hist[rep + r0i * 256 + (k0 & 255u)], 1u);
                    if ((k1 >> 8) == sl[2 * h + 1])
                        atomicAdd(&hist[rep + r1i * 256 + (k1 & 255u)], 1u);
                }
            }
        }
    }
    __syncthreads();

    // ---- scan1: T, wantT; init tot with tie term ----
#pragma unroll
    for (int rp = 0; rp < 2; ++rp) {
        const int rr = wv + 8 * rp;
        u32 hh4[4];
#pragma unroll
        for (int j = 0; j < 4; ++j)
            hh4[j] = hist[rr * 256 + 4 * lane + j] + hist[4096 + rr * 256 + 4 * lane + j];
        const u32 s = hh4[0] + hh4[1] + hh4[2] + hh4[3];
        u32 sum = s;
#pragma unroll
        for (int off = 1; off < 64; off <<= 1) {
            const u32 t = __shfl_down(sum, off);
            if (lane + off < 64) sum += t;
        }
        int cnt = (int)(sum - s);
        const int want = (int)wantr[rr];
        for (int j = 3; j >= 0; --j) {
            const int c = (int)hh4[j];
            if (cnt < want && cnt + c >= want) {
                const u32 T = (selb[rr] << 8) | (u32)(4 * lane + j);
                Trow[rr] = T;
                invtot[rr] =
                    (float)(want - cnt) * __expf(fminf(key2f(T) - Mrow[rr], 0.f));
            }
            cnt += c;
        }
    }
    __syncthreads();

    // ---- ps pass from registers; convert logits -> exp (unnormalized) in regs ----
    {
        u32 Tq[4];
        float Mq[4];
#pragma unroll
        for (int r = 0; r < 4; ++r) {
            Tq[r] = Trow[quad * 4 + r];
            Mq[r] = Mrow[quad * 4 + r];
        }
        float ps[4] = {0.f, 0.f, 0.f, 0.f};
#pragma unroll
        for (int i = 0; i < NCH; ++i) {
            const int c = wv + i * 8;
            if (c < NCHT) {
#pragma unroll
                for (int h = 0; h < 2; ++h) {
                    const u32 pr = pk[i][h];
                    const int r0i = 2 * h, r1i = 2 * h + 1;
                    const u32 k0 = flip16(pr & 0xffffu), k1 = flip16(pr >> 16);
                    float e0 = 0.f, e1 = 0.f;
                    if (k0 >= Tq[r0i]) {
                        e0 = __expf(fminf(b2f((u16)(pr & 0xffffu)) - Mq[r0i], 0.f));
                        if (k0 > Tq[r0i]) ps[r0i] += e0;
                    }
                    if (k1 >= Tq[r1i]) {
                        e1 = __expf(fminf(b2f((u16)(pr >> 16)) - Mq[r1i], 0.f));
                        if (k1 > Tq[r1i]) ps[r1i] += e1;
                    }
                    pk[i][h] = (u32)f2b(e0) | ((u32)f2b(e1) << 16);
                }
            }
        }
#pragma unroll
        for (int off = 1; off < 16; off <<= 1) {
#pragma unroll
            for (int r = 0; r < 4; ++r) ps[r] += __shfl_xor(ps[r], off);
        }
        if (n16 == 0) {
#pragma unroll
            for (int r = 0; r < 4; ++r) atomicAdd(&invtot[quad * 4 + r], ps[r]);
        }
    }
    __syncthreads();
    if (tid < 16) invtot[tid] = 1.f / fmaxf(invtot[tid], 1e-30f);
    __syncthreads();

    // ---- write normalized weights into wgt[row][key] for PV ----
    {
        float iv[4];
#pragma unroll
        for (int r = 0; r < 4; ++r) iv[r] = invtot[quad * 4 + r];
#pragma unroll
        for (int i = 0; i < NCH; ++i) {
            const int c = wv + i * 8;
            if (c < NCHT) {
                const int l = (c << 4) + n16;
#pragma unroll
                for (int h = 0; h < 2; ++h) {
                    const u32 pr = pk[i][h];
                    wgt[(size_t)(quad * 4 + 2 * h) * LP + l] =
                        f2b(b2f((u16)(pr & 0xffffu)) * iv[2 * h]);
                    wgt[(size_t)(quad * 4 + 2 * h + 1) * LP + l] =
                        f2b(b2f((u16)(pr >> 16)) * iv[2 * h + 1]);
                }
            }
        }
    }
    __syncthreads();

    // ---- PV via MFMA (weights already normalized) ----
    {
        const int half = wv & 1, dc = wv >> 1;
        constexpr int PVI = (L / 2) / 32;
        const int kbeg = half * (L / 2);
        const u16* vp =
            vt + ((size_t)bh * 64 + dc * 16 + n16) * 3200 + vtoff + quad * 8 + kbeg;
        const u16* wrow2 = wgt + (size_t)n16 * LP + quad * 8 + kbeg;
        f32x4 acc = {0.f, 0.f, 0.f, 0.f};
#pragma unroll 4
        for (int i = 0; i < PVI; ++i) {
            const short8 a = *(const short8*)(wrow2 + i * 32);
            const short8 bf = *(const short8*)(vp + i * 32);
            acc = __builtin_amdgcn_mfma_f32_16x16x32_bf16(a, bf, acc, 0, 0, 0);
        }
#pragma unroll
        for (int r = 0; r < 4; ++r) {
            const int rowi = quad * 4 + r;
            obuf[(half * 16 + rowi) * 64 + dc * 16 + n16] = acc[r];
        }
    }
    __syncthreads();
#pragma unroll
    for (int ii = 0; ii < 2; ++ii) {
        const int idx = tid + ii * 512;
        const int rowi = idx >> 6, dd = idx & 63;
        aob[((size_t)bb * NTOK + r0 + rowi) * CD + hh * 64 + dd] =
            obuf[rowi * 64 + dd] + obuf[(16 + rowi) * 64 + dd];
    }
}

// ---------------- proj routing coefficients ----------------
__global__ __launch_bounds__(256) void coef_kernel(const float* __restrict__ aob,
                                                   const float* __restrict__ rW,
                                                   const float* __restrict__ Ap,
                                                   float* __restrict__ coef) {
    __shared__ float rl[8][4];
    __shared__ float rw[8][4];
    const int slot = threadIdx.x >> 5, lane = threadIdx.x & 31;
    const int m = blockIdx.x * 8 + slot;
    const float* xr = aob + (size_t)m * CD;
    const float z = dot768_ff(xr, Ap + (size_t)lane * CD);
    if (lane < 4) rl[slot][lane] = dot768_ff(xr, rW + (size_t)lane * CD);
    __syncthreads();
    if (lane == 0) {
        const float mx = fmaxf(fmaxf(rl[slot][0], rl[slot][1]), fmaxf(rl[slot][2], rl[slot][3]));
        const float e0 = __expf(rl[slot][0] - mx), e1 = __expf(rl[slot][1] - mx);
        const float e2 = __expf(rl[slot][2] - mx), e3 = __expf(rl[slot][3] - mx);
        const float is = 1.f / (e0 + e1 + e2 + e3);
        rw[slot][0] = e0 * is; rw[slot][1] = e1 * is; rw[slot][2] = e2 * is; rw[slot][3] = e3 * is;
    }
    __syncthreads();
    coef[(size_t)m * 32 + lane] = rw[slot][lane >> 3] * z * 0.125f;
}

// ---------------- aob_aug builder ----------------
__global__ __launch_bounds__(256) void cvt_aobaug(const float* __restrict__ aob,
                                                  const float* __restrict__ coef,
                                                  u16* __restrict__ dst) {
    const int idx = blockIdx.x * 256 + threadIdx.x;  // 320000
    const int m = idx / 100, c8 = idx - m * 100;
    short8 v;
    if (c8 < 96) {
        const float* s = aob + (size_t)m * CD + c8 * 8;
#pragma unroll
        for (int i = 0; i < 8; ++i) v[i] = (short)f2b(s[i]);
    } else {
        const float* s = coef + (size_t)m * 32 + (c8 - 96) * 8;
#pragma unroll
        for (int i = 0; i < 8; ++i) v[i] = (short)f2b(s[i]);
    }
    *(short8*)(dst + (size_t)m * 800 + c8 * 8) = v;
}

extern "C" void kernel_launch(void* const* d_in, const int* in_sizes, int n_in,
                              void* d_out, int out_size, void* d_ws, size_t ws_size,
                              hipStream_t stream) {
    const float* x = (const float*)d_in[0];
    const float* id_total = (const float*)d_in[1];
    const float* mem_k = (const float*)d_in[2];
    const float* mem_v = (const float*)d_in[3];
    const float* W_qkv = (const float*)d_in[4];
    const float* b_qkv = (const float*)d_in[5];
    const float* A_qkv = (const float*)d_in[6];
    const float* B_qkv = (const float*)d_in[7];
    const float* W_proj = (const float*)d_in[8];
    const float* b_proj = (const float*)d_in[9];
    const float* routeW_proj = (const float*)d_in[10];
    const float* A_proj = (const float*)d_in[11];
    const float* B_proj = (const float*)d_in[12];
    const float* W_idk = (const float*)d_in[13];
    const float* b_idk = (const float*)d_in[14];
    const float* A_idk = (const float*)d_in[16];
    const float* B_idk = (const float*)d_in[17];
    const float* W_idv = (const float*)d_in[18];
    const float* b_idv = (const float*)d_in[19];
    const float* A_idv = (const float*)d_in[21];
    const float* B_idv = (const float*)d_in[22];

    float* io = (float*)d_out;                       // staging -> aob -> final out
    float* o_km = io + (size_t)BN * NTOK * CD;       // f32 k_m (& mem-attn K); widv_aug first
    float* o_vm = o_km + (size_t)BN * NH * NM * HD;  // f32 ID_V -> v_m

    u16* x_aug = (u16*)io;            // 3200*800 u16
    u16* wqkv_aug = x_aug + 2560000;  // 2304*800 u16 (io region total 8.8 MB <= 9.83 MB)
    u16* widv_aug = (u16*)o_km;       // 768*800 u16 = 1.23 MB <= 3.54 MB (dead pre-qkv)

    // workspace: 26,613,760 bytes
    u16* qbh = (u16*)d_ws;                  // (B,H,N,64) Q bf16; id_aug first
    u16* kseq = qbh + 2457600;              // (B,H,3200,64); later aob_aug
    u16* vt = kseq + 4915200;               // (B,H,64,3200) V^T
    float* zq = (float*)(vt + 4915200);     // 76800
    float* ziv = zq + 76800;                // 9216
    float* IDK = ziv + 9216;                // 13824
    float* coef = IDK + 13824;              // 102400
    u16* wproj_aug = (u16*)(coef + 102400); // 768*800 u16
    u16* id_aug = qbh;                      // 1152*800 u16 (dead pre-qkv)

    const int smem_seq = 16 * (3200 + 8) * 2 + 33600;  // 136,256
    const int smem_mem = 16 * (NM + 8) * 2 + 33600;    // 52,288
    hipFuncSetAttribute((const void*)attn8_kernel<3200, false>,
                        hipFuncAttributeMaxDynamicSharedMemorySize, smem_seq);
    hipFuncSetAttribute((const void*)attn8_kernel<NM, true>,
                        hipFuncAttributeMaxDynamicSharedMemorySize, smem_mem);

    small_dots<<<4352, 256, 0, stream>>>(x, A_qkv, zq, id_total, A_idk, A_idv,
                                         W_idk, b_idk, B_idk, ziv, IDK);
    stage_all<<<5000, 256, 0, stream>>>(x, zq, x_aug, W_qkv, B_qkv, wqkv_aug,
                                        W_proj, B_proj, wproj_aug, mem_k, kseq,
                                        mem_v, vt, id_total, ziv, id_aug,
                                        W_idv, B_idv, widv_aug);
    // ID_V via MFMA -> o_vm
    gemm16_kernel<2><<<dim3(6, 18), 128, 0, stream>>>(id_aug, widv_aug, b_idv, nullptr,
                                                      nullptr, nullptr, nullptr, nullptr,
                                                      o_vm, nullptr);
    // qkv via MFMA, fused LoRA + gate/ID_V epilogue
    gemm16_kernel<0><<<dim3(18, 25), 256, 0, stream>>>(x_aug, wqkv_aug, b_qkv, IDK,
                                                       qbh, kseq, vt, o_km, o_vm, nullptr);

    // memory attention: L=576, top=288, K=o_km (f32), V=VT cols 1600..2175
    attn8_kernel<NM, true><<<dim3(NM / 16, BN * NH), 512, smem_mem, stream>>>(
        qbh, nullptr, o_km, vt, io, NM / 2, 0, NM, 1600);
    // seq attention: L=3200, top=1600, K=kseq, V=VT cols 0..3199
    attn8_kernel<3200, false><<<dim3(NS / 16, BN * NH), 512, smem_seq, stream>>>(
        qbh, kseq, nullptr, vt, io, 1600, NM, 3200, 0);

    coef_kernel<<<400, 256, 0, stream>>>(io, routeW_proj, A_proj, coef);
    cvt_aobaug<<<1250, 256, 0, stream>>>(io, coef, kseq);
    // proj via MFMA, fused routed-LoRA, f32 out in-place
    gemm16_kernel<1><<<dim3(6, 50), 128, 0, stream>>>(kseq, wproj_aug, b_proj, nullptr,
                                                      nullptr, nullptr, nullptr, nullptr,
                                                      nullptr, io);
}

// Round 9
// 667.518 us; speedup vs baseline: 11.0089x; 1.0248x over previous
//
#include <hip/hip_runtime.h>
#include <hip/hip_bf16.h>

#define BN 2
#define NH 12
#define NTOK 1600
#define NM 576
#define NS 1024
#define CD 768
#define HD 64

typedef unsigned short u16;
typedef unsigned int u32;
typedef __attribute__((ext_vector_type(8))) short short8;   // 8 bf16 (4 VGPRs)
typedef __attribute__((ext_vector_type(4))) float f32x4;    // MFMA C/D

__device__ __forceinline__ float fbits(u32 u) { return __uint_as_float(u); }
__device__ __forceinline__ u16 f2b(float f) {  // RNE f32->bf16
    u32 u = __float_as_uint(f);
    u32 r = u + 0x7FFFu + ((u >> 16) & 1u);
    return (u16)(r >> 16);
}
__device__ __forceinline__ float b2f(u16 s) { return fbits(((u32)s) << 16); }
__device__ __forceinline__ u32 flip16(u32 u) {  // order-preserving bf16 -> u16 key
    return (u & 0x8000u) ? (0xFFFFu & ~u) : (u | 0x8000u);
}
__device__ __forceinline__ float key2f(u32 k) {
    u32 b = (k & 0x8000u) ? (k & 0x7FFFu) : (0xFFFFu & ~k);
    return fbits(b << 16);
}
__device__ __forceinline__ float wave_red(float p) {
#pragma unroll
    for (int off = 1; off < 64; off <<= 1) p += __shfl_xor(p, off);
    return p;
}

__device__ __forceinline__ float dot768_ff(const float* __restrict__ a,
                                           const float* __restrict__ b) {
    float s = 0.f;
    for (int c = 0; c < CD; c += 4) {
        float4 fa = *(const float4*)(a + c);
        float4 fb = *(const float4*)(b + c);
        s += fa.x * fb.x + fa.y * fb.y + fa.z * fb.z + fa.w * fb.w;
    }
    return s;
}

// ---------------- small_dots: z24 (x tokens) + ziv/IDK (id tokens) ----------------
__global__ __launch_bounds__(256) void small_dots(const float* __restrict__ x,
                                                  const float* __restrict__ Aq,
                                                  float* __restrict__ zq,
                                                  const float* __restrict__ id,
                                                  const float* __restrict__ Aik,
                                                  const float* __restrict__ Aiv,
                                                  const float* __restrict__ Wik,
                                                  const float* __restrict__ bik,
                                                  const float* __restrict__ Bik,
                                                  float* __restrict__ ziv,
                                                  float* __restrict__ IDK) {
    __shared__ float dres[28];
    const int blk = blockIdx.x;
    const int tid = threadIdx.x, lane = tid & 63, wv = tid >> 6;
    if (blk < 3200) {  // x token: 24 LoRA dots
        const float* xr = x + (size_t)blk * CD;
#pragma unroll
        for (int t = 0; t < 6; ++t) {
            const int q = wv * 6 + t;
            const float* ar = Aq + (size_t)q * CD;
            float p = 0.f;
#pragma unroll
            for (int c = 0; c < 12; ++c) p += xr[lane + c * 64] * ar[lane + c * 64];
            p = wave_red(p);
            if (lane == 0) zq[(size_t)blk * 24 + q] = p;
        }
    } else {  // id token: 8 zik + 8 ziv + 12 W_idk dots, then IDK
        const int m = blk - 3200;
        const float* xr = id + (size_t)m * CD;
#pragma unroll
        for (int t = 0; t < 7; ++t) {
            const int q = wv * 7 + t;
            const float* ar = (q < 8) ? Aik + (size_t)q * CD
                            : (q < 16) ? Aiv + (size_t)(q - 8) * CD
                                       : Wik + (size_t)(q - 16) * CD;
            float p = 0.f;
#pragma unroll
            for (int c = 0; c < 12; ++c) p += xr[lane + c * 64] * ar[lane + c * 64];
            p = wave_red(p);
            if (lane == 0) dres[q] = p;
        }
        __syncthreads();
        if (tid < 8) ziv[(size_t)m * 8 + tid] = dres[8 + tid];
        if (tid < 12) {
            float v = dres[16 + tid] + bik[tid];
            float lo = 0.f;
#pragma unroll
            for (int r = 0; r < 8; ++r) lo += dres[r] * Bik[tid * 8 + r];
            IDK[m * NH + tid] = v + 0.125f * lo;
        }
    }
}

// ---------------- stage_all: every bf16 staging conversion in one launch ----------------
__global__ __launch_bounds__(256) void stage_all(const float* __restrict__ x,
                                                 const float* __restrict__ zq,
                                                 u16* __restrict__ x_aug,
                                                 const float* __restrict__ Wq,
                                                 const float* __restrict__ Bq,
                                                 u16* __restrict__ wqkv_aug,
                                                 const float* __restrict__ Wp,
                                                 const float* __restrict__ Bp,
                                                 u16* __restrict__ wproj_aug,
                                                 const float* __restrict__ mk,
                                                 u16* __restrict__ kseq,
                                                 const float* __restrict__ mv,
                                                 u16* __restrict__ vt,
                                                 const float* __restrict__ id,
                                                 const float* __restrict__ ziv,
                                                 u16* __restrict__ id_aug,
                                                 const float* __restrict__ Widv,
                                                 const float* __restrict__ Bidv,
                                                 u16* __restrict__ widv_aug) {
    __shared__ float tile[64][65];
    const int blk = blockIdx.x;
    const int tid = threadIdx.x;
    if (blk < 1250) {  // x_aug: [x | zq | 0]
        const int idx = blk * 256 + tid;
        const int m = idx / 100, c8 = idx - m * 100;
        short8 v;
        if (c8 < 96) {
            const float* s = x + (size_t)m * CD + c8 * 8;
#pragma unroll
            for (int i = 0; i < 8; ++i) v[i] = (short)f2b(s[i]);
        } else if (c8 < 99) {
            const float* s = zq + (size_t)m * 24 + (c8 - 96) * 8;
#pragma unroll
            for (int i = 0; i < 8; ++i) v[i] = (short)f2b(s[i]);
        } else {
#pragma unroll
            for (int i = 0; i < 8; ++i) v[i] = 0;
        }
        *(short8*)(x_aug + (size_t)m * 800 + c8 * 8) = v;
    } else if (blk < 2150) {  // wqkv_aug
        const int idx = (blk - 1250) * 256 + tid;
        const int j = idx / 100, c8 = idx - j * 100;
        short8 v;
        if (c8 < 96) {
            const float* s = Wq + (size_t)j * CD + c8 * 8;
#pragma unroll
            for (int i = 0; i < 8; ++i) v[i] = (short)f2b(s[i]);
        } else if (c8 < 99) {
            const int g = j / CD, c = j - g * CD;
            const int gp = c8 - 96;
#pragma unroll
            for (int i = 0; i < 8; ++i)
                v[i] = (gp == g) ? (short)f2b(0.125f * Bq[((size_t)g * CD + c) * 8 + i])
                                 : (short)0;
        } else {
#pragma unroll
            for (int i = 0; i < 8; ++i) v[i] = 0;
        }
        *(short8*)(wqkv_aug + (size_t)j * 800 + c8 * 8) = v;
    } else if (blk < 2450) {  // wproj_aug
        const int idx = (blk - 2150) * 256 + tid;
        const int j = idx / 100, c8 = idx - j * 100;
        short8 v;
        if (c8 < 96) {
            const float* s = Wp + (size_t)j * CD + c8 * 8;
#pragma unroll
            for (int i = 0; i < 8; ++i) v[i] = (short)f2b(s[i]);
        } else {
            const int e = c8 - 96;
#pragma unroll
            for (int i = 0; i < 8; ++i) v[i] = (short)f2b(Bp[((size_t)e * CD + j) * 8 + i]);
        }
        *(short8*)(wproj_aug + (size_t)j * 800 + c8 * 8) = v;
    } else if (blk < 3650) {  // mem_k -> kseq rows 0..1599
        const int t = (blk - 2450) * 256 + tid;
        const size_t e = (size_t)t * 8;
        const size_t bh = e / (1600 * 64);
        const size_t rem = e - bh * (1600 * 64);
        const float4 f0 = *(const float4*)(mk + e);
        const float4 f1 = *(const float4*)(mk + e + 4);
        short8 s;
        s[0] = (short)f2b(f0.x); s[1] = (short)f2b(f0.y);
        s[2] = (short)f2b(f0.z); s[3] = (short)f2b(f0.w);
        s[4] = (short)f2b(f1.x); s[5] = (short)f2b(f1.y);
        s[6] = (short)f2b(f1.z); s[7] = (short)f2b(f1.w);
        *(short8*)(kseq + bh * (3200 * 64) + rem) = s;
    } else if (blk < 4250) {  // mem_v -> VT cols 0..1599 (transpose)
        const int i = blk - 3650;
        const int kt = i % 25, bh = i / 25;
        const int r = tid >> 2, c0 = (tid & 3) * 16;
        const float* src = mv + ((size_t)bh * 1600 + (size_t)kt * 64 + r) * 64 + c0;
#pragma unroll
        for (int q = 0; q < 4; ++q) {
            const float4 f = *(const float4*)(src + q * 4);
            tile[r][c0 + q * 4 + 0] = f.x;
            tile[r][c0 + q * 4 + 1] = f.y;
            tile[r][c0 + q * 4 + 2] = f.z;
            tile[r][c0 + q * 4 + 3] = f.w;
        }
        __syncthreads();
        short8 s0, s1;
#pragma unroll
        for (int q = 0; q < 8; ++q) s0[q] = (short)f2b(tile[c0 + q][r]);
#pragma unroll
        for (int q = 0; q < 8; ++q) s1[q] = (short)f2b(tile[c0 + 8 + q][r]);
        u16* dst = vt + ((size_t)bh * 64 + r) * 3200 + (size_t)kt * 64 + c0;
        *(short8*)dst = s0;
        *(short8*)(dst + 8) = s1;
    } else if (blk < 4700) {  // id_aug: [id | ziv | 0]
        const int idx = (blk - 4250) * 256 + tid;  // 115200
        const int m = idx / 100, c8 = idx - m * 100;
        short8 v;
        if (c8 < 96) {
            const float* s = id + (size_t)m * CD + c8 * 8;
#pragma unroll
            for (int i = 0; i < 8; ++i) v[i] = (short)f2b(s[i]);
        } else if (c8 == 96) {
            const float* s = ziv + (size_t)m * 8;
#pragma unroll
            for (int i = 0; i < 8; ++i) v[i] = (short)f2b(s[i]);
        } else {
#pragma unroll
            for (int i = 0; i < 8; ++i) v[i] = 0;
        }
        *(short8*)(id_aug + (size_t)m * 800 + c8 * 8) = v;
    } else {  // widv_aug
        const int idx = (blk - 4700) * 256 + tid;  // 76800
        const int j = idx / 100, c8 = idx - j * 100;
        short8 v;
        if (c8 < 96) {
            const float* s = Widv + (size_t)j * CD + c8 * 8;
#pragma unroll
            for (int i = 0; i < 8; ++i) v[i] = (short)f2b(s[i]);
        } else if (c8 == 96) {
#pragma unroll
            for (int i = 0; i < 8; ++i) v[i] = (short)f2b(0.125f * Bidv[(size_t)j * 8 + i]);
        } else {
#pragma unroll
            for (int i = 0; i < 8; ++i) v[i] = 0;
        }
        *(short8*)(widv_aug + (size_t)j * 800 + c8 * 8) = v;
    }
}

// ---------------- MFMA GEMM, K=800 augmented ----------------
template <int MODE>
__global__ __launch_bounds__(MODE == 0 ? 256 : 128) void
gemm16_kernel(const u16* __restrict__ A16, const u16* __restrict__ B16,
              const float* __restrict__ bias, const float* __restrict__ IDK,
              u16* __restrict__ qbh, u16* __restrict__ kseq, u16* __restrict__ vt,
              float* __restrict__ okm, float* __restrict__ ovm,
              float* __restrict__ io) {
    const int tid = threadIdx.x;
    const int lane = tid & 63, wv = tid >> 6;
    const int quad = lane >> 4, n16 = lane & 15;
    int m0, n0;
    if (MODE == 0) {
        m0 = blockIdx.y * 128 + (wv >> 1) * 64;
        n0 = blockIdx.x * 128 + (wv & 1) * 64;
    } else {
        m0 = blockIdx.y * 64;
        n0 = blockIdx.x * 128 + wv * 64;
    }

    f32x4 acc[4][4];
#pragma unroll
    for (int a = 0; a < 4; ++a)
#pragma unroll
        for (int b = 0; b < 4; ++b) acc[a][b] = (f32x4){0.f, 0.f, 0.f, 0.f};

    const u16* ap = A16 + (size_t)(m0 + n16) * 800 + quad * 8;
    const u16* bp = B16 + (size_t)(n0 + n16) * 800 + quad * 8;
#pragma unroll 2
    for (int k0 = 0; k0 < 800; k0 += 32) {
        short8 aA[4], aB[4];
#pragma unroll
        for (int c = 0; c < 4; ++c) {
            aA[c] = *(const short8*)(ap + (size_t)c * 16 * 800 + k0);
            aB[c] = *(const short8*)(bp + (size_t)c * 16 * 800 + k0);
        }
#pragma unroll
        for (int mc = 0; mc < 4; ++mc)
#pragma unroll
            for (int nc = 0; nc < 4; ++nc)
                acc[mc][nc] =
                    __builtin_amdgcn_mfma_f32_16x16x32_bf16(aA[mc], aB[nc], acc[mc][nc], 0, 0, 0);
    }

    if (MODE == 0) {
        const int g = n0 / CD;
        const int hq = (n0 % CD) >> 6;
#pragma unroll
        for (int mc = 0; mc < 4; ++mc) {
#pragma unroll
            for (int r = 0; r < 4; ++r) {
                const int m = m0 + mc * 16 + quad * 4 + r;
                const int b = m / NTOK, n = m - (m / NTOK) * NTOK;
                const size_t bh = (size_t)(b * NH + hq);
                float gate = 0.f;
                if (g == 1 && n < NM) gate = 1.f + tanhf(IDK[(b * NM + n) * NH + hq]);
#pragma unroll
                for (int nc = 0; nc < 4; ++nc) {
                    const int d = nc * 16 + n16;
                    const int j = n0 + d;
                    const float val = acc[mc][nc][r] + bias[j];
                    const size_t om = (bh * NM + n) * 64 + d;
                    if (g == 0) {
                        qbh[(bh * NTOK + n) * 64 + d] = f2b(val * 0.125f);
                    } else if (g == 1) {
                        kseq[(bh * 3200 + 1600 + n) * 64 + d] = f2b(val);
                        if (n < NM) okm[om] = val * gate;
                    } else {
                        float vv = val;
                        if (n < NM) {
                            vv = val + ovm[om];
                            ovm[om] = vv;
                        }
                        vt[(bh * 64 + d) * 3200 + 1600 + n] = f2b(vv);
                    }
                }
            }
        }
    } else if (MODE == 1) {
#pragma unroll
        for (int mc = 0; mc < 4; ++mc) {
#pragma unroll
            for (int r = 0; r < 4; ++r) {
                const int m = m0 + mc * 16 + quad * 4 + r;
#pragma unroll
                for (int nc = 0; nc < 4; ++nc) {
                    const int j = n0 + nc * 16 + n16;
                    io[(size_t)m * CD + j] = acc[mc][nc][r] + bias[j];
                }
            }
        }
    } else {  // MODE 2: idv -> ovm scatter
#pragma unroll
        for (int mc = 0; mc < 4; ++mc) {
#pragma unroll
            for (int r = 0; r < 4; ++r) {
                const int m = m0 + mc * 16 + quad * 4 + r;
                const int b = m / NM, n = m - (m / NM) * NM;
#pragma unroll
                for (int nc = 0; nc < 4; ++nc) {
                    const int j = n0 + nc * 16 + n16;
                    const int h = j >> 6, d = j & 63;
                    ovm[(((size_t)(b * NH + h)) * NM + n) * 64 + d] = acc[mc][nc][r] + bias[j];
                }
            }
        }
    }
}

// ---------------- v9 top-k attention: register-resident, spill-free ----------------
// __launch_bounds__(512,1): min 1 wave/EU -> VGPR budget up to ~512/thread, no
// scratch spill of pk[] (r8 spilled at the default 128-VGPR target: 193 MB
// WRITE_SIZE of scratch traffic). LDS forces 1 block/CU for seq anyway.
template <int L, bool KF32>
__global__ __launch_bounds__(512, 1) void attn9_kernel(const u16* __restrict__ qbh,
                                                       const u16* __restrict__ Kb,
                                                       const float* __restrict__ Kf,
                                                       const u16* __restrict__ vt,
                                                       float* __restrict__ aob,
                                                       int top, int row_start, int krows,
                                                       int vtoff) {
    constexpr int LP = L + 8;
    constexpr int NCHT = L / 16;
    constexpr int NCH = (NCHT + 7) / 8;
    constexpr bool FULL = (NCHT % 8) == 0;  // seq: no per-chunk guards
    extern __shared__ __align__(16) u16 smem[];
    u16* wgt = smem;                          // 16*LP u16
    u32* hist = (u32*)(smem + 16 * LP);       // 2 replicas x 16 x 256 u32
    float* obuf = (float*)hist;               // alias (PV phase)
    float* rowmax = (float*)(hist + 8192);    // 128
    float* invtot = rowmax + 128;             // 16 (tot, then 1/tot)
    float* Mrow = invtot + 16;                // 16
    u32* selb = (u32*)(Mrow + 16);            // 16
    u32* Trow = selb + 16;                    // 16
    u32* wantr = Trow + 16;                   // 16

    const int tid = threadIdx.x;
    const int lane = tid & 63, wv = tid >> 6;
    const int quad = lane >> 4, n16 = lane & 15;
    const int rep = (n16 & 1) * 4096;
    const int bh = blockIdx.y;
    const int bb = bh / NH, hh = bh - bb * NH;
    const int r0 = row_start + blockIdx.x * 16;

    for (int i = tid; i < 8192; i += 512) hist[i] = 0;

    short8 aQ0, aQ1;
    {
        const u16* qp = qbh + ((size_t)bh * NTOK + r0 + n16) * 64;
        aQ0 = *(const short8*)(qp + quad * 8);
        aQ1 = *(const short8*)(qp + 32 + quad * 8);
    }
    __syncthreads();  // hist zero visible

    // ---- phase 1: QK^T MFMA; logits stay in regs; coarse hist from regs ----
    u32 pk[NCH][2];
    float rmax[4] = {-3.4e38f, -3.4e38f, -3.4e38f, -3.4e38f};
#pragma unroll
    for (int i = 0; i < NCH; ++i) {
        pk[i][0] = 0u; pk[i][1] = 0u;
        const int c = wv + i * 8;
        if (FULL || c < NCHT) {
            const int l0 = c << 4;
            short8 fb0, fb1;
            if (KF32) {
                const float* kp = Kf + ((size_t)bh * krows + l0 + n16) * 64 + quad * 8;
                const float4 x0 = *(const float4*)kp;
                const float4 x1 = *(const float4*)(kp + 4);
                const float4 y0 = *(const float4*)(kp + 32);
                const float4 y1 = *(const float4*)(kp + 36);
                fb0[0] = (short)f2b(x0.x); fb0[1] = (short)f2b(x0.y);
                fb0[2] = (short)f2b(x0.z); fb0[3] = (short)f2b(x0.w);
                fb0[4] = (short)f2b(x1.x); fb0[5] = (short)f2b(x1.y);
                fb0[6] = (short)f2b(x1.z); fb0[7] = (short)f2b(x1.w);
                fb1[0] = (short)f2b(y0.x); fb1[1] = (short)f2b(y0.y);
                fb1[2] = (short)f2b(y0.z); fb1[3] = (short)f2b(y0.w);
                fb1[4] = (short)f2b(y1.x); fb1[5] = (short)f2b(y1.y);
                fb1[6] = (short)f2b(y1.z); fb1[7] = (short)f2b(y1.w);
            } else {
                const u16* kp = Kb + ((size_t)bh * krows + l0 + n16) * 64 + quad * 8;
                fb0 = *(const short8*)kp;
                fb1 = *(const short8*)(kp + 32);
            }
            f32x4 d = {0.f, 0.f, 0.f, 0.f};
            d = __builtin_amdgcn_mfma_f32_16x16x32_bf16(aQ0, fb0, d, 0, 0, 0);
            d = __builtin_amdgcn_mfma_f32_16x16x32_bf16(aQ1, fb1, d, 0, 0, 0);
            const u16 w0 = f2b(d[0]), w1 = f2b(d[1]), w2 = f2b(d[2]), w3 = f2b(d[3]);
#pragma unroll
            for (int r = 0; r < 4; ++r) rmax[r] = fmaxf(rmax[r], d[r]);
            pk[i][0] = (u32)w0 | ((u32)w1 << 16);
            pk[i][1] = (u32)w2 | ((u32)w3 << 16);
            atomicAdd(&hist[rep + (quad * 4 + 0) * 256 + (flip16((u32)w0) >> 8)], 1u);
            atomicAdd(&hist[rep + (quad * 4 + 1) * 256 + (flip16((u32)w1) >> 8)], 1u);
            atomicAdd(&hist[rep + (quad * 4 + 2) * 256 + (flip16((u32)w2) >> 8)], 1u);
            atomicAdd(&hist[rep + (quad * 4 + 3) * 256 + (flip16((u32)w3) >> 8)], 1u);
        }
    }
#pragma unroll
    for (int off = 1; off < 16; off <<= 1) {
#pragma unroll
        for (int r = 0; r < 4; ++r) rmax[r] = fmaxf(rmax[r], __shfl_xor(rmax[r], off));
    }
    if (n16 == 0) {
#pragma unroll
        for (int r = 0; r < 4; ++r) rowmax[wv * 16 + quad * 4 + r] = rmax[r];
    }
    __syncthreads();

    // ---- scan0: wave per row (rows wv, wv+8) ----
#pragma unroll
    for (int rp = 0; rp < 2; ++rp) {
        const int rr = wv + 8 * rp;
        float M = -3.4e38f;
#pragma unroll
        for (int w = 0; w < 8; ++w) M = fmaxf(M, rowmax[w * 16 + rr]);
        if (lane == 0) Mrow[rr] = M;
        u32 hh4[4];
#pragma unroll
        for (int j = 0; j < 4; ++j)
            hh4[j] = hist[rr * 256 + 4 * lane + j] + hist[4096 + rr * 256 + 4 * lane + j];
        const u32 s = hh4[0] + hh4[1] + hh4[2] + hh4[3];
        u32 sum = s;
#pragma unroll
        for (int off = 1; off < 64; off <<= 1) {
            const u32 t = __shfl_down(sum, off);
            if (lane + off < 64) sum += t;
        }
        int cnt = (int)(sum - s);
        const int want = top;
        for (int j = 3; j >= 0; --j) {
            const int c = (int)hh4[j];
            if (cnt < want && cnt + c >= want) {
                selb[rr] = (u32)(4 * lane + j);
                wantr[rr] = (u32)(want - cnt);
            }
            cnt += c;
        }
    }
    __syncthreads();
    for (int i = tid; i < 8192; i += 512) hist[i] = 0;
    __syncthreads();

    // ---- round 1 from registers ----
    {
        u32 sl[4];
#pragma unroll
        for (int r = 0; r < 4; ++r) sl[r] = selb[quad * 4 + r];
#pragma unroll
        for (int i = 0; i < NCH; ++i) {
            const int c = wv + i * 8;
            if (FULL || c < NCHT) {
#pragma unroll
                for (int h = 0; h < 2; ++h) {
                    const u32 pr = pk[i][h];
                    const u32 k0 = flip16(pr & 0xffffu), k1 = flip16(pr >> 16);
                    const int r0i = quad * 4 + 2 * h, r1i = r0i + 1;
                    if ((k0 >> 8) == sl[2 * h])
                        atomicAdd(&hist[rep + r0i * 256 + (k0 & 255u)], 1u);
                    if ((k1 >> 8) == sl[2 * h + 1])
                        atomicAdd(&hist[rep + r1i * 256 + (k1 & 255u)], 1u);
                }
            }
        }
    }
    __syncthreads();

    // ---- scan1: T, wantT; init tot with tie term ----
#pragma unroll
    for (int rp = 0; rp < 2; ++rp) {
        const int rr = wv + 8 * rp;
        u32 hh4[4];
#pragma unroll
        for (int j = 0; j < 4; ++j)
            hh4[j] = hist[rr * 256 + 4 * lane + j] + hist[4096 + rr * 256 + 4 * lane + j];
        const u32 s = hh4[0] + hh4[1] + hh4[2] + hh4[3];
        u32 sum = s;
#pragma unroll
        for (int off = 1; off < 64; off <<= 1) {
            const u32 t = __shfl_down(sum, off);
            if (lane + off < 64) sum += t;
        }
        int cnt = (int)(sum - s);
        const int want = (int)wantr[rr];
        for (int j = 3; j >= 0; --j) {
            const int c = (int)hh4[j];
            if (cnt < want && cnt + c >= want) {
                const u32 T = (selb[rr] << 8) | (u32)(4 * lane + j);
                Trow[rr] = T;
                invtot[rr] =
                    (float)(want - cnt) * __expf(fminf(key2f(T) - Mrow[rr], 0.f));
            }
            cnt += c;
        }
    }
    __syncthreads();

    // ---- ps pass from registers; convert logits -> exp (unnormalized) in regs ----
    {
        u32 Tq[4];
        float Mq[4];
#pragma unroll
        for (int r = 0; r < 4; ++r) {
            Tq[r] = Trow[quad * 4 + r];
            Mq[r] = Mrow[quad * 4 + r];
        }
        float ps[4] = {0.f, 0.f, 0.f, 0.f};
#pragma unroll
        for (int i = 0; i < NCH; ++i) {
            const int c = wv + i * 8;
            if (FULL || c < NCHT) {
#pragma unroll
                for (int h = 0; h < 2; ++h) {
                    const u32 pr = pk[i][h];
                    const int r0i = 2 * h, r1i = 2 * h + 1;
                    const u32 k0 = flip16(pr & 0xffffu), k1 = flip16(pr >> 16);
                    float e0 = 0.f, e1 = 0.f;
                    if (k0 >= Tq[r0i]) {
                        e0 = __expf(fminf(b2f((u16)(pr & 0xffffu)) - Mq[r0i], 0.f));
                        if (k0 > Tq[r0i]) ps[r0i] += e0;
                    }
                    if (k1 >= Tq[r1i]) {
                        e1 = __expf(fminf(b2f((u16)(pr >> 16)) - Mq[r1i], 0.f));
                        if (k1 > Tq[r1i]) ps[r1i] += e1;
                    }
                    pk[i][h] = (u32)f2b(e0) | ((u32)f2b(e1) << 16);
                }
            }
        }
#pragma unroll
        for (int off = 1; off < 16; off <<= 1) {
#pragma unroll
            for (int r = 0; r < 4; ++r) ps[r] += __shfl_xor(ps[r], off);
        }
        if (n16 == 0) {
#pragma unroll
            for (int r = 0; r < 4; ++r) atomicAdd(&invtot[quad * 4 + r], ps[r]);
        }
    }
    __syncthreads();
    if (tid < 16) invtot[tid] = 1.f / fmaxf(invtot[tid], 1e-30f);
    __syncthreads();

    // ---- write normalized weights into wgt[row][key] for PV ----
    {
        float iv[4];
#pragma unroll
        for (int r = 0; r < 4; ++r) iv[r] = invtot[quad * 4 + r];
#pragma unroll
        for (int i = 0; i < NCH; ++i) {
            const int c = wv + i * 8;
            if (FULL || c < NCHT) {
                const int l = (c << 4) + n16;
#pragma unroll
                for (int h = 0; h < 2; ++h) {
                    const u32 pr = pk[i][h];
                    wgt[(size_t)(quad * 4 + 2 * h) * LP + l] =
                        f2b(b2f((u16)(pr & 0xffffu)) * iv[2 * h]);
                    wgt[(size_t)(quad * 4 + 2 * h + 1) * LP + l] =
                        f2b(b2f((u16)(pr >> 16)) * iv[2 * h + 1]);
                }
            }
        }
    }
    __syncthreads();

    // ---- PV via MFMA (weights already normalized) ----
    {
        const int half = wv & 1, dc = wv >> 1;
        constexpr int PVI = (L / 2) / 32;
        const int kbeg = half * (L / 2);
        const u16* vp =
            vt + ((size_t)bh * 64 + dc * 16 + n16) * 3200 + vtoff + quad * 8 + kbeg;
        const u16* wrow2 = wgt + (size_t)n16 * LP + quad * 8 + kbeg;
        f32x4 acc = {0.f, 0.f, 0.f, 0.f};
#pragma unroll 8
        for (int i = 0; i < PVI; ++i) {
            const short8 a = *(const short8*)(wrow2 + i * 32);
            const short8 bf = *(const short8*)(vp + i * 32);
            acc = __builtin_amdgcn_mfma_f32_16x16x32_bf16(a, bf, acc, 0, 0, 0);
        }
#pragma unroll
        for (int r = 0; r < 4; ++r) {
            const int rowi = quad * 4 + r;
            obuf[(half * 16 + rowi) * 64 + dc * 16 + n16] = acc[r];
        }
    }
    __syncthreads();
#pragma unroll
    for (int ii = 0; ii < 2; ++ii) {
        const int idx = tid + ii * 512;
        const int rowi = idx >> 6, dd = idx & 63;
        aob[((size_t)bb * NTOK + r0 + rowi) * CD + hh * 64 + dd] =
            obuf[rowi * 64 + dd] + obuf[(16 + rowi) * 64 + dd];
    }
}

// ---------------- proj routing coefficients ----------------
__global__ __launch_bounds__(256) void coef_kernel(const float* __restrict__ aob,
                                                   const float* __restrict__ rW,
                                                   const float* __restrict__ Ap,
                                                   float* __restrict__ coef) {
    __shared__ float rl[8][4];
    __shared__ float rw[8][4];
    const int slot = threadIdx.x >> 5, lane = threadIdx.x & 31;
    const int m = blockIdx.x * 8 + slot;
    const float* xr = aob + (size_t)m * CD;
    const float z = dot768_ff(xr, Ap + (size_t)lane * CD);
    if (lane < 4) rl[slot][lane] = dot768_ff(xr, rW + (size_t)lane * CD);
    __syncthreads();
    if (lane == 0) {
        const float mx = fmaxf(fmaxf(rl[slot][0], rl[slot][1]), fmaxf(rl[slot][2], rl[slot][3]));
        const float e0 = __expf(rl[slot][0] - mx), e1 = __expf(rl[slot][1] - mx);
        const float e2 = __expf(rl[slot][2] - mx), e3 = __expf(rl[slot][3] - mx);
        const float is = 1.f / (e0 + e1 + e2 + e3);
        rw[slot][0] = e0 * is; rw[slot][1] = e1 * is; rw[slot][2] = e2 * is; rw[slot][3] = e3 * is;
    }
    __syncthreads();
    coef[(size_t)m * 32 + lane] = rw[slot][lane >> 3] * z * 0.125f;
}

// ---------------- aob_aug builder ----------------
__global__ __launch_bounds__(256) void cvt_aobaug(const float* __restrict__ aob,
                                                  const float* __restrict__ coef,
                                                  u16* __restrict__ dst) {
    const int idx = blockIdx.x * 256 + threadIdx.x;  // 320000
    const int m = idx / 100, c8 = idx - m * 100;
    short8 v;
    if (c8 < 96) {
        const float* s = aob + (size_t)m * CD + c8 * 8;
#pragma unroll
        for (int i = 0; i < 8; ++i) v[i] = (short)f2b(s[i]);
    } else {
        const float* s = coef + (size_t)m * 32 + (c8 - 96) * 8;
#pragma unroll
        for (int i = 0; i < 8; ++i) v[i] = (short)f2b(s[i]);
    }
    *(short8*)(dst + (size_t)m * 800 + c8 * 8) = v;
}

extern "C" void kernel_launch(void* const* d_in, const int* in_sizes, int n_in,
                              void* d_out, int out_size, void* d_ws, size_t ws_size,
                              hipStream_t stream) {
    const float* x = (const float*)d_in[0];
    const float* id_total = (const float*)d_in[1];
    const float* mem_k = (const float*)d_in[2];
    const float* mem_v = (const float*)d_in[3];
    const float* W_qkv = (const float*)d_in[4];
    const float* b_qkv = (const float*)d_in[5];
    const float* A_qkv = (const float*)d_in[6];
    const float* B_qkv = (const float*)d_in[7];
    const float* W_proj = (const float*)d_in[8];
    const float* b_proj = (const float*)d_in[9];
    const float* routeW_proj = (const float*)d_in[10];
    const float* A_proj = (const float*)d_in[11];
    const float* B_proj = (const float*)d_in[12];
    const float* W_idk = (const float*)d_in[13];
    const float* b_idk = (const float*)d_in[14];
    const float* A_idk = (const float*)d_in[16];
    const float* B_idk = (const float*)d_in[17];
    const float* W_idv = (const float*)d_in[18];
    const float* b_idv = (const float*)d_in[19];
    const float* A_idv = (const float*)d_in[21];
    const float* B_idv = (const float*)d_in[22];

    float* io = (float*)d_out;                       // staging -> aob -> final out
    float* o_km = io + (size_t)BN * NTOK * CD;       // f32 k_m (& mem-attn K); widv_aug first
    float* o_vm = o_km + (size_t)BN * NH * NM * HD;  // f32 ID_V -> v_m

    u16* x_aug = (u16*)io;            // 3200*800 u16
    u16* wqkv_aug = x_aug + 2560000;  // 2304*800 u16 (io region total 8.8 MB <= 9.83 MB)
    u16* widv_aug = (u16*)o_km;       // 768*800 u16 = 1.23 MB <= 3.54 MB (dead pre-qkv)

    // workspace: 26,613,760 bytes
    u16* qbh = (u16*)d_ws;                  // (B,H,N,64) Q bf16; id_aug first
    u16* kseq = qbh + 2457600;              // (B,H,3200,64); later aob_aug
    u16* vt = kseq + 4915200;               // (B,H,64,3200) V^T
    float* zq = (float*)(vt + 4915200);     // 76800
    float* ziv = zq + 76800;                // 9216
    float* IDK = ziv + 9216;                // 13824
    float* coef = IDK + 13824;              // 102400
    u16* wproj_aug = (u16*)(coef + 102400); // 768*800 u16
    u16* id_aug = qbh;                      // 1152*800 u16 (dead pre-qkv)

    const int smem_seq = 16 * (3200 + 8) * 2 + 33600;  // 136,256
    const int smem_mem = 16 * (NM + 8) * 2 + 33600;    // 52,288
    hipFuncSetAttribute((const void*)attn9_kernel<3200, false>,
                        hipFuncAttributeMaxDynamicSharedMemorySize, smem_seq);
    hipFuncSetAttribute((const void*)attn9_kernel<NM, true>,
                        hipFuncAttributeMaxDynamicSharedMemorySize, smem_mem);

    small_dots<<<4352, 256, 0, stream>>>(x, A_qkv, zq, id_total, A_idk, A_idv,
                                         W_idk, b_idk, B_idk, ziv, IDK);
    stage_all<<<5000, 256, 0, stream>>>(x, zq, x_aug, W_qkv, B_qkv, wqkv_aug,
                                        W_proj, B_proj, wproj_aug, mem_k, kseq,
                                        mem_v, vt, id_total, ziv, id_aug,
                                        W_idv, B_idv, widv_aug);
    // ID_V via MFMA -> o_vm
    gemm16_kernel<2><<<dim3(6, 18), 128, 0, stream>>>(id_aug, widv_aug, b_idv, nullptr,
                                                      nullptr, nullptr, nullptr, nullptr,
                                                      o_vm, nullptr);
    // qkv via MFMA, fused LoRA + gate/ID_V epilogue
    gemm16_kernel<0><<<dim3(18, 25), 256, 0, stream>>>(x_aug, wqkv_aug, b_qkv, IDK,
                                                       qbh, kseq, vt, o_km, o_vm, nullptr);

    // memory attention: L=576, top=288, K=o_km (f32), V=VT cols 1600..2175
    attn9_kernel<NM, true><<<dim3(NM / 16, BN * NH), 512, smem_mem, stream>>>(
        qbh, nullptr, o_km, vt, io, NM / 2, 0, NM, 1600);
    // seq attention: L=3200, top=1600, K=kseq, V=VT cols 0..3199
    attn9_kernel<3200, false><<<dim3(NS / 16, BN * NH), 512, smem_seq, stream>>>(
        qbh, kseq, nullptr, vt, io, 1600, NM, 3200, 0);

    coef_kernel<<<400, 256, 0, stream>>>(io, routeW_proj, A_proj, coef);
    cvt_aobaug<<<1250, 256, 0, stream>>>(io, coef, kseq);
    // proj via MFMA, fused routed-LoRA, f32 out in-place
    gemm16_kernel<1><<<dim3(6, 50), 128, 0, stream>>>(kseq, wproj_aug, b_proj, nullptr,
                                                      nullptr, nullptr, nullptr, nullptr,
                                                      nullptr, io);
}

// Round 10
// 609.182 us; speedup vs baseline: 12.0632x; 1.0958x over previous
//
#include <hip/hip_runtime.h>
#include <hip/hip_bf16.h>

#define BN 2
#define NH 12
#define NTOK 1600
#define NM 576
#define NS 1024
#define CD 768
#define HD 64

typedef unsigned short u16;
typedef unsigned int u32;
typedef __attribute__((ext_vector_type(8))) short short8;   // 8 bf16 (4 VGPRs)
typedef __attribute__((ext_vector_type(4))) float f32x4;    // MFMA C/D

__device__ __forceinline__ float fbits(u32 u) { return __uint_as_float(u); }
__device__ __forceinline__ u16 f2b(float f) {  // RNE f32->bf16
    u32 u = __float_as_uint(f);
    u32 r = u + 0x7FFFu + ((u >> 16) & 1u);
    return (u16)(r >> 16);
}
__device__ __forceinline__ float b2f(u16 s) { return fbits(((u32)s) << 16); }
__device__ __forceinline__ u32 flip16(u32 u) {  // order-preserving bf16 -> u16 key
    return (u & 0x8000u) ? (0xFFFFu & ~u) : (u | 0x8000u);
}
__device__ __forceinline__ float key2f(u32 k) {
    u32 b = (k & 0x8000u) ? (k & 0x7FFFu) : (0xFFFFu & ~k);
    return fbits(b << 16);
}
__device__ __forceinline__ float wave_red(float p) {
#pragma unroll
    for (int off = 1; off < 64; off <<= 1) p += __shfl_xor(p, off);
    return p;
}

__device__ __forceinline__ float dot768_ff(const float* __restrict__ a,
                                           const float* __restrict__ b) {
    float s = 0.f;
    for (int c = 0; c < CD; c += 4) {
        float4 fa = *(const float4*)(a + c);
        float4 fb = *(const float4*)(b + c);
        s += fa.x * fb.x + fa.y * fb.y + fa.z * fb.z + fa.w * fb.w;
    }
    return s;
}

// ---------------- small_dots: z24 (x tokens) + ziv/IDK (id tokens) ----------------
__global__ __launch_bounds__(256) void small_dots(const float* __restrict__ x,
                                                  const float* __restrict__ Aq,
                                                  float* __restrict__ zq,
                                                  const float* __restrict__ id,
                                                  const float* __restrict__ Aik,
                                                  const float* __restrict__ Aiv,
                                                  const float* __restrict__ Wik,
                                                  const float* __restrict__ bik,
                                                  const float* __restrict__ Bik,
                                                  float* __restrict__ ziv,
                                                  float* __restrict__ IDK) {
    __shared__ float dres[28];
    const int blk = blockIdx.x;
    const int tid = threadIdx.x, lane = tid & 63, wv = tid >> 6;
    if (blk < 3200) {  // x token: 24 LoRA dots
        const float* xr = x + (size_t)blk * CD;
#pragma unroll
        for (int t = 0; t < 6; ++t) {
            const int q = wv * 6 + t;
            const float* ar = Aq + (size_t)q * CD;
            float p = 0.f;
#pragma unroll
            for (int c = 0; c < 12; ++c) p += xr[lane + c * 64] * ar[lane + c * 64];
            p = wave_red(p);
            if (lane == 0) zq[(size_t)blk * 24 + q] = p;
        }
    } else {  // id token: 8 zik + 8 ziv + 12 W_idk dots, then IDK
        const int m = blk - 3200;
        const float* xr = id + (size_t)m * CD;
#pragma unroll
        for (int t = 0; t < 7; ++t) {
            const int q = wv * 7 + t;
            const float* ar = (q < 8) ? Aik + (size_t)q * CD
                            : (q < 16) ? Aiv + (size_t)(q - 8) * CD
                                       : Wik + (size_t)(q - 16) * CD;
            float p = 0.f;
#pragma unroll
            for (int c = 0; c < 12; ++c) p += xr[lane + c * 64] * ar[lane + c * 64];
            p = wave_red(p);
            if (lane == 0) dres[q] = p;
        }
        __syncthreads();
        if (tid < 8) ziv[(size_t)m * 8 + tid] = dres[8 + tid];
        if (tid < 12) {
            float v = dres[16 + tid] + bik[tid];
            float lo = 0.f;
#pragma unroll
            for (int r = 0; r < 8; ++r) lo += dres[r] * Bik[tid * 8 + r];
            IDK[m * NH + tid] = v + 0.125f * lo;
        }
    }
}

// ---------------- stage_all: every bf16 staging conversion in one launch ----------------
__global__ __launch_bounds__(256) void stage_all(const float* __restrict__ x,
                                                 const float* __restrict__ zq,
                                                 u16* __restrict__ x_aug,
                                                 const float* __restrict__ Wq,
                                                 const float* __restrict__ Bq,
                                                 u16* __restrict__ wqkv_aug,
                                                 const float* __restrict__ Wp,
                                                 const float* __restrict__ Bp,
                                                 u16* __restrict__ wproj_aug,
                                                 const float* __restrict__ mk,
                                                 u16* __restrict__ kseq,
                                                 const float* __restrict__ mv,
                                                 u16* __restrict__ vt,
                                                 const float* __restrict__ id,
                                                 const float* __restrict__ ziv,
                                                 u16* __restrict__ id_aug,
                                                 const float* __restrict__ Widv,
                                                 const float* __restrict__ Bidv,
                                                 u16* __restrict__ widv_aug) {
    __shared__ float tile[64][65];
    const int blk = blockIdx.x;
    const int tid = threadIdx.x;
    if (blk < 1250) {  // x_aug: [x | zq | 0]
        const int idx = blk * 256 + tid;
        const int m = idx / 100, c8 = idx - m * 100;
        short8 v;
        if (c8 < 96) {
            const float* s = x + (size_t)m * CD + c8 * 8;
#pragma unroll
            for (int i = 0; i < 8; ++i) v[i] = (short)f2b(s[i]);
        } else if (c8 < 99) {
            const float* s = zq + (size_t)m * 24 + (c8 - 96) * 8;
#pragma unroll
            for (int i = 0; i < 8; ++i) v[i] = (short)f2b(s[i]);
        } else {
#pragma unroll
            for (int i = 0; i < 8; ++i) v[i] = 0;
        }
        *(short8*)(x_aug + (size_t)m * 800 + c8 * 8) = v;
    } else if (blk < 2150) {  // wqkv_aug
        const int idx = (blk - 1250) * 256 + tid;
        const int j = idx / 100, c8 = idx - j * 100;
        short8 v;
        if (c8 < 96) {
            const float* s = Wq + (size_t)j * CD + c8 * 8;
#pragma unroll
            for (int i = 0; i < 8; ++i) v[i] = (short)f2b(s[i]);
        } else if (c8 < 99) {
            const int g = j / CD, c = j - g * CD;
            const int gp = c8 - 96;
#pragma unroll
            for (int i = 0; i < 8; ++i)
                v[i] = (gp == g) ? (short)f2b(0.125f * Bq[((size_t)g * CD + c) * 8 + i])
                                 : (short)0;
        } else {
#pragma unroll
            for (int i = 0; i < 8; ++i) v[i] = 0;
        }
        *(short8*)(wqkv_aug + (size_t)j * 800 + c8 * 8) = v;
    } else if (blk < 2450) {  // wproj_aug
        const int idx = (blk - 2150) * 256 + tid;
        const int j = idx / 100, c8 = idx - j * 100;
        short8 v;
        if (c8 < 96) {
            const float* s = Wp + (size_t)j * CD + c8 * 8;
#pragma unroll
            for (int i = 0; i < 8; ++i) v[i] = (short)f2b(s[i]);
        } else {
            const int e = c8 - 96;
#pragma unroll
            for (int i = 0; i < 8; ++i) v[i] = (short)f2b(Bp[((size_t)e * CD + j) * 8 + i]);
        }
        *(short8*)(wproj_aug + (size_t)j * 800 + c8 * 8) = v;
    } else if (blk < 3650) {  // mem_k -> kseq rows 0..1599
        const int t = (blk - 2450) * 256 + tid;
        const size_t e = (size_t)t * 8;
        const size_t bh = e / (1600 * 64);
        const size_t rem = e - bh * (1600 * 64);
        const float4 f0 = *(const float4*)(mk + e);
        const float4 f1 = *(const float4*)(mk + e + 4);
        short8 s;
        s[0] = (short)f2b(f0.x); s[1] = (short)f2b(f0.y);
        s[2] = (short)f2b(f0.z); s[3] = (short)f2b(f0.w);
        s[4] = (short)f2b(f1.x); s[5] = (short)f2b(f1.y);
        s[6] = (short)f2b(f1.z); s[7] = (short)f2b(f1.w);
        *(short8*)(kseq + bh * (3200 * 64) + rem) = s;
    } else if (blk < 4250) {  // mem_v -> VT cols 0..1599 (transpose)
        const int i = blk - 3650;
        const int kt = i % 25, bh = i / 25;
        const int r = tid >> 2, c0 = (tid & 3) * 16;
        const float* src = mv + ((size_t)bh * 1600 + (size_t)kt * 64 + r) * 64 + c0;
#pragma unroll
        for (int q = 0; q < 4; ++q) {
            const float4 f = *(const float4*)(src + q * 4);
            tile[r][c0 + q * 4 + 0] = f.x;
            tile[r][c0 + q * 4 + 1] = f.y;
            tile[r][c0 + q * 4 + 2] = f.z;
            tile[r][c0 + q * 4 + 3] = f.w;
        }
        __syncthreads();
        short8 s0, s1;
#pragma unroll
        for (int q = 0; q < 8; ++q) s0[q] = (short)f2b(tile[c0 + q][r]);
#pragma unroll
        for (int q = 0; q < 8; ++q) s1[q] = (short)f2b(tile[c0 + 8 + q][r]);
        u16* dst = vt + ((size_t)bh * 64 + r) * 3200 + (size_t)kt * 64 + c0;
        *(short8*)dst = s0;
        *(short8*)(dst + 8) = s1;
    } else if (blk < 4700) {  // id_aug: [id | ziv | 0]
        const int idx = (blk - 4250) * 256 + tid;  // 115200
        const int m = idx / 100, c8 = idx - m * 100;
        short8 v;
        if (c8 < 96) {
            const float* s = id + (size_t)m * CD + c8 * 8;
#pragma unroll
            for (int i = 0; i < 8; ++i) v[i] = (short)f2b(s[i]);
        } else if (c8 == 96) {
            const float* s = ziv + (size_t)m * 8;
#pragma unroll
            for (int i = 0; i < 8; ++i) v[i] = (short)f2b(s[i]);
        } else {
#pragma unroll
            for (int i = 0; i < 8; ++i) v[i] = 0;
        }
        *(short8*)(id_aug + (size_t)m * 800 + c8 * 8) = v;
    } else {  // widv_aug
        const int idx = (blk - 4700) * 256 + tid;  // 76800
        const int j = idx / 100, c8 = idx - j * 100;
        short8 v;
        if (c8 < 96) {
            const float* s = Widv + (size_t)j * CD + c8 * 8;
#pragma unroll
            for (int i = 0; i < 8; ++i) v[i] = (short)f2b(s[i]);
        } else if (c8 == 96) {
#pragma unroll
            for (int i = 0; i < 8; ++i) v[i] = (short)f2b(0.125f * Bidv[(size_t)j * 8 + i]);
        } else {
#pragma unroll
            for (int i = 0; i < 8; ++i) v[i] = 0;
        }
        *(short8*)(widv_aug + (size_t)j * 800 + c8 * 8) = v;
    }
}

// ---------------- MFMA GEMM, K=800 augmented ----------------
template <int MODE>
__global__ __launch_bounds__(MODE == 0 ? 256 : 128) void
gemm16_kernel(const u16* __restrict__ A16, const u16* __restrict__ B16,
              const float* __restrict__ bias, const float* __restrict__ IDK,
              u16* __restrict__ qbh, u16* __restrict__ kseq, u16* __restrict__ vt,
              float* __restrict__ okm, float* __restrict__ ovm,
              float* __restrict__ io) {
    const int tid = threadIdx.x;
    const int lane = tid & 63, wv = tid >> 6;
    const int quad = lane >> 4, n16 = lane & 15;
    int m0, n0;
    if (MODE == 0) {
        m0 = blockIdx.y * 128 + (wv >> 1) * 64;
        n0 = blockIdx.x * 128 + (wv & 1) * 64;
    } else {
        m0 = blockIdx.y * 64;
        n0 = blockIdx.x * 128 + wv * 64;
    }

    f32x4 acc[4][4];
#pragma unroll
    for (int a = 0; a < 4; ++a)
#pragma unroll
        for (int b = 0; b < 4; ++b) acc[a][b] = (f32x4){0.f, 0.f, 0.f, 0.f};

    const u16* ap = A16 + (size_t)(m0 + n16) * 800 + quad * 8;
    const u16* bp = B16 + (size_t)(n0 + n16) * 800 + quad * 8;
#pragma unroll 2
    for (int k0 = 0; k0 < 800; k0 += 32) {
        short8 aA[4], aB[4];
#pragma unroll
        for (int c = 0; c < 4; ++c) {
            aA[c] = *(const short8*)(ap + (size_t)c * 16 * 800 + k0);
            aB[c] = *(const short8*)(bp + (size_t)c * 16 * 800 + k0);
        }
#pragma unroll
        for (int mc = 0; mc < 4; ++mc)
#pragma unroll
            for (int nc = 0; nc < 4; ++nc)
                acc[mc][nc] =
                    __builtin_amdgcn_mfma_f32_16x16x32_bf16(aA[mc], aB[nc], acc[mc][nc], 0, 0, 0);
    }

    if (MODE == 0) {
        const int g = n0 / CD;
        const int hq = (n0 % CD) >> 6;
#pragma unroll
        for (int mc = 0; mc < 4; ++mc) {
#pragma unroll
            for (int r = 0; r < 4; ++r) {
                const int m = m0 + mc * 16 + quad * 4 + r;
                const int b = m / NTOK, n = m - (m / NTOK) * NTOK;
                const size_t bh = (size_t)(b * NH + hq);
                float gate = 0.f;
                if (g == 1 && n < NM) gate = 1.f + tanhf(IDK[(b * NM + n) * NH + hq]);
#pragma unroll
                for (int nc = 0; nc < 4; ++nc) {
                    const int d = nc * 16 + n16;
                    const int j = n0 + d;
                    const float val = acc[mc][nc][r] + bias[j];
                    const size_t om = (bh * NM + n) * 64 + d;
                    if (g == 0) {
                        qbh[(bh * NTOK + n) * 64 + d] = f2b(val * 0.125f);
                    } else if (g == 1) {
                        kseq[(bh * 3200 + 1600 + n) * 64 + d] = f2b(val);
                        if (n < NM) okm[om] = val * gate;
                    } else {
                        float vv = val;
                        if (n < NM) {
                            vv = val + ovm[om];
                            ovm[om] = vv;
                        }
                        vt[(bh * 64 + d) * 3200 + 1600 + n] = f2b(vv);
                    }
                }
            }
        }
    } else if (MODE == 1) {
#pragma unroll
        for (int mc = 0; mc < 4; ++mc) {
#pragma unroll
            for (int r = 0; r < 4; ++r) {
                const int m = m0 + mc * 16 + quad * 4 + r;
#pragma unroll
                for (int nc = 0; nc < 4; ++nc) {
                    const int j = n0 + nc * 16 + n16;
                    io[(size_t)m * CD + j] = acc[mc][nc][r] + bias[j];
                }
            }
        }
    } else {  // MODE 2: idv -> ovm scatter
#pragma unroll
        for (int mc = 0; mc < 4; ++mc) {
#pragma unroll
            for (int r = 0; r < 4; ++r) {
                const int m = m0 + mc * 16 + quad * 4 + r;
                const int b = m / NM, n = m - (m / NM) * NM;
#pragma unroll
                for (int nc = 0; nc < 4; ++nc) {
                    const int j = n0 + nc * 16 + n16;
                    const int h = j >> 6, d = j & 63;
                    ovm[(((size_t)(b * NH + h)) * NM + n) * 64 + d] = acc[mc][nc][r] + bias[j];
                }
            }
        }
    }
}

// ---------------- v10 top-k attention: LDS-resident logits, wave-private select ----
// No per-thread logit array (r8/r9 spilled it: 98-193 MB scratch traffic). Logits
// go to wgt in phase 1; selection rows are wave-private; all row passes are
// fully-unrolled batched ds_read_b32. Normalization deferred to PV epilogue.
template <int L, bool KF32>
__global__ __launch_bounds__(512) void attn10_kernel(const u16* __restrict__ qbh,
                                                     const u16* __restrict__ Kb,
                                                     const float* __restrict__ Kf,
                                                     const u16* __restrict__ vt,
                                                     float* __restrict__ aob,
                                                     int top, int row_start, int krows,
                                                     int vtoff) {
    constexpr int LP = L + 8;
    constexpr int NCHT = L / 16;
    constexpr int NCH = (NCHT + 7) / 8;
    constexpr bool FULL = (NCHT % 8) == 0;
    constexpr int PAIRS = L / 2;
    constexpr int NPIT = (PAIRS + 63) / 64;
    constexpr bool PFULL = (PAIRS % 64) == 0;
    extern __shared__ __align__(16) u16 smem[];
    u16* wgt = smem;                          // 16*LP u16 (logits -> exp weights)
    u32* hist = (u32*)(smem + 16 * LP);       // 2 replicas x 16 x 256 u32
    float* obuf = (float*)hist;               // alias (PV phase)
    float* rowmax = (float*)(hist + 8192);    // 128
    float* invtot = rowmax + 128;             // 16 (tie-term, then 1/total)
    float* Mrow = invtot + 16;                // 16
    u32* selb = (u32*)(Mrow + 16);            // 16
    u32* Trow = selb + 16;                    // 16
    u32* wantr = Trow + 16;                   // 16

    const int tid = threadIdx.x;
    const int lane = tid & 63, wv = tid >> 6;
    const int quad = lane >> 4, n16 = lane & 15;
    const int rep = (n16 & 1) * 4096;
    const int bh = blockIdx.y;
    const int bb = bh / NH, hh = bh - bb * NH;
    const int r0 = row_start + blockIdx.x * 16;

    for (int i = tid; i < 8192; i += 512) hist[i] = 0;

    short8 aQ0, aQ1;
    {
        const u16* qp = qbh + ((size_t)bh * NTOK + r0 + n16) * 64;
        aQ0 = *(const short8*)(qp + quad * 8);
        aQ1 = *(const short8*)(qp + 32 + quad * 8);
    }
    __syncthreads();  // hist zero visible

    // ---- phase 1: QK^T MFMA -> wgt (bf16); coarse hist from in-flight regs ----
    float rmax[4] = {-3.4e38f, -3.4e38f, -3.4e38f, -3.4e38f};
#pragma unroll
    for (int i = 0; i < NCH; ++i) {
        const int c = wv + i * 8;
        if (FULL || c < NCHT) {
            const int l0 = c << 4;
            short8 fb0, fb1;
            if (KF32) {
                const float* kp = Kf + ((size_t)bh * krows + l0 + n16) * 64 + quad * 8;
                const float4 x0 = *(const float4*)kp;
                const float4 x1 = *(const float4*)(kp + 4);
                const float4 y0 = *(const float4*)(kp + 32);
                const float4 y1 = *(const float4*)(kp + 36);
                fb0[0] = (short)f2b(x0.x); fb0[1] = (short)f2b(x0.y);
                fb0[2] = (short)f2b(x0.z); fb0[3] = (short)f2b(x0.w);
                fb0[4] = (short)f2b(x1.x); fb0[5] = (short)f2b(x1.y);
                fb0[6] = (short)f2b(x1.z); fb0[7] = (short)f2b(x1.w);
                fb1[0] = (short)f2b(y0.x); fb1[1] = (short)f2b(y0.y);
                fb1[2] = (short)f2b(y0.z); fb1[3] = (short)f2b(y0.w);
                fb1[4] = (short)f2b(y1.x); fb1[5] = (short)f2b(y1.y);
                fb1[6] = (short)f2b(y1.z); fb1[7] = (short)f2b(y1.w);
            } else {
                const u16* kp = Kb + ((size_t)bh * krows + l0 + n16) * 64 + quad * 8;
                fb0 = *(const short8*)kp;
                fb1 = *(const short8*)(kp + 32);
            }
            f32x4 d = {0.f, 0.f, 0.f, 0.f};
            d = __builtin_amdgcn_mfma_f32_16x16x32_bf16(aQ0, fb0, d, 0, 0, 0);
            d = __builtin_amdgcn_mfma_f32_16x16x32_bf16(aQ1, fb1, d, 0, 0, 0);
            const u16 w0 = f2b(d[0]), w1 = f2b(d[1]), w2 = f2b(d[2]), w3 = f2b(d[3]);
#pragma unroll
            for (int r = 0; r < 4; ++r) rmax[r] = fmaxf(rmax[r], d[r]);
            wgt[(size_t)(quad * 4 + 0) * LP + l0 + n16] = w0;
            wgt[(size_t)(quad * 4 + 1) * LP + l0 + n16] = w1;
            wgt[(size_t)(quad * 4 + 2) * LP + l0 + n16] = w2;
            wgt[(size_t)(quad * 4 + 3) * LP + l0 + n16] = w3;
            atomicAdd(&hist[rep + (quad * 4 + 0) * 256 + (flip16((u32)w0) >> 8)], 1u);
            atomicAdd(&hist[rep + (quad * 4 + 1) * 256 + (flip16((u32)w1) >> 8)], 1u);
            atomicAdd(&hist[rep + (quad * 4 + 2) * 256 + (flip16((u32)w2) >> 8)], 1u);
            atomicAdd(&hist[rep + (quad * 4 + 3) * 256 + (flip16((u32)w3) >> 8)], 1u);
        }
    }
#pragma unroll
    for (int off = 1; off < 16; off <<= 1) {
#pragma unroll
        for (int r = 0; r < 4; ++r) rmax[r] = fmaxf(rmax[r], __shfl_xor(rmax[r], off));
    }
    if (n16 == 0) {
#pragma unroll
        for (int r = 0; r < 4; ++r) rowmax[wv * 16 + quad * 4 + r] = rmax[r];
    }
    __syncthreads();

    // ---- scan0: wave per row (rows wv, wv+8); needs all waves' hist ----
#pragma unroll
    for (int rp = 0; rp < 2; ++rp) {
        const int rr = wv + 8 * rp;
        float M = -3.4e38f;
#pragma unroll
        for (int w = 0; w < 8; ++w) M = fmaxf(M, rowmax[w * 16 + rr]);
        if (lane == 0) Mrow[rr] = M;
        u32 hh4[4];
#pragma unroll
        for (int j = 0; j < 4; ++j)
            hh4[j] = hist[rr * 256 + 4 * lane + j] + hist[4096 + rr * 256 + 4 * lane + j];
        const u32 s = hh4[0] + hh4[1] + hh4[2] + hh4[3];
        u32 sum = s;
#pragma unroll
        for (int off = 1; off < 64; off <<= 1) {
            const u32 t = __shfl_down(sum, off);
            if (lane + off < 64) sum += t;
        }
        int cnt = (int)(sum - s);
        const int want = top;
        for (int j = 3; j >= 0; --j) {
            const int c = (int)hh4[j];
            if (cnt < want && cnt + c >= want) {
                selb[rr] = (u32)(4 * lane + j);
                wantr[rr] = (u32)(want - cnt);
            }
            cnt += c;
        }
    }
    __syncthreads();
    for (int i = tid; i < 8192; i += 512) hist[i] = 0;
    __syncthreads();

    // ---- wave-private per-row: round1 hist -> scan1 -> exp/sum/writeback ----
#pragma unroll
    for (int rp = 0; rp < 2; ++rp) {
        const int rr = wv + 8 * rp;
        const u32* row32 = (const u32*)(wgt + (size_t)rr * LP);
        const u32 sel1 = selb[rr];
        const float M = Mrow[rr];
        // round 1: fine-byte hist over keys whose coarse byte == sel1
#pragma unroll
        for (int i = 0; i < NPIT; ++i) {
            if (PFULL || lane + 64 * i < PAIRS) {
                const u32 pr = row32[lane + 64 * i];
                const u32 k0 = flip16(pr & 0xffffu), k1 = flip16(pr >> 16);
                if ((k0 >> 8) == sel1) atomicAdd(&hist[rep + rr * 256 + (k0 & 255u)], 1u);
                if ((k1 >> 8) == sel1) atomicAdd(&hist[rep + rr * 256 + (k1 & 255u)], 1u);
            }
        }
        __threadfence_block();
        // scan1: T, tie-term
        {
            u32 hh4[4];
#pragma unroll
            for (int j = 0; j < 4; ++j)
                hh4[j] = hist[rr * 256 + 4 * lane + j] + hist[4096 + rr * 256 + 4 * lane + j];
            const u32 s = hh4[0] + hh4[1] + hh4[2] + hh4[3];
            u32 sum = s;
#pragma unroll
            for (int off = 1; off < 64; off <<= 1) {
                const u32 t = __shfl_down(sum, off);
                if (lane + off < 64) sum += t;
            }
            int cnt = (int)(sum - s);
            const int want = (int)wantr[rr];
            for (int j = 3; j >= 0; --j) {
                const int c = (int)hh4[j];
                if (cnt < want && cnt + c >= want) {
                    const u32 T = (sel1 << 8) | (u32)(4 * lane + j);
                    Trow[rr] = T;
                    invtot[rr] = (float)(want - cnt) * __expf(fminf(key2f(T) - M, 0.f));
                }
                cnt += c;
            }
        }
        __threadfence_block();
        // exp + writeback + partial sum (single pass)
        {
            const u32 T = Trow[rr];
            u32* roww = (u32*)(wgt + (size_t)rr * LP);
            float ps = 0.f;
#pragma unroll
            for (int i = 0; i < NPIT; ++i) {
                if (PFULL || lane + 64 * i < PAIRS) {
                    const u32 pr = roww[lane + 64 * i];
                    const u32 k0 = flip16(pr & 0xffffu), k1 = flip16(pr >> 16);
                    float e0 = 0.f, e1 = 0.f;
                    if (k0 >= T) {
                        e0 = __expf(fminf(b2f((u16)(pr & 0xffffu)) - M, 0.f));
                        if (k0 > T) ps += e0;
                    }
                    if (k1 >= T) {
                        e1 = __expf(fminf(b2f((u16)(pr >> 16)) - M, 0.f));
                        if (k1 > T) ps += e1;
                    }
                    roww[lane + 64 * i] = (u32)f2b(e0) | ((u32)f2b(e1) << 16);
                }
            }
            ps = wave_red(ps);
            if (lane == 0) invtot[rr] = 1.f / fmaxf(invtot[rr] + ps, 1e-30f);
        }
    }
    __syncthreads();

    // ---- PV via MFMA; normalize in epilogue ----
    {
        const int half = wv & 1, dc = wv >> 1;
        constexpr int PVI = (L / 2) / 32;
        const int kbeg = half * (L / 2);
        const u16* vp =
            vt + ((size_t)bh * 64 + dc * 16 + n16) * 3200 + vtoff + quad * 8 + kbeg;
        const u16* wrow2 = wgt + (size_t)n16 * LP + quad * 8 + kbeg;
        f32x4 acc = {0.f, 0.f, 0.f, 0.f};
#pragma unroll 8
        for (int i = 0; i < PVI; ++i) {
            const short8 a = *(const short8*)(wrow2 + i * 32);
            const short8 bf = *(const short8*)(vp + i * 32);
            acc = __builtin_amdgcn_mfma_f32_16x16x32_bf16(a, bf, acc, 0, 0, 0);
        }
#pragma unroll
        for (int r = 0; r < 4; ++r) {
            const int rowi = quad * 4 + r;
            obuf[(half * 16 + rowi) * 64 + dc * 16 + n16] = acc[r] * invtot[rowi];
        }
    }
    __syncthreads();
#pragma unroll
    for (int ii = 0; ii < 2; ++ii) {
        const int idx = tid + ii * 512;
        const int rowi = idx >> 6, dd = idx & 63;
        aob[((size_t)bb * NTOK + r0 + rowi) * CD + hh * 64 + dd] =
            obuf[rowi * 64 + dd] + obuf[(16 + rowi) * 64 + dd];
    }
}

// ---------------- proj routing coefficients ----------------
__global__ __launch_bounds__(256) void coef_kernel(const float* __restrict__ aob,
                                                   const float* __restrict__ rW,
                                                   const float* __restrict__ Ap,
                                                   float* __restrict__ coef) {
    __shared__ float rl[8][4];
    __shared__ float rw[8][4];
    const int slot = threadIdx.x >> 5, lane = threadIdx.x & 31;
    const int m = blockIdx.x * 8 + slot;
    const float* xr = aob + (size_t)m * CD;
    const float z = dot768_ff(xr, Ap + (size_t)lane * CD);
    if (lane < 4) rl[slot][lane] = dot768_ff(xr, rW + (size_t)lane * CD);
    __syncthreads();
    if (lane == 0) {
        const float mx = fmaxf(fmaxf(rl[slot][0], rl[slot][1]), fmaxf(rl[slot][2], rl[slot][3]));
        const float e0 = __expf(rl[slot][0] - mx), e1 = __expf(rl[slot][1] - mx);
        const float e2 = __expf(rl[slot][2] - mx), e3 = __expf(rl[slot][3] - mx);
        const float is = 1.f / (e0 + e1 + e2 + e3);
        rw[slot][0] = e0 * is; rw[slot][1] = e1 * is; rw[slot][2] = e2 * is; rw[slot][3] = e3 * is;
    }
    __syncthreads();
    coef[(size_t)m * 32 + lane] = rw[slot][lane >> 3] * z * 0.125f;
}

// ---------------- aob_aug builder ----------------
__global__ __launch_bounds__(256) void cvt_aobaug(const float* __restrict__ aob,
                                                  const float* __restrict__ coef,
                                                  u16* __restrict__ dst) {
    const int idx = blockIdx.x * 256 + threadIdx.x;  // 320000
    const int m = idx / 100, c8 = idx - m * 100;
    short8 v;
    if (c8 < 96) {
        const float* s = aob + (size_t)m * CD + c8 * 8;
#pragma unroll
        for (int i = 0; i < 8; ++i) v[i] = (short)f2b(s[i]);
    } else {
        const float* s = coef + (size_t)m * 32 + (c8 - 96) * 8;
#pragma unroll
        for (int i = 0; i < 8; ++i) v[i] = (short)f2b(s[i]);
    }
    *(short8*)(dst + (size_t)m * 800 + c8 * 8) = v;
}

extern "C" void kernel_launch(void* const* d_in, const int* in_sizes, int n_in,
                              void* d_out, int out_size, void* d_ws, size_t ws_size,
                              hipStream_t stream) {
    const float* x = (const float*)d_in[0];
    const float* id_total = (const float*)d_in[1];
    const float* mem_k = (const float*)d_in[2];
    const float* mem_v = (const float*)d_in[3];
    const float* W_qkv = (const float*)d_in[4];
    const float* b_qkv = (const float*)d_in[5];
    const float* A_qkv = (const float*)d_in[6];
    const float* B_qkv = (const float*)d_in[7];
    const float* W_proj = (const float*)d_in[8];
    const float* b_proj = (const float*)d_in[9];
    const float* routeW_proj = (const float*)d_in[10];
    const float* A_proj = (const float*)d_in[11];
    const float* B_proj = (const float*)d_in[12];
    const float* W_idk = (const float*)d_in[13];
    const float* b_idk = (const float*)d_in[14];
    const float* A_idk = (const float*)d_in[16];
    const float* B_idk = (const float*)d_in[17];
    const float* W_idv = (const float*)d_in[18];
    const float* b_idv = (const float*)d_in[19];
    const float* A_idv = (const float*)d_in[21];
    const float* B_idv = (const float*)d_in[22];

    float* io = (float*)d_out;                       // staging -> aob -> final out
    float* o_km = io + (size_t)BN * NTOK * CD;       // f32 k_m (& mem-attn K); widv_aug first
    float* o_vm = o_km + (size_t)BN * NH * NM * HD;  // f32 ID_V -> v_m

    u16* x_aug = (u16*)io;            // 3200*800 u16
    u16* wqkv_aug = x_aug + 2560000;  // 2304*800 u16 (io region total 8.8 MB <= 9.83 MB)
    u16* widv_aug = (u16*)o_km;       // 768*800 u16 (dead pre-qkv)

    // workspace: 26,613,760 bytes
    u16* qbh = (u16*)d_ws;                  // (B,H,N,64) Q bf16; id_aug first
    u16* kseq = qbh + 2457600;              // (B,H,3200,64); later aob_aug
    u16* vt = kseq + 4915200;               // (B,H,64,3200) V^T
    float* zq = (float*)(vt + 4915200);     // 76800
    float* ziv = zq + 76800;                // 9216
    float* IDK = ziv + 9216;                // 13824
    float* coef = IDK + 13824;              // 102400
    u16* wproj_aug = (u16*)(coef + 102400); // 768*800 u16
    u16* id_aug = qbh;                      // 1152*800 u16 (dead pre-qkv)

    const int smem_seq = 16 * (3200 + 8) * 2 + 33600;  // 136,256
    const int smem_mem = 16 * (NM + 8) * 2 + 33600;    // 52,288
    hipFuncSetAttribute((const void*)attn10_kernel<3200, false>,
                        hipFuncAttributeMaxDynamicSharedMemorySize, smem_seq);
    hipFuncSetAttribute((const void*)attn10_kernel<NM, true>,
                        hipFuncAttributeMaxDynamicSharedMemorySize, smem_mem);

    small_dots<<<4352, 256, 0, stream>>>(x, A_qkv, zq, id_total, A_idk, A_idv,
                                         W_idk, b_idk, B_idk, ziv, IDK);
    stage_all<<<5000, 256, 0, stream>>>(x, zq, x_aug, W_qkv, B_qkv, wqkv_aug,
                                        W_proj, B_proj, wproj_aug, mem_k, kseq,
                                        mem_v, vt, id_total, ziv, id_aug,
                                        W_idv, B_idv, widv_aug);
    // ID_V via MFMA -> o_vm
    gemm16_kernel<2><<<dim3(6, 18), 128, 0, stream>>>(id_aug, widv_aug, b_idv, nullptr,
                                                      nullptr, nullptr, nullptr, nullptr,
                                                      o_vm, nullptr);
    // qkv via MFMA, fused LoRA + gate/ID_V epilogue
    gemm16_kernel<0><<<dim3(18, 25), 256, 0, stream>>>(x_aug, wqkv_aug, b_qkv, IDK,
                                                       qbh, kseq, vt, o_km, o_vm, nullptr);

    // memory attention: L=576, top=288, K=o_km (f32), V=VT cols 1600..2175
    attn10_kernel<NM, true><<<dim3(NM / 16, BN * NH), 512, smem_mem, stream>>>(
        qbh, nullptr, o_km, vt, io, NM / 2, 0, NM, 1600);
    // seq attention: L=3200, top=1600, K=kseq, V=VT cols 0..3199
    attn10_kernel<3200, false><<<dim3(NS / 16, BN * NH), 512, smem_seq, stream>>>(
        qbh, kseq, nullptr, vt, io, 1600, NM, 3200, 0);

    coef_kernel<<<400, 256, 0, stream>>>(io, routeW_proj, A_proj, coef);
    cvt_aobaug<<<1250, 256, 0, stream>>>(io, coef, kseq);
    // proj via MFMA, fused routed-LoRA, f32 out in-place
    gemm16_kernel<1><<<dim3(6, 50), 128, 0, stream>>>(kseq, wproj_aug, b_proj, nullptr,
                                                      nullptr, nullptr, nullptr, nullptr,
                                                      nullptr, io);
}